// Round 4
// baseline (1143.983 us; speedup 1.0000x reference)
//
#include <hip/hip_runtime.h>
#include <hip/hip_bf16.h>

using u16 = unsigned short;

__device__ __forceinline__ float b2f(u16 u) {
    union { unsigned int i; float f; } v; v.i = ((unsigned int)u) << 16; return v.f;
}
__device__ __forceinline__ u16 f2b(float f) {
    __hip_bfloat16 h = __float2bfloat16(f);
    u16 u; __builtin_memcpy(&u, &h, sizeof(u)); return u;
}

// B=4, fine 64x64x256, coarse 32x32x256, F=256, DG=8, KK=9, om ch=216
// Inputs fp32; OUTPUT fp32 (bf16 label in harness is hardcoded; buffer is fp32).
// Intermediates: cu/fine_cal bf16, W_eff/om fp32.

// ---------------- stage 1a: global average pool (partial + atomic) --------------
__global__ __launch_bounds__(256) void k_gap(const float* __restrict__ fine,
                                             float* __restrict__ gap) {
    int b = blockIdx.y, chunk = blockIdx.x, c = threadIdx.x;
    const float* p = fine + ((size_t)b * 4096 + (size_t)chunk * 128) * 256 + c;
    float s = 0.f;
    for (int i = 0; i < 128; i++) s += p[(size_t)i * 256];
    atomicAdd(&gap[b * 256 + c], s);
}

// ---------------- stage 1b: a1 = sigmoid(gap@W / 4096) + 1 ----------------------
__global__ __launch_bounds__(256) void k_attn(const float* __restrict__ gap,
                                              const float* __restrict__ w,
                                              float* __restrict__ a1) {
    int b = blockIdx.x, d = threadIdx.x;
    float s = 0.f;
    for (int c = 0; c < 256; c++) s += gap[b * 256 + c] * w[c * 256 + d];
    s *= (1.0f / 4096.0f);
    a1[b * 256 + d] = 1.0f + 1.0f / (1.0f + expf(-s));
}

// ---------------- stage 2: bilinear 2x upsample (half-pixel, clamped) -> bf16 ---
__global__ __launch_bounds__(256) void k_upsample(const float* __restrict__ coarse,
                                                  u16* __restrict__ cu) {
    int y = blockIdx.x, b = blockIdx.y, c = threadIdx.x;
    float sy = fminf(fmaxf(0.5f * y - 0.25f, 0.0f), 31.0f);
    int y0 = (int)floorf(sy); float wy = sy - (float)y0; int y1 = min(y0 + 1, 31);
    const float* base = coarse + (size_t)b * 32 * 32 * 256 + c;
    u16* ob = cu + ((size_t)b * 64 + y) * 64 * 256 + c;
    for (int x = 0; x < 64; x++) {
        float sx = fminf(fmaxf(0.5f * x - 0.25f, 0.0f), 31.0f);
        int x0 = (int)floorf(sx); float wx = sx - (float)x0; int x1 = min(x0 + 1, 31);
        float v00 = base[((size_t)y0 * 32 + x0) * 256];
        float v01 = base[((size_t)y0 * 32 + x1) * 256];
        float v10 = base[((size_t)y1 * 32 + x0) * 256];
        float v11 = base[((size_t)y1 * 32 + x1) * 256];
        ob[(size_t)x * 256] = f2b((1.f - wy) * ((1.f - wx) * v00 + wx * v01)
                                + wy * ((1.f - wx) * v10 + wx * v11));
    }
}

// ---------------- stage 3: fine_cal = (fine * a1) @ fs_conv_w -> bf16 -----------
__global__ __launch_bounds__(256) void k_gemm0(const float* __restrict__ fine,
                                               const float* __restrict__ a1,
                                               const float* __restrict__ Bw,
                                               u16* __restrict__ C) {
    __shared__ float As[16][68];
    __shared__ float Bs[16][64];
    int tid = threadIdx.x;
    int n0 = blockIdx.x * 64, m0 = blockIdx.y * 64;
    int tx = tid & 15, ty = tid >> 4;
    int am = tid >> 2, ak = (tid & 3) * 4;
    int bk = tid >> 4, bn = (tid & 15) * 4;
    float acc[4][4] = {};
    for (int k0 = 0; k0 < 256; k0 += 16) {
        int row = m0 + am, k = k0 + ak;
        float4 r = *(const float4*)(fine + (size_t)row * 256 + k);
        const float* ap = a1 + (row >> 12) * 256 + k;
        As[ak + 0][am] = r.x * ap[0];
        As[ak + 1][am] = r.y * ap[1];
        As[ak + 2][am] = r.z * ap[2];
        As[ak + 3][am] = r.w * ap[3];
        float4 w = *(const float4*)(Bw + (size_t)(k0 + bk) * 256 + n0 + bn);
        Bs[bk][bn + 0] = w.x; Bs[bk][bn + 1] = w.y;
        Bs[bk][bn + 2] = w.z; Bs[bk][bn + 3] = w.w;
        __syncthreads();
        #pragma unroll
        for (int kk = 0; kk < 16; kk++) {
            float4 a4 = *(const float4*)&As[kk][ty * 4];
            float4 b4 = *(const float4*)&Bs[kk][tx * 4];
            float a[4] = {a4.x, a4.y, a4.z, a4.w};
            float bb[4] = {b4.x, b4.y, b4.z, b4.w};
            #pragma unroll
            for (int i = 0; i < 4; i++)
                #pragma unroll
                for (int j = 0; j < 4; j++) acc[i][j] += a[i] * bb[j];
        }
        __syncthreads();
    }
    #pragma unroll
    for (int i = 0; i < 4; i++) {
        int row = m0 + ty * 4 + i;
        ushort4 o;
        o.x = f2b(acc[i][0]); o.y = f2b(acc[i][1]);
        o.z = f2b(acc[i][2]); o.w = f2b(acc[i][3]);
        *(ushort4*)&C[(size_t)row * 256 + n0 + tx * 4] = o;
    }
}

// ---------------- stage 4: W_eff[t,c,n] = sum_f offset_w[c,f]*om_w[t,f,n] -------
// output padded to n=256 (cols 216..255 = 0)
__global__ __launch_bounds__(256) void k_weff(const float* __restrict__ ow,
                                              const float* __restrict__ omw,
                                              float* __restrict__ W) {
    __shared__ float As[16][68];
    __shared__ float Bs[16][64];
    int tid = threadIdx.x;
    int t = blockIdx.z;
    int n0 = blockIdx.x * 64, m0 = blockIdx.y * 64;
    int tx = tid & 15, ty = tid >> 4;
    int am = tid >> 2, ak = (tid & 3) * 4;
    int bk = tid >> 4, bn = (tid & 15) * 4;
    float acc[4][4] = {};
    for (int k0 = 0; k0 < 512; k0 += 16) {
        int row = m0 + am, k = k0 + ak;
        float4 r = *(const float4*)(ow + (size_t)row * 512 + k);
        As[ak + 0][am] = r.x; As[ak + 1][am] = r.y;
        As[ak + 2][am] = r.z; As[ak + 3][am] = r.w;
        int n = n0 + bn;
        float w[4] = {0.f, 0.f, 0.f, 0.f};
        if (n < 216) {
            float4 ww = *(const float4*)(omw + ((size_t)t * 512 + k0 + bk) * 216 + n);
            w[0] = ww.x; w[1] = ww.y; w[2] = ww.z; w[3] = ww.w;
        }
        Bs[bk][bn + 0] = w[0]; Bs[bk][bn + 1] = w[1];
        Bs[bk][bn + 2] = w[2]; Bs[bk][bn + 3] = w[3];
        __syncthreads();
        #pragma unroll
        for (int kk = 0; kk < 16; kk++) {
            float4 a4 = *(const float4*)&As[kk][ty * 4];
            float4 b4 = *(const float4*)&Bs[kk][tx * 4];
            float a[4] = {a4.x, a4.y, a4.z, a4.w};
            float bb[4] = {b4.x, b4.y, b4.z, b4.w};
            #pragma unroll
            for (int i = 0; i < 4; i++)
                #pragma unroll
                for (int j = 0; j < 4; j++) acc[i][j] += a[i] * bb[j];
        }
        __syncthreads();
    }
    #pragma unroll
    for (int i = 0; i < 4; i++) {
        int row = m0 + ty * 4 + i;
        float4 o;
        o.x = acc[i][0]; o.y = acc[i][1]; o.z = acc[i][2]; o.w = acc[i][3];
        *(float4*)&W[((size_t)t * 512 + row) * 256 + n0 + tx * 4] = o;
    }
}

// ---------------- stage 5: om = im2col3x3(concat(fc, 2*cu)) @ W_eff + om_b ------
__global__ __launch_bounds__(256) void k_gemm2(const u16* __restrict__ fc,
                                               const u16* __restrict__ cu,
                                               const float* __restrict__ Weff,
                                               const float* __restrict__ bias,
                                               float* __restrict__ om) {
    __shared__ float As[16][68];
    __shared__ float Bs[16][64];
    int tid = threadIdx.x;
    int n0 = blockIdx.x * 64, m0 = blockIdx.y * 64;
    int tx = tid & 15, ty = tid >> 4;
    int am = tid >> 2, ak = (tid & 3) * 4;
    int bk = tid >> 4, bn = (tid & 15) * 4;
    float acc[4][4] = {};
    for (int k0 = 0; k0 < 4608; k0 += 16) {
        int row = m0 + am, k = k0 + ak;
        int t = k >> 9, cch = k & 511;
        int dy = t / 3 - 1, dx = t - (t / 3) * 3 - 1;
        int b = row >> 12, rem = row & 4095;
        int yy = (rem >> 6) + dy, xx = (rem & 63) + dx;
        float v[4] = {0.f, 0.f, 0.f, 0.f};
        if (yy >= 0 && yy < 64 && xx >= 0 && xx < 64) {
            size_t pix = (size_t)((b * 64 + yy) * 64 + xx);
            if (cch < 256) {
                ushort4 r = *(const ushort4*)(fc + pix * 256 + cch);
                v[0] = b2f(r.x); v[1] = b2f(r.y); v[2] = b2f(r.z); v[3] = b2f(r.w);
            } else {
                ushort4 r = *(const ushort4*)(cu + pix * 256 + (cch - 256));
                v[0] = 2.f * b2f(r.x); v[1] = 2.f * b2f(r.y);
                v[2] = 2.f * b2f(r.z); v[3] = 2.f * b2f(r.w);
            }
        }
        As[ak + 0][am] = v[0]; As[ak + 1][am] = v[1];
        As[ak + 2][am] = v[2]; As[ak + 3][am] = v[3];
        float4 w = *(const float4*)(Weff + (size_t)(k0 + bk) * 256 + n0 + bn);
        Bs[bk][bn + 0] = w.x; Bs[bk][bn + 1] = w.y;
        Bs[bk][bn + 2] = w.z; Bs[bk][bn + 3] = w.w;
        __syncthreads();
        #pragma unroll
        for (int kk = 0; kk < 16; kk++) {
            float4 a4 = *(const float4*)&As[kk][ty * 4];
            float4 b4 = *(const float4*)&Bs[kk][tx * 4];
            float a[4] = {a4.x, a4.y, a4.z, a4.w};
            float bb[4] = {b4.x, b4.y, b4.z, b4.w};
            #pragma unroll
            for (int i = 0; i < 4; i++)
                #pragma unroll
                for (int j = 0; j < 4; j++) acc[i][j] += a[i] * bb[j];
        }
        __syncthreads();
    }
    #pragma unroll
    for (int i = 0; i < 4; i++) {
        int row = m0 + ty * 4 + i;
        #pragma unroll
        for (int j = 0; j < 4; j++) {
            int n = n0 + tx * 4 + j;
            if (n < 216) om[(size_t)row * 216 + n] = acc[i][j] + bias[n];
        }
    }
}

// ---------------- stage 6: fused DCN sampling + matmul + epilogue ---------------
__global__ __launch_bounds__(256) void k_dcn(const u16* __restrict__ cu,
                                             const float* __restrict__ om,
                                             const float* __restrict__ Wk,
                                             const float* __restrict__ bias,
                                             const u16* __restrict__ fc,
                                             float* __restrict__ out) {
    __shared__ float offY[16][72];
    __shared__ float offX[16][72];
    __shared__ float msk[16][72];
    __shared__ float colsT[256][18];
    int tid = threadIdx.x;
    int p0 = blockIdx.x * 16;
    int b = p0 >> 12, rem = p0 & 4095;
    int y = rem >> 6, xbase = rem & 63;

    for (int j = tid; j < 16 * 72; j += 256) {
        int i = j / 72, gt = j - (j / 72) * 72;
        const float* omp = om + (size_t)(p0 + i) * 216;
        offY[i][gt] = omp[2 * gt];
        offX[i][gt] = omp[2 * gt + 1];
        msk[i][gt] = 2.0f / (1.0f + expf(-omp[144 + gt]));
    }
    __syncthreads();

    float acc[4][4] = {};
    int c = tid, g = tid >> 5;
    int tyq = tid >> 6, txf = tid & 63;
    const u16* cub = cu + (size_t)b * 4096 * 256 + c;

    for (int t = 0; t < 9; t++) {
        int dy = t / 3 - 1, dx = t - (t / 3) * 3 - 1;
        int gt = g * 9 + t;
        #pragma unroll
        for (int i = 0; i < 16; i++) {
            float py = (float)(y + dy) + offY[i][gt];
            float px = (float)(xbase + i + dx) + offX[i][gt];
            float fy = floorf(py), fx = floorf(px);
            int iy = (int)fy, ix = (int)fx;
            float wy1 = py - fy, wx1 = px - fx;
            float wy0 = 1.0f - wy1, wx0 = 1.0f - wx1;
            bool y0in = (iy >= 0) && (iy < 64);
            bool y1in = (iy >= -1) && (iy < 63);
            bool x0in = (ix >= 0) && (ix < 64);
            bool x1in = (ix >= -1) && (ix < 63);
            float v = 0.0f;
            if (y0in && x0in) v += wy0 * wx0 * b2f(cub[((size_t)iy * 64 + ix) * 256]);
            if (y0in && x1in) v += wy0 * wx1 * b2f(cub[((size_t)iy * 64 + ix + 1) * 256]);
            if (y1in && x0in) v += wy1 * wx0 * b2f(cub[((size_t)(iy + 1) * 64 + ix) * 256]);
            if (y1in && x1in) v += wy1 * wx1 * b2f(cub[((size_t)(iy + 1) * 64 + ix + 1) * 256]);
            colsT[c][i] = v * msk[i][gt];
        }
        __syncthreads();
        const float* wp = Wk + ((size_t)t * 256) * 256 + txf * 4;
        #pragma unroll 4
        for (int cc = 0; cc < 256; cc++) {
            float4 w4 = *(const float4*)(wp + (size_t)cc * 256);
            float2 a01 = *(const float2*)&colsT[cc][tyq * 4];
            float2 a23 = *(const float2*)&colsT[cc][tyq * 4 + 2];
            float a[4] = {a01.x, a01.y, a23.x, a23.y};
            #pragma unroll
            for (int ii = 0; ii < 4; ii++) {
                acc[ii][0] += a[ii] * w4.x;
                acc[ii][1] += a[ii] * w4.y;
                acc[ii][2] += a[ii] * w4.z;
                acc[ii][3] += a[ii] * w4.w;
            }
        }
        __syncthreads();
    }
    float bs[4];
    #pragma unroll
    for (int jj = 0; jj < 4; jj++) bs[jj] = bias[txf * 4 + jj];
    #pragma unroll
    for (int ii = 0; ii < 4; ii++) {
        int p = p0 + tyq * 4 + ii;
        ushort4 f4 = *(const ushort4*)(fc + (size_t)p * 256 + txf * 4);
        float4 o;
        o.x = fmaxf(acc[ii][0] + bs[0], 0.0f) + b2f(f4.x);
        o.y = fmaxf(acc[ii][1] + bs[1], 0.0f) + b2f(f4.y);
        o.z = fmaxf(acc[ii][2] + bs[2], 0.0f) + b2f(f4.z);
        o.w = fmaxf(acc[ii][3] + bs[3], 0.0f) + b2f(f4.w);
        *(float4*)&out[(size_t)p * 256 + txf * 4] = o;
    }
}

// ---------------- launch ----------------
extern "C" void kernel_launch(void* const* d_in, const int* in_sizes, int n_in,
                              void* d_out, int out_size, void* d_ws, size_t ws_size,
                              hipStream_t stream) {
    const float* fine       = (const float*)d_in[0];
    const float* coarse     = (const float*)d_in[1];
    const float* fs_attn_w  = (const float*)d_in[2];
    const float* fs_conv_w  = (const float*)d_in[3];
    const float* offset_w   = (const float*)d_in[4];
    const float* om_w       = (const float*)d_in[5];
    const float* om_b       = (const float*)d_in[6];
    const float* dcn_kernel = (const float*)d_in[7];
    const float* dcn_bias   = (const float*)d_in[8];
    float* out = (float*)d_out;

    // workspace layout (total ~35.7 MB)
    char* ws = (char*)d_ws;
    float* gap  = (float*)ws;                       // 4 KB
    float* a1   = (float*)(ws + 4096);              // 4 KB
    u16*   cu   = (u16*)(ws + 8192);                            // 8 MB (bf16)
    u16*   fc   = (u16*)(ws + 8192 + 8388608ull);               // 8 MB (bf16)
    float* Weff = (float*)(ws + 8192 + 16777216ull);            // 4.7 MB
    float* om   = (float*)(ws + 8192 + 16777216ull + 4718592ull); // 13.5 MB

    hipMemsetAsync(gap, 0, 4 * 256 * sizeof(float), stream);
    k_gap<<<dim3(32, 4), 256, 0, stream>>>(fine, gap);
    k_attn<<<4, 256, 0, stream>>>(gap, fs_attn_w, a1);
    k_upsample<<<dim3(64, 4), 256, 0, stream>>>(coarse, cu);
    k_gemm0<<<dim3(4, 256), 256, 0, stream>>>(fine, a1, fs_conv_w, fc);
    k_weff<<<dim3(4, 8, 9), 256, 0, stream>>>(offset_w, om_w, Weff);
    k_gemm2<<<dim3(4, 256), 256, 0, stream>>>(fc, cu, Weff, om_b, om);
    k_dcn<<<1024, 256, 0, stream>>>(cu, om, dcn_kernel, dcn_bias, fc, out);
}

// Round 5
// 718.864 us; speedup vs baseline: 1.5914x; 1.5914x over previous
//
#include <hip/hip_runtime.h>
#include <hip/hip_bf16.h>

using u16 = unsigned short;
typedef __attribute__((ext_vector_type(8))) short short8;
typedef __attribute__((ext_vector_type(4))) float floatx4;

__device__ __forceinline__ float b2f(u16 u) {
    union { unsigned int i; float f; } v; v.i = ((unsigned int)u) << 16; return v.f;
}
__device__ __forceinline__ u16 f2b(float f) {
    __hip_bfloat16 h = __float2bfloat16(f);
    u16 u; __builtin_memcpy(&u, &h, sizeof(u)); return u;
}

// B=4, fine 64x64x256, coarse 32x32x256, F=256, DG=8, KK=9, om ch=216
// Inputs fp32; OUTPUT fp32. Intermediates: fcu (fc|cu interleaved, bf16),
// WT (Weff transposed [n][k], bf16, x2 folded into c>=256 rows), om fp32.

// ---------------- stage 1a: global average pool (partial + atomic) --------------
__global__ __launch_bounds__(256) void k_gap(const float* __restrict__ fine,
                                             float* __restrict__ gap) {
    int b = blockIdx.y, chunk = blockIdx.x, c = threadIdx.x;
    const float* p = fine + ((size_t)b * 4096 + (size_t)chunk * 128) * 256 + c;
    float s = 0.f;
    for (int i = 0; i < 128; i++) s += p[(size_t)i * 256];
    atomicAdd(&gap[b * 256 + c], s);
}

// ---------------- stage 1b: a1 = sigmoid(gap@W / 4096) + 1 ----------------------
__global__ __launch_bounds__(256) void k_attn(const float* __restrict__ gap,
                                              const float* __restrict__ w,
                                              float* __restrict__ a1) {
    int b = blockIdx.x, d = threadIdx.x;
    float s = 0.f;
    for (int c = 0; c < 256; c++) s += gap[b * 256 + c] * w[c * 256 + d];
    s *= (1.0f / 4096.0f);
    a1[b * 256 + d] = 1.0f + 1.0f / (1.0f + expf(-s));
}

// ---------------- stage 2: bilinear 2x upsample -> fcu[pix][256+c] (bf16) -------
__global__ __launch_bounds__(256) void k_upsample(const float* __restrict__ coarse,
                                                  u16* __restrict__ fcu) {
    int y = blockIdx.x, b = blockIdx.y, c = threadIdx.x;
    float sy = fminf(fmaxf(0.5f * y - 0.25f, 0.0f), 31.0f);
    int y0 = (int)floorf(sy); float wy = sy - (float)y0; int y1 = min(y0 + 1, 31);
    const float* base = coarse + (size_t)b * 32 * 32 * 256 + c;
    u16* ob = fcu + ((size_t)b * 64 + y) * 64 * 512 + 256 + c;
    for (int x = 0; x < 64; x++) {
        float sx = fminf(fmaxf(0.5f * x - 0.25f, 0.0f), 31.0f);
        int x0 = (int)floorf(sx); float wx = sx - (float)x0; int x1 = min(x0 + 1, 31);
        float v00 = base[((size_t)y0 * 32 + x0) * 256];
        float v01 = base[((size_t)y0 * 32 + x1) * 256];
        float v10 = base[((size_t)y1 * 32 + x0) * 256];
        float v11 = base[((size_t)y1 * 32 + x1) * 256];
        ob[(size_t)x * 512] = f2b((1.f - wy) * ((1.f - wx) * v00 + wx * v01)
                                + wy * ((1.f - wx) * v10 + wx * v11));
    }
}

// ---------------- stage 3: fine_cal = (fine * a1) @ fs_conv_w -> fcu[pix][c] ----
__global__ __launch_bounds__(256) void k_gemm0(const float* __restrict__ fine,
                                               const float* __restrict__ a1,
                                               const float* __restrict__ Bw,
                                               u16* __restrict__ fcu) {
    __shared__ float As[16][68];
    __shared__ float Bs[16][64];
    int tid = threadIdx.x;
    int n0 = blockIdx.x * 64, m0 = blockIdx.y * 64;
    int tx = tid & 15, ty = tid >> 4;
    int am = tid >> 2, ak = (tid & 3) * 4;
    int bk = tid >> 4, bn = (tid & 15) * 4;
    float acc[4][4] = {};
    for (int k0 = 0; k0 < 256; k0 += 16) {
        int row = m0 + am, k = k0 + ak;
        float4 r = *(const float4*)(fine + (size_t)row * 256 + k);
        const float* ap = a1 + (row >> 12) * 256 + k;
        As[ak + 0][am] = r.x * ap[0];
        As[ak + 1][am] = r.y * ap[1];
        As[ak + 2][am] = r.z * ap[2];
        As[ak + 3][am] = r.w * ap[3];
        float4 w = *(const float4*)(Bw + (size_t)(k0 + bk) * 256 + n0 + bn);
        Bs[bk][bn + 0] = w.x; Bs[bk][bn + 1] = w.y;
        Bs[bk][bn + 2] = w.z; Bs[bk][bn + 3] = w.w;
        __syncthreads();
        #pragma unroll
        for (int kk = 0; kk < 16; kk++) {
            float4 a4 = *(const float4*)&As[kk][ty * 4];
            float4 b4 = *(const float4*)&Bs[kk][tx * 4];
            float a[4] = {a4.x, a4.y, a4.z, a4.w};
            float bb[4] = {b4.x, b4.y, b4.z, b4.w};
            #pragma unroll
            for (int i = 0; i < 4; i++)
                #pragma unroll
                for (int j = 0; j < 4; j++) acc[i][j] += a[i] * bb[j];
        }
        __syncthreads();
    }
    #pragma unroll
    for (int i = 0; i < 4; i++) {
        int row = m0 + ty * 4 + i;
        ushort4 o;
        o.x = f2b(acc[i][0]); o.y = f2b(acc[i][1]);
        o.z = f2b(acc[i][2]); o.w = f2b(acc[i][3]);
        *(ushort4*)&fcu[(size_t)row * 512 + n0 + tx * 4] = o;
    }
}

// ---------------- stage 4: WT[n][t*512+c] = bf16( scale_c * sum_f ow[c,f]*omw[t,f,n] )
// scale_c = 2 for c>=256 (folds the concat 2*coarse factor); n>=216 rows are 0.
__global__ __launch_bounds__(256) void k_weff(const float* __restrict__ ow,
                                              const float* __restrict__ omw,
                                              u16* __restrict__ WT) {
    __shared__ float As[16][68];
    __shared__ float Bs[16][64];
    int tid = threadIdx.x;
    int t = blockIdx.z;
    int n0 = blockIdx.x * 64, m0 = blockIdx.y * 64;
    int tx = tid & 15, ty = tid >> 4;
    int am = tid >> 2, ak = (tid & 3) * 4;
    int bk = tid >> 4, bn = (tid & 15) * 4;
    float acc[4][4] = {};
    for (int k0 = 0; k0 < 512; k0 += 16) {
        int row = m0 + am, k = k0 + ak;
        float4 r = *(const float4*)(ow + (size_t)row * 512 + k);
        As[ak + 0][am] = r.x; As[ak + 1][am] = r.y;
        As[ak + 2][am] = r.z; As[ak + 3][am] = r.w;
        int n = n0 + bn;
        float w[4] = {0.f, 0.f, 0.f, 0.f};
        if (n < 216) {
            float4 ww = *(const float4*)(omw + ((size_t)t * 512 + k0 + bk) * 216 + n);
            w[0] = ww.x; w[1] = ww.y; w[2] = ww.z; w[3] = ww.w;
        }
        Bs[bk][bn + 0] = w[0]; Bs[bk][bn + 1] = w[1];
        Bs[bk][bn + 2] = w[2]; Bs[bk][bn + 3] = w[3];
        __syncthreads();
        #pragma unroll
        for (int kk = 0; kk < 16; kk++) {
            float4 a4 = *(const float4*)&As[kk][ty * 4];
            float4 b4 = *(const float4*)&Bs[kk][tx * 4];
            float a[4] = {a4.x, a4.y, a4.z, a4.w};
            float bb[4] = {b4.x, b4.y, b4.z, b4.w};
            #pragma unroll
            for (int i = 0; i < 4; i++)
                #pragma unroll
                for (int j = 0; j < 4; j++) acc[i][j] += a[i] * bb[j];
        }
        __syncthreads();
    }
    #pragma unroll
    for (int i = 0; i < 4; i++) {
        int row = m0 + ty * 4 + i;         // concat channel c
        float sc = (row >= 256) ? 2.0f : 1.0f;
        #pragma unroll
        for (int j = 0; j < 4; j++) {
            int n = n0 + tx * 4 + j;
            WT[(size_t)n * 4608 + (size_t)t * 512 + row] = f2b(acc[i][j] * sc);
        }
    }
}

// ---------------- stage 5: om = im2col3x3(fcu) @ WT^T + om_b  (bf16 MFMA) -------
// block: 256 thr / 4 waves (2x2), tile 128(M)x64(N), BK=32, K=4608
__global__ __launch_bounds__(256) void k_gemm2(const u16* __restrict__ fcu,
                                               const u16* __restrict__ wt,
                                               const float* __restrict__ bias,
                                               float* __restrict__ om) {
    __shared__ u16 As[128 * 40];   // stride 40 shorts = 80B (16B-aligned rows)
    __shared__ u16 Bs[64 * 40];
    int tid = threadIdx.x;
    int n0 = blockIdx.x * 64, m0 = blockIdx.y * 128;
    int wid = tid >> 6, lane = tid & 63;
    int wm = wid >> 1, wn = wid & 1;
    int r = lane & 15, quad = lane >> 4;
    int arow = tid >> 1, ahalf = tid & 1;
    int brow = (tid & 127) >> 1, bhalf = tid & 1;
    int m = m0 + arow;
    int b = m >> 12, rem = m & 4095;
    int py = rem >> 6, px = rem & 63;

    floatx4 acc[4][2];
    #pragma unroll
    for (int i = 0; i < 4; i++)
        #pragma unroll
        for (int j = 0; j < 2; j++) acc[i][j] = (floatx4){0.f, 0.f, 0.f, 0.f};

    for (int k0 = 0; k0 < 4608; k0 += 32) {
        // ---- A staging: 128 rows x 32 k (im2col of fcu) ----
        {
            int t = k0 >> 9;
            int dy = t / 3 - 1, dx = t - (t / 3) * 3 - 1;
            int yy = py + dy, xx = px + dx;
            int cch = (k0 & 511) + ahalf * 16;
            uint4 v0 = make_uint4(0, 0, 0, 0), v1 = make_uint4(0, 0, 0, 0);
            if (yy >= 0 && yy < 64 && xx >= 0 && xx < 64) {
                const uint4* p = (const uint4*)(fcu + ((size_t)((b * 64 + yy) * 64 + xx) * 512 + cch));
                v0 = p[0]; v1 = p[1];
            }
            uint4* dst = (uint4*)&As[arow * 40 + ahalf * 16];
            dst[0] = v0; dst[1] = v1;
        }
        // ---- B staging: 64 n-rows x 32 k from WT ----
        if (tid < 128) {
            const uint4* p = (const uint4*)(wt + (size_t)(n0 + brow) * 4608 + k0 + bhalf * 16);
            uint4 v0 = p[0], v1 = p[1];
            uint4* dst = (uint4*)&Bs[brow * 40 + bhalf * 16];
            dst[0] = v0; dst[1] = v1;
        }
        __syncthreads();
        short8 a[4], bb[2];
        #pragma unroll
        for (int mt = 0; mt < 4; mt++)
            a[mt] = *(const short8*)&As[(wm * 64 + mt * 16 + r) * 40 + quad * 8];
        #pragma unroll
        for (int nt = 0; nt < 2; nt++)
            bb[nt] = *(const short8*)&Bs[(wn * 32 + nt * 16 + r) * 40 + quad * 8];
        #pragma unroll
        for (int mt = 0; mt < 4; mt++)
            #pragma unroll
            for (int nt = 0; nt < 2; nt++)
                acc[mt][nt] = __builtin_amdgcn_mfma_f32_16x16x32_bf16(a[mt], bb[nt], acc[mt][nt], 0, 0, 0);
        __syncthreads();
    }
    // ---- epilogue: C[m][n] = acc + bias, n<216 ----
    #pragma unroll
    for (int nt = 0; nt < 2; nt++) {
        int n = n0 + wn * 32 + nt * 16 + r;
        if (n < 216) {
            float bsv = bias[n];
            #pragma unroll
            for (int mt = 0; mt < 4; mt++) {
                #pragma unroll
                for (int reg = 0; reg < 4; reg++) {
                    int mm = m0 + wm * 64 + mt * 16 + quad * 4 + reg;
                    om[(size_t)mm * 216 + n] = acc[mt][nt][reg] + bsv;
                }
            }
        }
    }
}

// ---------------- stage 6: fused DCN sampling + matmul + epilogue ---------------
__global__ __launch_bounds__(256) void k_dcn(const u16* __restrict__ fcu,
                                             const float* __restrict__ om,
                                             const float* __restrict__ Wk,
                                             const float* __restrict__ bias,
                                             float* __restrict__ out) {
    __shared__ float offY[16][72];
    __shared__ float offX[16][72];
    __shared__ float msk[16][72];
    __shared__ float colsT[256][18];
    int tid = threadIdx.x;
    int p0 = blockIdx.x * 16;
    int b = p0 >> 12, rem = p0 & 4095;
    int y = rem >> 6, xbase = rem & 63;

    for (int j = tid; j < 16 * 72; j += 256) {
        int i = j / 72, gt = j - (j / 72) * 72;
        const float* omp = om + (size_t)(p0 + i) * 216;
        offY[i][gt] = omp[2 * gt];
        offX[i][gt] = omp[2 * gt + 1];
        msk[i][gt] = 2.0f / (1.0f + expf(-omp[144 + gt]));
    }
    __syncthreads();

    float acc[4][4] = {};
    int c = tid, g = tid >> 5;
    int tyq = tid >> 6, txf = tid & 63;
    const u16* cub = fcu + (size_t)b * 4096 * 512 + 256 + c;

    for (int t = 0; t < 9; t++) {
        int dy = t / 3 - 1, dx = t - (t / 3) * 3 - 1;
        int gt = g * 9 + t;
        #pragma unroll
        for (int i = 0; i < 16; i++) {
            float py = (float)(y + dy) + offY[i][gt];
            float px = (float)(xbase + i + dx) + offX[i][gt];
            float fy = floorf(py), fx = floorf(px);
            int iy = (int)fy, ix = (int)fx;
            float wy1 = py - fy, wx1 = px - fx;
            float wy0 = 1.0f - wy1, wx0 = 1.0f - wx1;
            bool y0in = (iy >= 0) && (iy < 64);
            bool y1in = (iy >= -1) && (iy < 63);
            bool x0in = (ix >= 0) && (ix < 64);
            bool x1in = (ix >= -1) && (ix < 63);
            float v = 0.0f;
            if (y0in && x0in) v += wy0 * wx0 * b2f(cub[((size_t)iy * 64 + ix) * 512]);
            if (y0in && x1in) v += wy0 * wx1 * b2f(cub[((size_t)iy * 64 + ix + 1) * 512]);
            if (y1in && x0in) v += wy1 * wx0 * b2f(cub[((size_t)(iy + 1) * 64 + ix) * 512]);
            if (y1in && x1in) v += wy1 * wx1 * b2f(cub[((size_t)(iy + 1) * 64 + ix + 1) * 512]);
            colsT[c][i] = v * msk[i][gt];
        }
        __syncthreads();
        const float* wp = Wk + ((size_t)t * 256) * 256 + txf * 4;
        #pragma unroll 4
        for (int cc = 0; cc < 256; cc++) {
            float4 w4 = *(const float4*)(wp + (size_t)cc * 256);
            float2 a01 = *(const float2*)&colsT[cc][tyq * 4];
            float2 a23 = *(const float2*)&colsT[cc][tyq * 4 + 2];
            float a[4] = {a01.x, a01.y, a23.x, a23.y};
            #pragma unroll
            for (int ii = 0; ii < 4; ii++) {
                acc[ii][0] += a[ii] * w4.x;
                acc[ii][1] += a[ii] * w4.y;
                acc[ii][2] += a[ii] * w4.z;
                acc[ii][3] += a[ii] * w4.w;
            }
        }
        __syncthreads();
    }
    float bs[4];
    #pragma unroll
    for (int jj = 0; jj < 4; jj++) bs[jj] = bias[txf * 4 + jj];
    #pragma unroll
    for (int ii = 0; ii < 4; ii++) {
        int p = p0 + tyq * 4 + ii;
        ushort4 f4 = *(const ushort4*)(fcu + (size_t)p * 512 + txf * 4);
        float4 o;
        o.x = fmaxf(acc[ii][0] + bs[0], 0.0f) + b2f(f4.x);
        o.y = fmaxf(acc[ii][1] + bs[1], 0.0f) + b2f(f4.y);
        o.z = fmaxf(acc[ii][2] + bs[2], 0.0f) + b2f(f4.z);
        o.w = fmaxf(acc[ii][3] + bs[3], 0.0f) + b2f(f4.w);
        *(float4*)&out[(size_t)p * 256 + txf * 4] = o;
    }
}

// ---------------- launch ----------------
extern "C" void kernel_launch(void* const* d_in, const int* in_sizes, int n_in,
                              void* d_out, int out_size, void* d_ws, size_t ws_size,
                              hipStream_t stream) {
    const float* fine       = (const float*)d_in[0];
    const float* coarse     = (const float*)d_in[1];
    const float* fs_attn_w  = (const float*)d_in[2];
    const float* fs_conv_w  = (const float*)d_in[3];
    const float* offset_w   = (const float*)d_in[4];
    const float* om_w       = (const float*)d_in[5];
    const float* om_b       = (const float*)d_in[6];
    const float* dcn_kernel = (const float*)d_in[7];
    const float* dcn_bias   = (const float*)d_in[8];
    float* out = (float*)d_out;

    // workspace layout (~33.3 MB)
    char* ws = (char*)d_ws;
    float* gap = (float*)ws;                              // 4 KB
    float* a1  = (float*)(ws + 4096);                     // 4 KB
    u16*   fcu = (u16*)(ws + 8192);                       // 16384*512*2 = 16.78 MB
    float* om  = (float*)(ws + 8192 + 16777216ull);       // 16384*216*4 = 14.16 MB
    u16*   wt  = (u16*)(ws + 8192 + 16777216ull + 14155776ull); // 256*4608*2 = 2.36 MB

    hipMemsetAsync(gap, 0, 4 * 256 * sizeof(float), stream);
    k_gap<<<dim3(32, 4), 256, 0, stream>>>(fine, gap);
    k_attn<<<4, 256, 0, stream>>>(gap, fs_attn_w, a1);
    k_upsample<<<dim3(64, 4), 256, 0, stream>>>(coarse, fcu);
    k_gemm0<<<dim3(4, 256), 256, 0, stream>>>(fine, a1, fs_conv_w, fcu);
    k_weff<<<dim3(4, 8, 9), 256, 0, stream>>>(offset_w, om_w, wt);
    k_gemm2<<<dim3(4, 128), 256, 0, stream>>>(fcu, wt, om_b, om);
    k_dcn<<<1024, 256, 0, stream>>>(fcu, om, dcn_kernel, dcn_bias, out);
}

// Round 6
// 406.960 us; speedup vs baseline: 2.8110x; 1.7664x over previous
//
#include <hip/hip_runtime.h>
#include <hip/hip_bf16.h>

using u16 = unsigned short;
typedef __attribute__((ext_vector_type(8))) short short8;
typedef __attribute__((ext_vector_type(4))) float floatx4;

__device__ __forceinline__ float b2f(u16 u) {
    union { unsigned int i; float f; } v; v.i = ((unsigned int)u) << 16; return v.f;
}
__device__ __forceinline__ u16 f2b(float f) {
    __hip_bfloat16 h = __float2bfloat16(f);
    u16 u; __builtin_memcpy(&u, &h, sizeof(u)); return u;
}

// B=4, fine 64x64x256, coarse 32x32x256, F=256, DG=8, KK=9, om ch=216
// Inputs fp32; OUTPUT fp32. Intermediates: fcu (fc|cu interleaved, bf16),
// WT ([n][k] bf16 for gemm2), WkT-frag (MFMA fragment order for dcn), om fp32.

// ---------------- stage 1a: global average pool (partial + atomic) --------------
__global__ __launch_bounds__(256) void k_gap(const float* __restrict__ fine,
                                             float* __restrict__ gap) {
    int b = blockIdx.y, chunk = blockIdx.x, c = threadIdx.x;
    const float* p = fine + ((size_t)b * 4096 + (size_t)chunk * 128) * 256 + c;
    float s = 0.f;
    for (int i = 0; i < 128; i++) s += p[(size_t)i * 256];
    atomicAdd(&gap[b * 256 + c], s);
}

// ---------------- stage 1b: a1 = sigmoid(gap@W / 4096) + 1 ----------------------
__global__ __launch_bounds__(256) void k_attn(const float* __restrict__ gap,
                                              const float* __restrict__ w,
                                              float* __restrict__ a1) {
    int b = blockIdx.x, d = threadIdx.x;
    float s = 0.f;
    for (int c = 0; c < 256; c++) s += gap[b * 256 + c] * w[c * 256 + d];
    s *= (1.0f / 4096.0f);
    a1[b * 256 + d] = 1.0f + 1.0f / (1.0f + expf(-s));
}

// ---------------- stage 2: bilinear 2x upsample -> fcu[pix][256+c] (bf16) -------
__global__ __launch_bounds__(256) void k_upsample(const float* __restrict__ coarse,
                                                  u16* __restrict__ fcu) {
    int y = blockIdx.x, b = blockIdx.y, c = threadIdx.x;
    float sy = fminf(fmaxf(0.5f * y - 0.25f, 0.0f), 31.0f);
    int y0 = (int)floorf(sy); float wy = sy - (float)y0; int y1 = min(y0 + 1, 31);
    const float* base = coarse + (size_t)b * 32 * 32 * 256 + c;
    u16* ob = fcu + ((size_t)b * 64 + y) * 64 * 512 + 256 + c;
    for (int x = 0; x < 64; x++) {
        float sx = fminf(fmaxf(0.5f * x - 0.25f, 0.0f), 31.0f);
        int x0 = (int)floorf(sx); float wx = sx - (float)x0; int x1 = min(x0 + 1, 31);
        float v00 = base[((size_t)y0 * 32 + x0) * 256];
        float v01 = base[((size_t)y0 * 32 + x1) * 256];
        float v10 = base[((size_t)y1 * 32 + x0) * 256];
        float v11 = base[((size_t)y1 * 32 + x1) * 256];
        ob[(size_t)x * 512] = f2b((1.f - wy) * ((1.f - wx) * v00 + wx * v01)
                                + wy * ((1.f - wx) * v10 + wx * v11));
    }
}

// ---------------- stage 3: fine_cal = (fine * a1) @ fs_conv_w -> fcu[pix][c] ----
__global__ __launch_bounds__(256) void k_gemm0(const float* __restrict__ fine,
                                               const float* __restrict__ a1,
                                               const float* __restrict__ Bw,
                                               u16* __restrict__ fcu) {
    __shared__ float As[16][68];
    __shared__ float Bs[16][64];
    int tid = threadIdx.x;
    int n0 = blockIdx.x * 64, m0 = blockIdx.y * 64;
    int tx = tid & 15, ty = tid >> 4;
    int am = tid >> 2, ak = (tid & 3) * 4;
    int bk = tid >> 4, bn = (tid & 15) * 4;
    float acc[4][4] = {};
    for (int k0 = 0; k0 < 256; k0 += 16) {
        int row = m0 + am, k = k0 + ak;
        float4 r = *(const float4*)(fine + (size_t)row * 256 + k);
        const float* ap = a1 + (row >> 12) * 256 + k;
        As[ak + 0][am] = r.x * ap[0];
        As[ak + 1][am] = r.y * ap[1];
        As[ak + 2][am] = r.z * ap[2];
        As[ak + 3][am] = r.w * ap[3];
        float4 w = *(const float4*)(Bw + (size_t)(k0 + bk) * 256 + n0 + bn);
        Bs[bk][bn + 0] = w.x; Bs[bk][bn + 1] = w.y;
        Bs[bk][bn + 2] = w.z; Bs[bk][bn + 3] = w.w;
        __syncthreads();
        #pragma unroll
        for (int kk = 0; kk < 16; kk++) {
            float4 a4 = *(const float4*)&As[kk][ty * 4];
            float4 b4 = *(const float4*)&Bs[kk][tx * 4];
            float a[4] = {a4.x, a4.y, a4.z, a4.w};
            float bb[4] = {b4.x, b4.y, b4.z, b4.w};
            #pragma unroll
            for (int i = 0; i < 4; i++)
                #pragma unroll
                for (int j = 0; j < 4; j++) acc[i][j] += a[i] * bb[j];
        }
        __syncthreads();
    }
    #pragma unroll
    for (int i = 0; i < 4; i++) {
        int row = m0 + ty * 4 + i;
        ushort4 o;
        o.x = f2b(acc[i][0]); o.y = f2b(acc[i][1]);
        o.z = f2b(acc[i][2]); o.w = f2b(acc[i][3]);
        *(ushort4*)&fcu[(size_t)row * 512 + n0 + tx * 4] = o;
    }
}

// ---------------- stage 4: WT[n][t*512+c] = bf16( scale_c * sum_f ow[c,f]*omw[t,f,n] )
__global__ __launch_bounds__(256) void k_weff(const float* __restrict__ ow,
                                              const float* __restrict__ omw,
                                              u16* __restrict__ WT) {
    __shared__ float As[16][68];
    __shared__ float Bs[16][64];
    int tid = threadIdx.x;
    int t = blockIdx.z;
    int n0 = blockIdx.x * 64, m0 = blockIdx.y * 64;
    int tx = tid & 15, ty = tid >> 4;
    int am = tid >> 2, ak = (tid & 3) * 4;
    int bk = tid >> 4, bn = (tid & 15) * 4;
    float acc[4][4] = {};
    for (int k0 = 0; k0 < 512; k0 += 16) {
        int row = m0 + am, k = k0 + ak;
        float4 r = *(const float4*)(ow + (size_t)row * 512 + k);
        As[ak + 0][am] = r.x; As[ak + 1][am] = r.y;
        As[ak + 2][am] = r.z; As[ak + 3][am] = r.w;
        int n = n0 + bn;
        float w[4] = {0.f, 0.f, 0.f, 0.f};
        if (n < 216) {
            float4 ww = *(const float4*)(omw + ((size_t)t * 512 + k0 + bk) * 216 + n);
            w[0] = ww.x; w[1] = ww.y; w[2] = ww.z; w[3] = ww.w;
        }
        Bs[bk][bn + 0] = w[0]; Bs[bk][bn + 1] = w[1];
        Bs[bk][bn + 2] = w[2]; Bs[bk][bn + 3] = w[3];
        __syncthreads();
        #pragma unroll
        for (int kk = 0; kk < 16; kk++) {
            float4 a4 = *(const float4*)&As[kk][ty * 4];
            float4 b4 = *(const float4*)&Bs[kk][tx * 4];
            float a[4] = {a4.x, a4.y, a4.z, a4.w};
            float bb[4] = {b4.x, b4.y, b4.z, b4.w};
            #pragma unroll
            for (int i = 0; i < 4; i++)
                #pragma unroll
                for (int j = 0; j < 4; j++) acc[i][j] += a[i] * bb[j];
        }
        __syncthreads();
    }
    #pragma unroll
    for (int i = 0; i < 4; i++) {
        int row = m0 + ty * 4 + i;
        float sc = (row >= 256) ? 2.0f : 1.0f;
        #pragma unroll
        for (int j = 0; j < 4; j++) {
            int n = n0 + tx * 4 + j;
            WT[(size_t)n * 4608 + (size_t)t * 512 + row] = f2b(acc[i][j] * sc);
        }
    }
}

// ---------------- stage 5: om = im2col3x3(fcu) @ WT^T + om_b  (bf16 MFMA) -------
__global__ __launch_bounds__(256) void k_gemm2(const u16* __restrict__ fcu,
                                               const u16* __restrict__ wt,
                                               const float* __restrict__ bias,
                                               float* __restrict__ om) {
    __shared__ u16 As[128 * 40];
    __shared__ u16 Bs[64 * 40];
    int tid = threadIdx.x;
    int n0 = blockIdx.x * 64, m0 = blockIdx.y * 128;
    int wid = tid >> 6, lane = tid & 63;
    int wm = wid >> 1, wn = wid & 1;
    int r = lane & 15, quad = lane >> 4;
    int arow = tid >> 1, ahalf = tid & 1;
    int brow = (tid & 127) >> 1, bhalf = tid & 1;
    int m = m0 + arow;
    int b = m >> 12, rem = m & 4095;
    int py = rem >> 6, px = rem & 63;

    floatx4 acc[4][2];
    #pragma unroll
    for (int i = 0; i < 4; i++)
        #pragma unroll
        for (int j = 0; j < 2; j++) acc[i][j] = (floatx4){0.f, 0.f, 0.f, 0.f};

    for (int k0 = 0; k0 < 4608; k0 += 32) {
        {
            int t = k0 >> 9;
            int dy = t / 3 - 1, dx = t - (t / 3) * 3 - 1;
            int yy = py + dy, xx = px + dx;
            int cch = (k0 & 511) + ahalf * 16;
            uint4 v0 = make_uint4(0, 0, 0, 0), v1 = make_uint4(0, 0, 0, 0);
            if (yy >= 0 && yy < 64 && xx >= 0 && xx < 64) {
                const uint4* p = (const uint4*)(fcu + ((size_t)((b * 64 + yy) * 64 + xx) * 512 + cch));
                v0 = p[0]; v1 = p[1];
            }
            uint4* dst = (uint4*)&As[arow * 40 + ahalf * 16];
            dst[0] = v0; dst[1] = v1;
        }
        if (tid < 128) {
            const uint4* p = (const uint4*)(wt + (size_t)(n0 + brow) * 4608 + k0 + bhalf * 16);
            uint4 v0 = p[0], v1 = p[1];
            uint4* dst = (uint4*)&Bs[brow * 40 + bhalf * 16];
            dst[0] = v0; dst[1] = v1;
        }
        __syncthreads();
        short8 a[4], bb[2];
        #pragma unroll
        for (int mt = 0; mt < 4; mt++)
            a[mt] = *(const short8*)&As[(wm * 64 + mt * 16 + r) * 40 + quad * 8];
        #pragma unroll
        for (int nt = 0; nt < 2; nt++)
            bb[nt] = *(const short8*)&Bs[(wn * 32 + nt * 16 + r) * 40 + quad * 8];
        #pragma unroll
        for (int mt = 0; mt < 4; mt++)
            #pragma unroll
            for (int nt = 0; nt < 2; nt++)
                acc[mt][nt] = __builtin_amdgcn_mfma_f32_16x16x32_bf16(a[mt], bb[nt], acc[mt][nt], 0, 0, 0);
        __syncthreads();
    }
    #pragma unroll
    for (int nt = 0; nt < 2; nt++) {
        int n = n0 + wn * 32 + nt * 16 + r;
        if (n < 216) {
            float bsv = bias[n];
            #pragma unroll
            for (int mt = 0; mt < 4; mt++) {
                #pragma unroll
                for (int reg = 0; reg < 4; reg++) {
                    int mm = m0 + wm * 64 + mt * 16 + quad * 4 + reg;
                    om[(size_t)mm * 216 + n] = acc[mt][nt][reg] + bsv;
                }
            }
        }
    }
}

// ---------------- stage 5b: dcn_kernel -> bf16 MFMA-fragment order --------------
// layout: [ksg (72)][ntile (16)][lane (64)][j (8)]; value = Wk[k][n],
// n = ntile*16 + (lane&15), k = ksg*32 + (lane>>4)*8 + j
__global__ __launch_bounds__(256) void k_wkt(const float* __restrict__ Wk,
                                             u16* __restrict__ bf) {
    int idx = blockIdx.x * 256 + threadIdx.x;   // 73728 total
    int lane = idx & 63;
    int nt = (idx >> 6) & 15;
    int ks = idx >> 10;
    int n = nt * 16 + (lane & 15);
    int k0 = ks * 32 + (lane >> 4) * 8;
    u16 tmp[8];
    #pragma unroll
    for (int j = 0; j < 8; j++) tmp[j] = f2b(Wk[(size_t)(k0 + j) * 256 + n]);
    uint4 v; __builtin_memcpy(&v, tmp, 16);
    *(uint4*)(bf + (size_t)idx * 8) = v;
}

// ---------------- stage 6: fused DCN (vector gather + bf16 MFMA) ----------------
// block = 32 pixels (half row), 256 thr / 4 waves; M=32 (2 tiles), N=256 (4/wave)
__global__ __launch_bounds__(256) void k_dcn(const u16* __restrict__ fcu,
                                             const float* __restrict__ om,
                                             const u16* __restrict__ bfr,
                                             const float* __restrict__ bias,
                                             float* __restrict__ out) {
    __shared__ u16 cols[32 * 264];  // stride 264 shorts: 16B-aligned, uniform banks
    int tid = threadIdx.x;
    int p0 = blockIdx.x * 32;
    int b = p0 >> 12;
    int y = (p0 & 4095) >> 6;
    int x0 = p0 & 63;
    int lane = tid & 63, wid = tid >> 6;
    int r = lane & 15, quad = lane >> 4;
    int sp = tid >> 3, sg = tid & 7;      // sampling: thread = (pixel, group)
    int pix = p0 + sp;
    int xs = x0 + sp;
    const u16* cub = fcu + ((size_t)b * 4096) * 512 + 256;   // cu channel base
    const float* omp = om + (size_t)pix * 216;

    floatx4 acc[2][4];
    #pragma unroll
    for (int i = 0; i < 2; i++)
        #pragma unroll
        for (int j = 0; j < 4; j++) acc[i][j] = (floatx4){0.f, 0.f, 0.f, 0.f};

    for (int t = 0; t < 9; t++) {
        int dy = t / 3 - 1, dx = t - (t / 3) * 3 - 1;
        // ---- sampling: 32 channels of group sg at pixel sp ----
        float oy = omp[sg * 18 + 2 * t];
        float ox = omp[sg * 18 + 2 * t + 1];
        float mk = 2.0f / (1.0f + expf(-omp[144 + sg * 9 + t]));
        float py = (float)(y + dy) + oy;
        float pxx = (float)(xs + dx) + ox;
        float fy = floorf(py), fx = floorf(pxx);
        int iy = (int)fy, ix = (int)fx;
        float wy1 = py - fy, wx1 = pxx - fx;
        float wy0 = 1.f - wy1, wx0 = 1.f - wx1;
        bool y0in = iy >= 0 && iy < 64;
        bool y1in = iy >= -1 && iy < 63;
        bool x0in = ix >= 0 && ix < 64;
        bool x1in = ix >= -1 && ix < 63;
        float w00 = (y0in && x0in) ? wy0 * wx0 * mk : 0.f;
        float w01 = (y0in && x1in) ? wy0 * wx1 * mk : 0.f;
        float w10 = (y1in && x0in) ? wy1 * wx0 * mk : 0.f;
        float w11 = (y1in && x1in) ? wy1 * wx1 * mk : 0.f;
        int iy0c = min(max(iy, 0), 63), iy1c = min(max(iy + 1, 0), 63);
        int ix0c = min(max(ix, 0), 63), ix1c = min(max(ix + 1, 0), 63);
        const u16* r0 = cub + (size_t)(iy0c * 64) * 512 + sg * 32;
        const u16* r1 = cub + (size_t)(iy1c * 64) * 512 + sg * 32;
        u16* dst = &cols[sp * 264 + sg * 32];
        #pragma unroll
        for (int ch = 0; ch < 4; ch++) {
            uint4 v00 = *(const uint4*)(r0 + (size_t)ix0c * 512 + ch * 8);
            uint4 v01 = *(const uint4*)(r0 + (size_t)ix1c * 512 + ch * 8);
            uint4 v10 = *(const uint4*)(r1 + (size_t)ix0c * 512 + ch * 8);
            uint4 v11 = *(const uint4*)(r1 + (size_t)ix1c * 512 + ch * 8);
            const u16* p00 = (const u16*)&v00;
            const u16* p01 = (const u16*)&v01;
            const u16* p10 = (const u16*)&v10;
            const u16* p11 = (const u16*)&v11;
            u16 o[8];
            #pragma unroll
            for (int j = 0; j < 8; j++) {
                float v = w00 * b2f(p00[j]) + w01 * b2f(p01[j])
                        + w10 * b2f(p10[j]) + w11 * b2f(p11[j]);
                o[j] = f2b(v);
            }
            uint4 ov; __builtin_memcpy(&ov, o, 16);
            *(uint4*)(dst + ch * 8) = ov;
        }
        __syncthreads();
        // ---- MFMA: 8 K-steps of 32 over this tap's 256 channels ----
        #pragma unroll
        for (int ks = 0; ks < 8; ks++) {
            short8 a0 = *(const short8*)&cols[r * 264 + ks * 32 + quad * 8];
            short8 a1v = *(const short8*)&cols[(16 + r) * 264 + ks * 32 + quad * 8];
            int ksg = t * 8 + ks;
            const u16* bp = bfr + (((size_t)ksg * 16 + wid * 4) * 64 + lane) * 8;
            short8 b0 = *(const short8*)(bp);
            short8 b1 = *(const short8*)(bp + 512);
            short8 b2 = *(const short8*)(bp + 1024);
            short8 b3 = *(const short8*)(bp + 1536);
            acc[0][0] = __builtin_amdgcn_mfma_f32_16x16x32_bf16(a0, b0, acc[0][0], 0, 0, 0);
            acc[0][1] = __builtin_amdgcn_mfma_f32_16x16x32_bf16(a0, b1, acc[0][1], 0, 0, 0);
            acc[0][2] = __builtin_amdgcn_mfma_f32_16x16x32_bf16(a0, b2, acc[0][2], 0, 0, 0);
            acc[0][3] = __builtin_amdgcn_mfma_f32_16x16x32_bf16(a0, b3, acc[0][3], 0, 0, 0);
            acc[1][0] = __builtin_amdgcn_mfma_f32_16x16x32_bf16(a1v, b0, acc[1][0], 0, 0, 0);
            acc[1][1] = __builtin_amdgcn_mfma_f32_16x16x32_bf16(a1v, b1, acc[1][1], 0, 0, 0);
            acc[1][2] = __builtin_amdgcn_mfma_f32_16x16x32_bf16(a1v, b2, acc[1][2], 0, 0, 0);
            acc[1][3] = __builtin_amdgcn_mfma_f32_16x16x32_bf16(a1v, b3, acc[1][3], 0, 0, 0);
        }
        __syncthreads();
    }
    // ---- epilogue: relu(acc+bias) + fine_cal ----
    #pragma unroll
    for (int mt = 0; mt < 2; mt++) {
        #pragma unroll
        for (int nt = 0; nt < 4; nt++) {
            int f = wid * 64 + nt * 16 + r;
            float bv = bias[f];
            #pragma unroll
            for (int reg = 0; reg < 4; reg++) {
                int pp = p0 + mt * 16 + quad * 4 + reg;
                float fcv = b2f(fcu[(size_t)pp * 512 + f]);
                out[(size_t)pp * 256 + f] = fmaxf(acc[mt][nt][reg] + bv, 0.f) + fcv;
            }
        }
    }
}

// ---------------- launch ----------------
extern "C" void kernel_launch(void* const* d_in, const int* in_sizes, int n_in,
                              void* d_out, int out_size, void* d_ws, size_t ws_size,
                              hipStream_t stream) {
    const float* fine       = (const float*)d_in[0];
    const float* coarse     = (const float*)d_in[1];
    const float* fs_attn_w  = (const float*)d_in[2];
    const float* fs_conv_w  = (const float*)d_in[3];
    const float* offset_w   = (const float*)d_in[4];
    const float* om_w       = (const float*)d_in[5];
    const float* om_b       = (const float*)d_in[6];
    const float* dcn_kernel = (const float*)d_in[7];
    const float* dcn_bias   = (const float*)d_in[8];
    float* out = (float*)d_out;

    // workspace layout (~35.7 MB)
    char* ws = (char*)d_ws;
    float* gap = (float*)ws;                              // 4 KB
    float* a1  = (float*)(ws + 4096);                     // 4 KB
    u16*   fcu = (u16*)(ws + 8192);                       // 16.78 MB
    float* om  = (float*)(ws + 8192 + 16777216ull);       // 14.16 MB
    u16*   wt  = (u16*)(ws + 8192 + 16777216ull + 14155776ull);   // 2.36 MB
    u16*   wkt = (u16*)(ws + 8192 + 16777216ull + 14155776ull + 2359296ull); // 2.36 MB

    hipMemsetAsync(gap, 0, 4 * 256 * sizeof(float), stream);
    k_gap<<<dim3(32, 4), 256, 0, stream>>>(fine, gap);
    k_attn<<<4, 256, 0, stream>>>(gap, fs_attn_w, a1);
    k_upsample<<<dim3(64, 4), 256, 0, stream>>>(coarse, fcu);
    k_gemm0<<<dim3(4, 256), 256, 0, stream>>>(fine, a1, fs_conv_w, fcu);
    k_weff<<<dim3(4, 8, 9), 256, 0, stream>>>(offset_w, om_w, wt);
    k_wkt<<<288, 256, 0, stream>>>(dcn_kernel, wkt);
    k_gemm2<<<dim3(4, 128), 256, 0, stream>>>(fcu, wt, om_b, om);
    k_dcn<<<512, 256, 0, stream>>>(fcu, om, wkt, dcn_bias, out);
}

// Round 7
// 346.460 us; speedup vs baseline: 3.3019x; 1.1746x over previous
//
#include <hip/hip_runtime.h>
#include <hip/hip_bf16.h>

using u16 = unsigned short;
typedef __attribute__((ext_vector_type(8))) short short8;
typedef __attribute__((ext_vector_type(4))) float floatx4;

__device__ __forceinline__ float b2f(u16 u) {
    union { unsigned int i; float f; } v; v.i = ((unsigned int)u) << 16; return v.f;
}
__device__ __forceinline__ u16 f2b(float f) {
    __hip_bfloat16 h = __float2bfloat16(f);
    u16 u; __builtin_memcpy(&u, &h, sizeof(u)); return u;
}

// B=4, fine 64x64x256, coarse 32x32x256, F=256, DG=8, KK=9, om ch=216
// Inputs fp32; OUTPUT fp32. fcu = concat(fine_cal, coarse_up) bf16 interleaved.
// wtf: Weff in MFMA fragment order [ksg=t*16+cq][ntile][lane][8] (x2 folded c>=256)
// wkt: dcn_kernel in same fragment order. om fp32.

// ---------------- stage 1a: global average pool (partial + atomic) --------------
__global__ __launch_bounds__(256) void k_gap(const float* __restrict__ fine,
                                             float* __restrict__ gap) {
    int b = blockIdx.y, chunk = blockIdx.x, c = threadIdx.x;
    const float* p = fine + ((size_t)b * 4096 + (size_t)chunk * 128) * 256 + c;
    float s = 0.f;
    for (int i = 0; i < 128; i++) s += p[(size_t)i * 256];
    atomicAdd(&gap[b * 256 + c], s);
}

// ---------------- stage 1b: a1 = sigmoid(gap@W / 4096) + 1 ----------------------
__global__ __launch_bounds__(256) void k_attn(const float* __restrict__ gap,
                                              const float* __restrict__ w,
                                              float* __restrict__ a1) {
    int b = blockIdx.x, d = threadIdx.x;
    float s = 0.f;
    for (int c = 0; c < 256; c++) s += gap[b * 256 + c] * w[c * 256 + d];
    s *= (1.0f / 4096.0f);
    a1[b * 256 + d] = 1.0f + 1.0f / (1.0f + expf(-s));
}

// ---------------- stage 2: bilinear 2x upsample -> fcu[pix][256+c] (bf16) -------
__global__ __launch_bounds__(256) void k_upsample(const float* __restrict__ coarse,
                                                  u16* __restrict__ fcu) {
    int y = blockIdx.x, b = blockIdx.y, c = threadIdx.x;
    float sy = fminf(fmaxf(0.5f * y - 0.25f, 0.0f), 31.0f);
    int y0 = (int)floorf(sy); float wy = sy - (float)y0; int y1 = min(y0 + 1, 31);
    const float* base = coarse + (size_t)b * 32 * 32 * 256 + c;
    u16* ob = fcu + ((size_t)b * 64 + y) * 64 * 512 + 256 + c;
    for (int x = 0; x < 64; x++) {
        float sx = fminf(fmaxf(0.5f * x - 0.25f, 0.0f), 31.0f);
        int x0 = (int)floorf(sx); float wx = sx - (float)x0; int x1 = min(x0 + 1, 31);
        float v00 = base[((size_t)y0 * 32 + x0) * 256];
        float v01 = base[((size_t)y0 * 32 + x1) * 256];
        float v10 = base[((size_t)y1 * 32 + x0) * 256];
        float v11 = base[((size_t)y1 * 32 + x1) * 256];
        ob[(size_t)x * 512] = f2b((1.f - wy) * ((1.f - wx) * v00 + wx * v01)
                                + wy * ((1.f - wx) * v10 + wx * v11));
    }
}

// ---------------- stage 3: fine_cal = (fine * a1) @ fs_conv_w -> fcu[pix][c] ----
__global__ __launch_bounds__(256) void k_gemm0(const float* __restrict__ fine,
                                               const float* __restrict__ a1,
                                               const float* __restrict__ Bw,
                                               u16* __restrict__ fcu) {
    __shared__ float As[16][68];
    __shared__ float Bs[16][64];
    int tid = threadIdx.x;
    int n0 = blockIdx.x * 64, m0 = blockIdx.y * 64;
    int tx = tid & 15, ty = tid >> 4;
    int am = tid >> 2, ak = (tid & 3) * 4;
    int bk = tid >> 4, bn = (tid & 15) * 4;
    float acc[4][4] = {};
    for (int k0 = 0; k0 < 256; k0 += 16) {
        int row = m0 + am, k = k0 + ak;
        float4 r = *(const float4*)(fine + (size_t)row * 256 + k);
        const float* ap = a1 + (row >> 12) * 256 + k;
        As[ak + 0][am] = r.x * ap[0];
        As[ak + 1][am] = r.y * ap[1];
        As[ak + 2][am] = r.z * ap[2];
        As[ak + 3][am] = r.w * ap[3];
        float4 w = *(const float4*)(Bw + (size_t)(k0 + bk) * 256 + n0 + bn);
        Bs[bk][bn + 0] = w.x; Bs[bk][bn + 1] = w.y;
        Bs[bk][bn + 2] = w.z; Bs[bk][bn + 3] = w.w;
        __syncthreads();
        #pragma unroll
        for (int kk = 0; kk < 16; kk++) {
            float4 a4 = *(const float4*)&As[kk][ty * 4];
            float4 b4 = *(const float4*)&Bs[kk][tx * 4];
            float a[4] = {a4.x, a4.y, a4.z, a4.w};
            float bb[4] = {b4.x, b4.y, b4.z, b4.w};
            #pragma unroll
            for (int i = 0; i < 4; i++)
                #pragma unroll
                for (int j = 0; j < 4; j++) acc[i][j] += a[i] * bb[j];
        }
        __syncthreads();
    }
    #pragma unroll
    for (int i = 0; i < 4; i++) {
        int row = m0 + ty * 4 + i;
        ushort4 o;
        o.x = f2b(acc[i][0]); o.y = f2b(acc[i][1]);
        o.z = f2b(acc[i][2]); o.w = f2b(acc[i][3]);
        *(ushort4*)&fcu[(size_t)row * 512 + n0 + tx * 4] = o;
    }
}

// ---------------- stage 4: Weff -> wtf (MFMA fragment order) --------------------
// wtf[ksg][ntile][lane][j]: ksg=t*16+(c>>5), lane=((c>>3)&3)*16+(n&15), j=c&7
__global__ __launch_bounds__(256) void k_weff(const float* __restrict__ ow,
                                              const float* __restrict__ omw,
                                              u16* __restrict__ wtf) {
    __shared__ float As[16][68];
    __shared__ float Bs[16][64];
    int tid = threadIdx.x;
    int t = blockIdx.z;
    int n0 = blockIdx.x * 64, m0 = blockIdx.y * 64;
    int tx = tid & 15, ty = tid >> 4;
    int am = tid >> 2, ak = (tid & 3) * 4;
    int bk = tid >> 4, bn = (tid & 15) * 4;
    float acc[4][4] = {};
    for (int k0 = 0; k0 < 512; k0 += 16) {
        int row = m0 + am, k = k0 + ak;
        float4 r = *(const float4*)(ow + (size_t)row * 512 + k);
        As[ak + 0][am] = r.x; As[ak + 1][am] = r.y;
        As[ak + 2][am] = r.z; As[ak + 3][am] = r.w;
        int n = n0 + bn;
        float w[4] = {0.f, 0.f, 0.f, 0.f};
        if (n < 216) {
            float4 ww = *(const float4*)(omw + ((size_t)t * 512 + k0 + bk) * 216 + n);
            w[0] = ww.x; w[1] = ww.y; w[2] = ww.z; w[3] = ww.w;
        }
        Bs[bk][bn + 0] = w[0]; Bs[bk][bn + 1] = w[1];
        Bs[bk][bn + 2] = w[2]; Bs[bk][bn + 3] = w[3];
        __syncthreads();
        #pragma unroll
        for (int kk = 0; kk < 16; kk++) {
            float4 a4 = *(const float4*)&As[kk][ty * 4];
            float4 b4 = *(const float4*)&Bs[kk][tx * 4];
            float a[4] = {a4.x, a4.y, a4.z, a4.w};
            float bb[4] = {b4.x, b4.y, b4.z, b4.w};
            #pragma unroll
            for (int i = 0; i < 4; i++)
                #pragma unroll
                for (int j = 0; j < 4; j++) acc[i][j] += a[i] * bb[j];
        }
        __syncthreads();
    }
    #pragma unroll
    for (int i = 0; i < 4; i++) {
        int c = m0 + ty * 4 + i;
        float sc = (c >= 256) ? 2.0f : 1.0f;
        int ksg = t * 16 + (c >> 5);
        int laneq = ((c >> 3) & 3) * 16;
        #pragma unroll
        for (int j = 0; j < 4; j++) {
            int n = n0 + tx * 4 + j;
            size_t addr = (((size_t)ksg * 16 + (n >> 4)) * 64 + laneq + (n & 15)) * 8 + (c & 7);
            wtf[addr] = f2b(acc[i][j] * sc);
        }
    }
}

// ---------------- stage 5: halo-tiled 3x3 conv: om = conv(fcu) @ Weff + b -------
// block = 4x8 pixel patch (M=32) x N=256; 256 thr / 4 waves; K = 16 chunks x 9 taps
__global__ __launch_bounds__(256) void k_conv(const u16* __restrict__ fcu,
                                              const u16* __restrict__ wtf,
                                              const float* __restrict__ bias,
                                              float* __restrict__ om) {
    __shared__ u16 halo[2][6 * 10 * 36];   // per-pixel stride 36 shorts (32ch+4 pad)
    int tid = threadIdx.x;
    int bx = blockIdx.x;
    int b = bx >> 7, tile = bx & 127;
    int ty0 = (tile >> 3) * 4, tx0 = (tile & 7) * 8;
    int lane = tid & 63, wid = tid >> 6;
    int r = lane & 15, quad = lane >> 4;

    // staging role
    int hp = tid >> 2, cq8 = tid & 3;
    int hy = hp / 10, hx = hp - hy * 10;
    int gy = ty0 - 1 + hy, gx = tx0 - 1 + hx;
    bool stg = tid < 240;
    bool inb = stg && gy >= 0 && gy < 64 && gx >= 0 && gx < 64;
    int gyc = min(max(gy, 0), 63), gxc = min(max(gx, 0), 63);
    const u16* gsrc = fcu + ((size_t)((b * 64 + gyc) * 64 + gxc)) * 512 + cq8 * 8;
    int ldst = (hy * 10 + hx) * 36 + cq8 * 8;

    floatx4 acc[2][4];
    #pragma unroll
    for (int i = 0; i < 2; i++)
        #pragma unroll
        for (int j = 0; j < 4; j++) acc[i][j] = (floatx4){0.f, 0.f, 0.f, 0.f};

    // prologue: stage chunk 0
    {
        uint4 v = make_uint4(0, 0, 0, 0);
        if (inb) v = *(const uint4*)(gsrc);
        if (stg) *(uint4*)&halo[0][ldst] = v;
    }
    __syncthreads();

    for (int cq = 0; cq < 16; cq++) {
        int cur = cq & 1;
        uint4 vn = make_uint4(0, 0, 0, 0);
        if (cq < 15 && inb) vn = *(const uint4*)(gsrc + (cq + 1) * 32);
        #pragma unroll
        for (int t = 0; t < 9; t++) {
            int dy = t / 3 - 1, dx = t - (t / 3) * 3 - 1;
            int py0 = (r >> 3) + 1 + dy, px0 = (r & 7) + 1 + dx;
            short8 a0 = *(const short8*)&halo[cur][(py0 * 10 + px0) * 36 + quad * 8];
            short8 a1 = *(const short8*)&halo[cur][((py0 + 2) * 10 + px0) * 36 + quad * 8];
            int ksg = t * 16 + cq;
            const u16* bp = wtf + (((size_t)ksg * 16 + wid * 4) * 64 + lane) * 8;
            short8 b0 = *(const short8*)(bp);
            short8 b1 = *(const short8*)(bp + 512);
            short8 b2 = *(const short8*)(bp + 1024);
            short8 b3 = *(const short8*)(bp + 1536);
            acc[0][0] = __builtin_amdgcn_mfma_f32_16x16x32_bf16(a0, b0, acc[0][0], 0, 0, 0);
            acc[0][1] = __builtin_amdgcn_mfma_f32_16x16x32_bf16(a0, b1, acc[0][1], 0, 0, 0);
            acc[0][2] = __builtin_amdgcn_mfma_f32_16x16x32_bf16(a0, b2, acc[0][2], 0, 0, 0);
            acc[0][3] = __builtin_amdgcn_mfma_f32_16x16x32_bf16(a0, b3, acc[0][3], 0, 0, 0);
            acc[1][0] = __builtin_amdgcn_mfma_f32_16x16x32_bf16(a1, b0, acc[1][0], 0, 0, 0);
            acc[1][1] = __builtin_amdgcn_mfma_f32_16x16x32_bf16(a1, b1, acc[1][1], 0, 0, 0);
            acc[1][2] = __builtin_amdgcn_mfma_f32_16x16x32_bf16(a1, b2, acc[1][2], 0, 0, 0);
            acc[1][3] = __builtin_amdgcn_mfma_f32_16x16x32_bf16(a1, b3, acc[1][3], 0, 0, 0);
        }
        if (cq < 15 && stg) *(uint4*)&halo[cur ^ 1][ldst] = vn;
        __syncthreads();
    }
    // epilogue: om[pix][n] = acc + bias   (pixel m = mt*16 + quad*4 + reg)
    #pragma unroll
    for (int nt = 0; nt < 4; nt++) {
        int n = wid * 64 + nt * 16 + r;
        if (n < 216) {
            float bv = bias[n];
            #pragma unroll
            for (int mt = 0; mt < 2; mt++) {
                #pragma unroll
                for (int reg = 0; reg < 4; reg++) {
                    int m = mt * 16 + quad * 4 + reg;
                    int gyy = ty0 + (m >> 3), gxx = tx0 + (m & 7);
                    size_t pix = (size_t)((b * 64 + gyy) * 64 + gxx);
                    om[pix * 216 + n] = acc[mt][nt][reg] + bv;
                }
            }
        }
    }
}

// ---------------- stage 5b: dcn_kernel -> bf16 MFMA-fragment order --------------
__global__ __launch_bounds__(256) void k_wkt(const float* __restrict__ Wk,
                                             u16* __restrict__ bf) {
    int idx = blockIdx.x * 256 + threadIdx.x;   // 73728 total
    int lane = idx & 63;
    int nt = (idx >> 6) & 15;
    int ks = idx >> 10;
    int n = nt * 16 + (lane & 15);
    int k0 = ks * 32 + (lane >> 4) * 8;
    u16 tmp[8];
    #pragma unroll
    for (int j = 0; j < 8; j++) tmp[j] = f2b(Wk[(size_t)(k0 + j) * 256 + n]);
    uint4 v; __builtin_memcpy(&v, tmp, 16);
    *(uint4*)(bf + (size_t)idx * 8) = v;
}

// ---------------- stage 6: fused DCN (vector gather + bf16 MFMA) ----------------
__global__ __launch_bounds__(256) void k_dcn(const u16* __restrict__ fcu,
                                             const float* __restrict__ om,
                                             const u16* __restrict__ bfr,
                                             const float* __restrict__ bias,
                                             float* __restrict__ out) {
    __shared__ u16 cols[32 * 264];
    int tid = threadIdx.x;
    int p0 = blockIdx.x * 32;
    int b = p0 >> 12;
    int y = (p0 & 4095) >> 6;
    int x0 = p0 & 63;
    int lane = tid & 63, wid = tid >> 6;
    int r = lane & 15, quad = lane >> 4;
    int sp = tid >> 3, sg = tid & 7;
    int pix = p0 + sp;
    int xs = x0 + sp;
    const u16* cub = fcu + ((size_t)b * 4096) * 512 + 256;
    const float* omp = om + (size_t)pix * 216;

    floatx4 acc[2][4];
    #pragma unroll
    for (int i = 0; i < 2; i++)
        #pragma unroll
        for (int j = 0; j < 4; j++) acc[i][j] = (floatx4){0.f, 0.f, 0.f, 0.f};

    for (int t = 0; t < 9; t++) {
        int dy = t / 3 - 1, dx = t - (t / 3) * 3 - 1;
        float oy = omp[sg * 18 + 2 * t];
        float ox = omp[sg * 18 + 2 * t + 1];
        float mk = 2.0f / (1.0f + expf(-omp[144 + sg * 9 + t]));
        float py = (float)(y + dy) + oy;
        float pxx = (float)(xs + dx) + ox;
        float fy = floorf(py), fx = floorf(pxx);
        int iy = (int)fy, ix = (int)fx;
        float wy1 = py - fy, wx1 = pxx - fx;
        float wy0 = 1.f - wy1, wx0 = 1.f - wx1;
        bool y0in = iy >= 0 && iy < 64;
        bool y1in = iy >= -1 && iy < 63;
        bool x0in = ix >= 0 && ix < 64;
        bool x1in = ix >= -1 && ix < 63;
        float w00 = (y0in && x0in) ? wy0 * wx0 * mk : 0.f;
        float w01 = (y0in && x1in) ? wy0 * wx1 * mk : 0.f;
        float w10 = (y1in && x0in) ? wy1 * wx0 * mk : 0.f;
        float w11 = (y1in && x1in) ? wy1 * wx1 * mk : 0.f;
        int iy0c = min(max(iy, 0), 63), iy1c = min(max(iy + 1, 0), 63);
        int ix0c = min(max(ix, 0), 63), ix1c = min(max(ix + 1, 0), 63);
        const u16* r0 = cub + (size_t)(iy0c * 64) * 512 + sg * 32;
        const u16* r1 = cub + (size_t)(iy1c * 64) * 512 + sg * 32;
        u16* dst = &cols[sp * 264 + sg * 32];
        #pragma unroll
        for (int ch = 0; ch < 4; ch++) {
            uint4 v00 = *(const uint4*)(r0 + (size_t)ix0c * 512 + ch * 8);
            uint4 v01 = *(const uint4*)(r0 + (size_t)ix1c * 512 + ch * 8);
            uint4 v10 = *(const uint4*)(r1 + (size_t)ix0c * 512 + ch * 8);
            uint4 v11 = *(const uint4*)(r1 + (size_t)ix1c * 512 + ch * 8);
            const u16* p00 = (const u16*)&v00;
            const u16* p01 = (const u16*)&v01;
            const u16* p10 = (const u16*)&v10;
            const u16* p11 = (const u16*)&v11;
            u16 o[8];
            #pragma unroll
            for (int j = 0; j < 8; j++) {
                float v = w00 * b2f(p00[j]) + w01 * b2f(p01[j])
                        + w10 * b2f(p10[j]) + w11 * b2f(p11[j]);
                o[j] = f2b(v);
            }
            uint4 ov; __builtin_memcpy(&ov, o, 16);
            *(uint4*)(dst + ch * 8) = ov;
        }
        __syncthreads();
        #pragma unroll
        for (int ks = 0; ks < 8; ks++) {
            short8 a0 = *(const short8*)&cols[r * 264 + ks * 32 + quad * 8];
            short8 a1v = *(const short8*)&cols[(16 + r) * 264 + ks * 32 + quad * 8];
            int ksg = t * 8 + ks;
            const u16* bp = bfr + (((size_t)ksg * 16 + wid * 4) * 64 + lane) * 8;
            short8 b0 = *(const short8*)(bp);
            short8 b1 = *(const short8*)(bp + 512);
            short8 b2 = *(const short8*)(bp + 1024);
            short8 b3 = *(const short8*)(bp + 1536);
            acc[0][0] = __builtin_amdgcn_mfma_f32_16x16x32_bf16(a0, b0, acc[0][0], 0, 0, 0);
            acc[0][1] = __builtin_amdgcn_mfma_f32_16x16x32_bf16(a0, b1, acc[0][1], 0, 0, 0);
            acc[0][2] = __builtin_amdgcn_mfma_f32_16x16x32_bf16(a0, b2, acc[0][2], 0, 0, 0);
            acc[0][3] = __builtin_amdgcn_mfma_f32_16x16x32_bf16(a0, b3, acc[0][3], 0, 0, 0);
            acc[1][0] = __builtin_amdgcn_mfma_f32_16x16x32_bf16(a1v, b0, acc[1][0], 0, 0, 0);
            acc[1][1] = __builtin_amdgcn_mfma_f32_16x16x32_bf16(a1v, b1, acc[1][1], 0, 0, 0);
            acc[1][2] = __builtin_amdgcn_mfma_f32_16x16x32_bf16(a1v, b2, acc[1][2], 0, 0, 0);
            acc[1][3] = __builtin_amdgcn_mfma_f32_16x16x32_bf16(a1v, b3, acc[1][3], 0, 0, 0);
        }
        __syncthreads();
    }
    #pragma unroll
    for (int mt = 0; mt < 2; mt++) {
        #pragma unroll
        for (int nt = 0; nt < 4; nt++) {
            int f = wid * 64 + nt * 16 + r;
            float bv = bias[f];
            #pragma unroll
            for (int reg = 0; reg < 4; reg++) {
                int pp = p0 + mt * 16 + quad * 4 + reg;
                float fcv = b2f(fcu[(size_t)pp * 512 + f]);
                out[(size_t)pp * 256 + f] = fmaxf(acc[mt][nt][reg] + bv, 0.f) + fcv;
            }
        }
    }
}

// ---------------- launch ----------------
extern "C" void kernel_launch(void* const* d_in, const int* in_sizes, int n_in,
                              void* d_out, int out_size, void* d_ws, size_t ws_size,
                              hipStream_t stream) {
    const float* fine       = (const float*)d_in[0];
    const float* coarse     = (const float*)d_in[1];
    const float* fs_attn_w  = (const float*)d_in[2];
    const float* fs_conv_w  = (const float*)d_in[3];
    const float* offset_w   = (const float*)d_in[4];
    const float* om_w       = (const float*)d_in[5];
    const float* om_b       = (const float*)d_in[6];
    const float* dcn_kernel = (const float*)d_in[7];
    const float* dcn_bias   = (const float*)d_in[8];
    float* out = (float*)d_out;

    // workspace layout (~35.7 MB)
    char* ws = (char*)d_ws;
    float* gap = (float*)ws;                              // 4 KB
    float* a1  = (float*)(ws + 4096);                     // 4 KB
    u16*   fcu = (u16*)(ws + 8192);                       // 16.78 MB
    float* om  = (float*)(ws + 8192 + 16777216ull);       // 14.16 MB
    u16*   wtf = (u16*)(ws + 8192 + 16777216ull + 14155776ull);   // 2.36 MB
    u16*   wkt = (u16*)(ws + 8192 + 16777216ull + 14155776ull + 2359296ull); // 1.18 MB

    hipMemsetAsync(gap, 0, 4 * 256 * sizeof(float), stream);
    k_gap<<<dim3(32, 4), 256, 0, stream>>>(fine, gap);
    k_attn<<<4, 256, 0, stream>>>(gap, fs_attn_w, a1);
    k_upsample<<<dim3(64, 4), 256, 0, stream>>>(coarse, fcu);
    k_gemm0<<<dim3(4, 256), 256, 0, stream>>>(fine, a1, fs_conv_w, fcu);
    k_weff<<<dim3(4, 8, 9), 256, 0, stream>>>(offset_w, om_w, wtf);
    k_wkt<<<288, 256, 0, stream>>>(dcn_kernel, wkt);
    k_conv<<<512, 256, 0, stream>>>(fcu, wtf, om_b, om);
    k_dcn<<<512, 256, 0, stream>>>(fcu, om, wkt, dcn_bias, out);
}

// Round 8
// 300.555 us; speedup vs baseline: 3.8062x; 1.1527x over previous
//
#include <hip/hip_runtime.h>
#include <hip/hip_bf16.h>

using u16 = unsigned short;
typedef __attribute__((ext_vector_type(8))) short short8;
typedef __attribute__((ext_vector_type(4))) float floatx4;

__device__ __forceinline__ float b2f(u16 u) {
    union { unsigned int i; float f; } v; v.i = ((unsigned int)u) << 16; return v.f;
}
__device__ __forceinline__ u16 f2b(float f) {
    __hip_bfloat16 h = __float2bfloat16(f);
    u16 u; __builtin_memcpy(&u, &h, sizeof(u)); return u;
}

// B=4, fine 64x64x256, coarse 32x32x256, F=256, DG=8, KK=9, om ch=216
// Inputs fp32; OUTPUT fp32. fcu = concat(fine_cal, coarse_up) bf16 interleaved.
// wtf/wkt/wb0: weights in MFMA fragment order [ksg][ntile][lane][8].
// XCD-slab swizzle: XCD (bx&7) owns global rows [xcd*32, xcd*32+32).

// ---------------- stage 1a: global average pool (partial + atomic) --------------
__global__ __launch_bounds__(256) void k_gap(const float* __restrict__ fine,
                                             float* __restrict__ gap) {
    int b = blockIdx.y, chunk = blockIdx.x, c = threadIdx.x;
    const float* p = fine + ((size_t)b * 4096 + (size_t)chunk * 128) * 256 + c;
    float s = 0.f;
    for (int i = 0; i < 128; i++) s += p[(size_t)i * 256];
    atomicAdd(&gap[b * 256 + c], s);
}

// ---------------- stage 1b: a1 = sigmoid(gap@W / 4096) + 1 ----------------------
__global__ __launch_bounds__(256) void k_attn(const float* __restrict__ gap,
                                              const float* __restrict__ w,
                                              float* __restrict__ a1) {
    int b = blockIdx.x, d = threadIdx.x;
    float s = 0.f;
    for (int c = 0; c < 256; c++) s += gap[b * 256 + c] * w[c * 256 + d];
    s *= (1.0f / 4096.0f);
    a1[b * 256 + d] = 1.0f + 1.0f / (1.0f + expf(-s));
}

// ---------------- stage 2: bilinear 2x upsample -> fcu[pix][256+c] (bf16) -------
__global__ __launch_bounds__(256) void k_upsample(const float* __restrict__ coarse,
                                                  u16* __restrict__ fcu) {
    int y = blockIdx.x, b = blockIdx.y, c = threadIdx.x;
    float sy = fminf(fmaxf(0.5f * y - 0.25f, 0.0f), 31.0f);
    int y0 = (int)floorf(sy); float wy = sy - (float)y0; int y1 = min(y0 + 1, 31);
    const float* base = coarse + (size_t)b * 32 * 32 * 256 + c;
    u16* ob = fcu + ((size_t)b * 64 + y) * 64 * 512 + 256 + c;
    for (int x = 0; x < 64; x++) {
        float sx = fminf(fmaxf(0.5f * x - 0.25f, 0.0f), 31.0f);
        int x0 = (int)floorf(sx); float wx = sx - (float)x0; int x1 = min(x0 + 1, 31);
        float v00 = base[((size_t)y0 * 32 + x0) * 256];
        float v01 = base[((size_t)y0 * 32 + x1) * 256];
        float v10 = base[((size_t)y1 * 32 + x0) * 256];
        float v11 = base[((size_t)y1 * 32 + x1) * 256];
        ob[(size_t)x * 512] = f2b((1.f - wy) * ((1.f - wx) * v00 + wx * v01)
                                + wy * ((1.f - wx) * v10 + wx * v11));
    }
}

// ---------------- stage 3a: fs_conv_w (fp32 [k][n]) -> fragment order bf16 ------
__global__ __launch_bounds__(256) void k_wb0(const float* __restrict__ Bw,
                                             u16* __restrict__ wb) {
    int idx = blockIdx.x * 256 + threadIdx.x;   // 8192 total
    int lane = idx & 63;
    int nt = (idx >> 6) & 15;
    int ks = idx >> 10;                          // 0..7
    int n = nt * 16 + (lane & 15);
    int k0 = ks * 32 + (lane >> 4) * 8;
    u16 tmp[8];
    #pragma unroll
    for (int j = 0; j < 8; j++) tmp[j] = f2b(Bw[(size_t)(k0 + j) * 256 + n]);
    uint4 v; __builtin_memcpy(&v, tmp, 16);
    *(uint4*)(wb + (size_t)idx * 8) = v;
}

// ---------------- stage 3b: fine_cal = (fine * a1) @ fs_conv_w  (bf16 MFMA) -----
// block = 32 rows x N=256; 256 thr / 4 waves
__global__ __launch_bounds__(256) void k_g0(const float* __restrict__ fine,
                                            const float* __restrict__ a1,
                                            const u16* __restrict__ wb,
                                            u16* __restrict__ fcu) {
    __shared__ u16 cols[32 * 264];
    int tid = threadIdx.x;
    int m0 = blockIdx.x * 32;
    int lane = tid & 63, wid = tid >> 6;
    int r = lane & 15, quad = lane >> 4;
    int sp = tid >> 3, coff = (tid & 7) * 32;
    int row = m0 + sp;
    int b = row >> 12;
    // stage A: 32 ch fp32 -> *a1 -> bf16 -> LDS
    {
        const float* src = fine + (size_t)row * 256 + coff;
        const float* ap = a1 + b * 256 + coff;
        u16* dst = &cols[sp * 264 + coff];
        #pragma unroll
        for (int ch = 0; ch < 4; ch++) {
            float4 v0 = *(const float4*)(src + ch * 8);
            float4 v1 = *(const float4*)(src + ch * 8 + 4);
            float4 s0 = *(const float4*)(ap + ch * 8);
            float4 s1 = *(const float4*)(ap + ch * 8 + 4);
            u16 o[8] = {f2b(v0.x * s0.x), f2b(v0.y * s0.y), f2b(v0.z * s0.z), f2b(v0.w * s0.w),
                        f2b(v1.x * s1.x), f2b(v1.y * s1.y), f2b(v1.z * s1.z), f2b(v1.w * s1.w)};
            uint4 ov; __builtin_memcpy(&ov, o, 16);
            *(uint4*)(dst + ch * 8) = ov;
        }
    }
    __syncthreads();
    floatx4 acc[2][4];
    #pragma unroll
    for (int i = 0; i < 2; i++)
        #pragma unroll
        for (int j = 0; j < 4; j++) acc[i][j] = (floatx4){0.f, 0.f, 0.f, 0.f};
    #pragma unroll
    for (int ks = 0; ks < 8; ks++) {
        short8 a0 = *(const short8*)&cols[r * 264 + ks * 32 + quad * 8];
        short8 a1v = *(const short8*)&cols[(16 + r) * 264 + ks * 32 + quad * 8];
        const u16* bp = wb + (((size_t)ks * 16 + wid * 4) * 64 + lane) * 8;
        short8 b0 = *(const short8*)(bp);
        short8 b1 = *(const short8*)(bp + 512);
        short8 b2 = *(const short8*)(bp + 1024);
        short8 b3 = *(const short8*)(bp + 1536);
        acc[0][0] = __builtin_amdgcn_mfma_f32_16x16x32_bf16(a0, b0, acc[0][0], 0, 0, 0);
        acc[0][1] = __builtin_amdgcn_mfma_f32_16x16x32_bf16(a0, b1, acc[0][1], 0, 0, 0);
        acc[0][2] = __builtin_amdgcn_mfma_f32_16x16x32_bf16(a0, b2, acc[0][2], 0, 0, 0);
        acc[0][3] = __builtin_amdgcn_mfma_f32_16x16x32_bf16(a0, b3, acc[0][3], 0, 0, 0);
        acc[1][0] = __builtin_amdgcn_mfma_f32_16x16x32_bf16(a1v, b0, acc[1][0], 0, 0, 0);
        acc[1][1] = __builtin_amdgcn_mfma_f32_16x16x32_bf16(a1v, b1, acc[1][1], 0, 0, 0);
        acc[1][2] = __builtin_amdgcn_mfma_f32_16x16x32_bf16(a1v, b2, acc[1][2], 0, 0, 0);
        acc[1][3] = __builtin_amdgcn_mfma_f32_16x16x32_bf16(a1v, b3, acc[1][3], 0, 0, 0);
    }
    #pragma unroll
    for (int mt = 0; mt < 2; mt++)
        #pragma unroll
        for (int nt = 0; nt < 4; nt++) {
            int f = wid * 64 + nt * 16 + r;
            #pragma unroll
            for (int reg = 0; reg < 4; reg++) {
                int pp = m0 + mt * 16 + quad * 4 + reg;
                fcu[(size_t)pp * 512 + f] = f2b(acc[mt][nt][reg]);
            }
        }
}

// ---------------- stage 4: Weff -> wtf (MFMA fragment order) --------------------
__global__ __launch_bounds__(256) void k_weff(const float* __restrict__ ow,
                                              const float* __restrict__ omw,
                                              u16* __restrict__ wtf) {
    __shared__ float As[16][68];
    __shared__ float Bs[16][64];
    int tid = threadIdx.x;
    int t = blockIdx.z;
    int n0 = blockIdx.x * 64, m0 = blockIdx.y * 64;
    int tx = tid & 15, ty = tid >> 4;
    int am = tid >> 2, ak = (tid & 3) * 4;
    int bk = tid >> 4, bn = (tid & 15) * 4;
    float acc[4][4] = {};
    for (int k0 = 0; k0 < 512; k0 += 16) {
        int row = m0 + am, k = k0 + ak;
        float4 r = *(const float4*)(ow + (size_t)row * 512 + k);
        As[ak + 0][am] = r.x; As[ak + 1][am] = r.y;
        As[ak + 2][am] = r.z; As[ak + 3][am] = r.w;
        int n = n0 + bn;
        float w[4] = {0.f, 0.f, 0.f, 0.f};
        if (n < 216) {
            float4 ww = *(const float4*)(omw + ((size_t)t * 512 + k0 + bk) * 216 + n);
            w[0] = ww.x; w[1] = ww.y; w[2] = ww.z; w[3] = ww.w;
        }
        Bs[bk][bn + 0] = w[0]; Bs[bk][bn + 1] = w[1];
        Bs[bk][bn + 2] = w[2]; Bs[bk][bn + 3] = w[3];
        __syncthreads();
        #pragma unroll
        for (int kk = 0; kk < 16; kk++) {
            float4 a4 = *(const float4*)&As[kk][ty * 4];
            float4 b4 = *(const float4*)&Bs[kk][tx * 4];
            float a[4] = {a4.x, a4.y, a4.z, a4.w};
            float bb[4] = {b4.x, b4.y, b4.z, b4.w};
            #pragma unroll
            for (int i = 0; i < 4; i++)
                #pragma unroll
                for (int j = 0; j < 4; j++) acc[i][j] += a[i] * bb[j];
        }
        __syncthreads();
    }
    #pragma unroll
    for (int i = 0; i < 4; i++) {
        int c = m0 + ty * 4 + i;
        float sc = (c >= 256) ? 2.0f : 1.0f;
        int ksg = t * 16 + (c >> 5);
        int laneq = ((c >> 3) & 3) * 16;
        #pragma unroll
        for (int j = 0; j < 4; j++) {
            int n = n0 + tx * 4 + j;
            size_t addr = (((size_t)ksg * 16 + (n >> 4)) * 64 + laneq + (n & 15)) * 8 + (c & 7);
            wtf[addr] = f2b(acc[i][j] * sc);
        }
    }
}

// ---------------- stage 5: halo-tiled 3x3 conv (XCD-slab swizzled) --------------
__global__ __launch_bounds__(256) void k_conv(const u16* __restrict__ fcu,
                                              const u16* __restrict__ wtf,
                                              const float* __restrict__ bias,
                                              float* __restrict__ om) {
    __shared__ u16 halo[2][6 * 10 * 36];
    int tid = threadIdx.x;
    int bx = blockIdx.x;
    int xcd = bx & 7, i5 = bx >> 3;          // slab swizzle
    int prow = xcd * 8 + (i5 >> 3);          // global patch-row 0..63
    int pcol = i5 & 7;
    int b = prow >> 4;
    int ty0 = (prow & 15) * 4, tx0 = pcol * 8;
    int lane = tid & 63, wid = tid >> 6;
    int r = lane & 15, quad = lane >> 4;

    int hp = tid >> 2, cq8 = tid & 3;
    int hy = hp / 10, hx = hp - hy * 10;
    int gy = ty0 - 1 + hy, gx = tx0 - 1 + hx;
    bool stg = tid < 240;
    bool inb = stg && gy >= 0 && gy < 64 && gx >= 0 && gx < 64;
    int gyc = min(max(gy, 0), 63), gxc = min(max(gx, 0), 63);
    const u16* gsrc = fcu + ((size_t)((b * 64 + gyc) * 64 + gxc)) * 512 + cq8 * 8;
    int ldst = (hy * 10 + hx) * 36 + cq8 * 8;

    floatx4 acc[2][4];
    #pragma unroll
    for (int i = 0; i < 2; i++)
        #pragma unroll
        for (int j = 0; j < 4; j++) acc[i][j] = (floatx4){0.f, 0.f, 0.f, 0.f};

    {
        uint4 v = make_uint4(0, 0, 0, 0);
        if (inb) v = *(const uint4*)(gsrc);
        if (stg) *(uint4*)&halo[0][ldst] = v;
    }
    __syncthreads();

    for (int cq = 0; cq < 16; cq++) {
        int cur = cq & 1;
        uint4 vn = make_uint4(0, 0, 0, 0);
        if (cq < 15 && inb) vn = *(const uint4*)(gsrc + (cq + 1) * 32);
        #pragma unroll
        for (int t = 0; t < 9; t++) {
            int dy = t / 3 - 1, dx = t - (t / 3) * 3 - 1;
            int py0 = (r >> 3) + 1 + dy, px0 = (r & 7) + 1 + dx;
            short8 a0 = *(const short8*)&halo[cur][(py0 * 10 + px0) * 36 + quad * 8];
            short8 a1 = *(const short8*)&halo[cur][((py0 + 2) * 10 + px0) * 36 + quad * 8];
            int ksg = t * 16 + cq;
            const u16* bp = wtf + (((size_t)ksg * 16 + wid * 4) * 64 + lane) * 8;
            short8 b0 = *(const short8*)(bp);
            short8 b1 = *(const short8*)(bp + 512);
            short8 b2 = *(const short8*)(bp + 1024);
            short8 b3 = *(const short8*)(bp + 1536);
            acc[0][0] = __builtin_amdgcn_mfma_f32_16x16x32_bf16(a0, b0, acc[0][0], 0, 0, 0);
            acc[0][1] = __builtin_amdgcn_mfma_f32_16x16x32_bf16(a0, b1, acc[0][1], 0, 0, 0);
            acc[0][2] = __builtin_amdgcn_mfma_f32_16x16x32_bf16(a0, b2, acc[0][2], 0, 0, 0);
            acc[0][3] = __builtin_amdgcn_mfma_f32_16x16x32_bf16(a0, b3, acc[0][3], 0, 0, 0);
            acc[1][0] = __builtin_amdgcn_mfma_f32_16x16x32_bf16(a1, b0, acc[1][0], 0, 0, 0);
            acc[1][1] = __builtin_amdgcn_mfma_f32_16x16x32_bf16(a1, b1, acc[1][1], 0, 0, 0);
            acc[1][2] = __builtin_amdgcn_mfma_f32_16x16x32_bf16(a1, b2, acc[1][2], 0, 0, 0);
            acc[1][3] = __builtin_amdgcn_mfma_f32_16x16x32_bf16(a1, b3, acc[1][3], 0, 0, 0);
        }
        if (cq < 15 && stg) *(uint4*)&halo[cur ^ 1][ldst] = vn;
        __syncthreads();
    }
    #pragma unroll
    for (int nt = 0; nt < 4; nt++) {
        int n = wid * 64 + nt * 16 + r;
        if (n < 216) {
            float bv = bias[n];
            #pragma unroll
            for (int mt = 0; mt < 2; mt++) {
                #pragma unroll
                for (int reg = 0; reg < 4; reg++) {
                    int m = mt * 16 + quad * 4 + reg;
                    int gyy = ty0 + (m >> 3), gxx = tx0 + (m & 7);
                    size_t pix = (size_t)((b * 64 + gyy) * 64 + gxx);
                    om[pix * 216 + n] = acc[mt][nt][reg] + bv;
                }
            }
        }
    }
}

// ---------------- stage 5b: dcn_kernel -> bf16 MFMA-fragment order --------------
__global__ __launch_bounds__(256) void k_wkt(const float* __restrict__ Wk,
                                             u16* __restrict__ bf) {
    int idx = blockIdx.x * 256 + threadIdx.x;   // 73728 total
    int lane = idx & 63;
    int nt = (idx >> 6) & 15;
    int ks = idx >> 10;
    int n = nt * 16 + (lane & 15);
    int k0 = ks * 32 + (lane >> 4) * 8;
    u16 tmp[8];
    #pragma unroll
    for (int j = 0; j < 8; j++) tmp[j] = f2b(Wk[(size_t)(k0 + j) * 256 + n]);
    uint4 v; __builtin_memcpy(&v, tmp, 16);
    *(uint4*)(bf + (size_t)idx * 8) = v;
}

// ---------------- stage 6: fused DCN (XCD-slab swizzled) ------------------------
__global__ __launch_bounds__(256) void k_dcn(const u16* __restrict__ fcu,
                                             const float* __restrict__ om,
                                             const u16* __restrict__ bfr,
                                             const float* __restrict__ bias,
                                             float* __restrict__ out) {
    __shared__ u16 cols[32 * 264];
    int tid = threadIdx.x;
    int bx = blockIdx.x;
    int xcd = bx & 7, i5 = bx >> 3;          // slab swizzle
    int grow = xcd * 32 + (i5 >> 1);         // global row 0..255
    int p0 = grow * 64 + (i5 & 1) * 32;
    int b = p0 >> 12;
    int y = (p0 & 4095) >> 6;
    int x0 = p0 & 63;
    int lane = tid & 63, wid = tid >> 6;
    int r = lane & 15, quad = lane >> 4;
    int sp = tid >> 3, sg = tid & 7;
    int pix = p0 + sp;
    int xs = x0 + sp;
    const u16* cub = fcu + ((size_t)b * 4096) * 512 + 256;
    const float* omp = om + (size_t)pix * 216;

    floatx4 acc[2][4];
    #pragma unroll
    for (int i = 0; i < 2; i++)
        #pragma unroll
        for (int j = 0; j < 4; j++) acc[i][j] = (floatx4){0.f, 0.f, 0.f, 0.f};

    for (int t = 0; t < 9; t++) {
        int dy = t / 3 - 1, dx = t - (t / 3) * 3 - 1;
        float oy = omp[sg * 18 + 2 * t];
        float ox = omp[sg * 18 + 2 * t + 1];
        float mk = 2.0f / (1.0f + expf(-omp[144 + sg * 9 + t]));
        float py = (float)(y + dy) + oy;
        float pxx = (float)(xs + dx) + ox;
        float fy = floorf(py), fx = floorf(pxx);
        int iy = (int)fy, ix = (int)fx;
        float wy1 = py - fy, wx1 = pxx - fx;
        float wy0 = 1.f - wy1, wx0 = 1.f - wx1;
        bool y0in = iy >= 0 && iy < 64;
        bool y1in = iy >= -1 && iy < 63;
        bool x0in = ix >= 0 && ix < 64;
        bool x1in = ix >= -1 && ix < 63;
        float w00 = (y0in && x0in) ? wy0 * wx0 * mk : 0.f;
        float w01 = (y0in && x1in) ? wy0 * wx1 * mk : 0.f;
        float w10 = (y1in && x0in) ? wy1 * wx0 * mk : 0.f;
        float w11 = (y1in && x1in) ? wy1 * wx1 * mk : 0.f;
        int iy0c = min(max(iy, 0), 63), iy1c = min(max(iy + 1, 0), 63);
        int ix0c = min(max(ix, 0), 63), ix1c = min(max(ix + 1, 0), 63);
        const u16* r0 = cub + (size_t)(iy0c * 64) * 512 + sg * 32;
        const u16* r1 = cub + (size_t)(iy1c * 64) * 512 + sg * 32;
        u16* dst = &cols[sp * 264 + sg * 32];
        #pragma unroll
        for (int ch = 0; ch < 4; ch++) {
            uint4 v00 = *(const uint4*)(r0 + (size_t)ix0c * 512 + ch * 8);
            uint4 v01 = *(const uint4*)(r0 + (size_t)ix1c * 512 + ch * 8);
            uint4 v10 = *(const uint4*)(r1 + (size_t)ix0c * 512 + ch * 8);
            uint4 v11 = *(const uint4*)(r1 + (size_t)ix1c * 512 + ch * 8);
            const u16* p00 = (const u16*)&v00;
            const u16* p01 = (const u16*)&v01;
            const u16* p10 = (const u16*)&v10;
            const u16* p11 = (const u16*)&v11;
            u16 o[8];
            #pragma unroll
            for (int j = 0; j < 8; j++) {
                float v = w00 * b2f(p00[j]) + w01 * b2f(p01[j])
                        + w10 * b2f(p10[j]) + w11 * b2f(p11[j]);
                o[j] = f2b(v);
            }
            uint4 ov; __builtin_memcpy(&ov, o, 16);
            *(uint4*)(dst + ch * 8) = ov;
        }
        __syncthreads();
        #pragma unroll
        for (int ks = 0; ks < 8; ks++) {
            short8 a0 = *(const short8*)&cols[r * 264 + ks * 32 + quad * 8];
            short8 a1v = *(const short8*)&cols[(16 + r) * 264 + ks * 32 + quad * 8];
            int ksg = t * 8 + ks;
            const u16* bp = bfr + (((size_t)ksg * 16 + wid * 4) * 64 + lane) * 8;
            short8 b0 = *(const short8*)(bp);
            short8 b1 = *(const short8*)(bp + 512);
            short8 b2 = *(const short8*)(bp + 1024);
            short8 b3 = *(const short8*)(bp + 1536);
            acc[0][0] = __builtin_amdgcn_mfma_f32_16x16x32_bf16(a0, b0, acc[0][0], 0, 0, 0);
            acc[0][1] = __builtin_amdgcn_mfma_f32_16x16x32_bf16(a0, b1, acc[0][1], 0, 0, 0);
            acc[0][2] = __builtin_amdgcn_mfma_f32_16x16x32_bf16(a0, b2, acc[0][2], 0, 0, 0);
            acc[0][3] = __builtin_amdgcn_mfma_f32_16x16x32_bf16(a0, b3, acc[0][3], 0, 0, 0);
            acc[1][0] = __builtin_amdgcn_mfma_f32_16x16x32_bf16(a1v, b0, acc[1][0], 0, 0, 0);
            acc[1][1] = __builtin_amdgcn_mfma_f32_16x16x32_bf16(a1v, b1, acc[1][1], 0, 0, 0);
            acc[1][2] = __builtin_amdgcn_mfma_f32_16x16x32_bf16(a1v, b2, acc[1][2], 0, 0, 0);
            acc[1][3] = __builtin_amdgcn_mfma_f32_16x16x32_bf16(a1v, b3, acc[1][3], 0, 0, 0);
        }
        __syncthreads();
    }
    #pragma unroll
    for (int mt = 0; mt < 2; mt++) {
        #pragma unroll
        for (int nt = 0; nt < 4; nt++) {
            int f = wid * 64 + nt * 16 + r;
            float bv = bias[f];
            #pragma unroll
            for (int reg = 0; reg < 4; reg++) {
                int pp = p0 + mt * 16 + quad * 4 + reg;
                float fcv = b2f(fcu[(size_t)pp * 512 + f]);
                out[(size_t)pp * 256 + f] = fmaxf(acc[mt][nt][reg] + bv, 0.f) + fcv;
            }
        }
    }
}

// ---------------- launch ----------------
extern "C" void kernel_launch(void* const* d_in, const int* in_sizes, int n_in,
                              void* d_out, int out_size, void* d_ws, size_t ws_size,
                              hipStream_t stream) {
    const float* fine       = (const float*)d_in[0];
    const float* coarse     = (const float*)d_in[1];
    const float* fs_attn_w  = (const float*)d_in[2];
    const float* fs_conv_w  = (const float*)d_in[3];
    const float* offset_w   = (const float*)d_in[4];
    const float* om_w       = (const float*)d_in[5];
    const float* om_b       = (const float*)d_in[6];
    const float* dcn_kernel = (const float*)d_in[7];
    const float* dcn_bias   = (const float*)d_in[8];
    float* out = (float*)d_out;

    // workspace layout (~36 MB)
    char* ws = (char*)d_ws;
    float* gap = (float*)ws;                              // 4 KB
    float* a1  = (float*)(ws + 4096);                     // 4 KB
    u16*   fcu = (u16*)(ws + 8192);                       // 16.78 MB
    float* om  = (float*)(ws + 8192 + 16777216ull);       // 14.16 MB
    u16*   wtf = (u16*)(ws + 8192 + 16777216ull + 14155776ull);   // 2.36 MB
    u16*   wkt = (u16*)(ws + 8192 + 16777216ull + 14155776ull + 2359296ull); // 1.18 MB
    u16*   wb0 = (u16*)(ws + 8192 + 16777216ull + 14155776ull + 2359296ull + 1179648ull); // 128 KB

    hipMemsetAsync(gap, 0, 4 * 256 * sizeof(float), stream);
    k_gap<<<dim3(32, 4), 256, 0, stream>>>(fine, gap);
    k_attn<<<4, 256, 0, stream>>>(gap, fs_attn_w, a1);
    k_upsample<<<dim3(64, 4), 256, 0, stream>>>(coarse, fcu);
    k_wb0<<<32, 256, 0, stream>>>(fs_conv_w, wb0);
    k_g0<<<512, 256, 0, stream>>>(fine, a1, wb0, fcu);
    k_weff<<<dim3(4, 8, 9), 256, 0, stream>>>(offset_w, om_w, wtf);
    k_wkt<<<288, 256, 0, stream>>>(dcn_kernel, wkt);
    k_conv<<<512, 256, 0, stream>>>(fcu, wtf, om_b, om);
    k_dcn<<<512, 256, 0, stream>>>(fcu, om, wkt, dcn_bias, out);
}

// Round 9
// 299.788 us; speedup vs baseline: 3.8160x; 1.0026x over previous
//
#include <hip/hip_runtime.h>
#include <hip/hip_bf16.h>

using u16 = unsigned short;
typedef __attribute__((ext_vector_type(8))) short short8;
typedef __attribute__((ext_vector_type(4))) float floatx4;

__device__ __forceinline__ float b2f(u16 u) {
    union { unsigned int i; float f; } v; v.i = ((unsigned int)u) << 16; return v.f;
}
__device__ __forceinline__ u16 f2b(float f) {
    __hip_bfloat16 h = __float2bfloat16(f);
    u16 u; __builtin_memcpy(&u, &h, sizeof(u)); return u;
}

// B=4, fine 64x64x256, coarse 32x32x256, F=256, DG=8, KK=9, om ch=216
// Inputs fp32; OUTPUT fp32. fcu = concat(fine_cal, coarse_up) bf16 interleaved.
// wtf/wkt/wb0: weights in MFMA fragment order [ksg][ntile][lane][8].
// XCD-slab swizzle: XCD (bx&7) owns a contiguous slab of global rows.

// ---------------- stage 1a: global average pool (partial + atomic) --------------
__global__ __launch_bounds__(256) void k_gap(const float* __restrict__ fine,
                                             float* __restrict__ gap) {
    int b = blockIdx.y, chunk = blockIdx.x, c = threadIdx.x;
    const float* p = fine + ((size_t)b * 4096 + (size_t)chunk * 128) * 256 + c;
    float s = 0.f;
    for (int i = 0; i < 128; i++) s += p[(size_t)i * 256];
    atomicAdd(&gap[b * 256 + c], s);
}

// ---------------- stage 1b: a1 = sigmoid(gap@W / 4096) + 1 ----------------------
__global__ __launch_bounds__(256) void k_attn(const float* __restrict__ gap,
                                              const float* __restrict__ w,
                                              float* __restrict__ a1) {
    int b = blockIdx.x, d = threadIdx.x;
    float s = 0.f;
    for (int c = 0; c < 256; c++) s += gap[b * 256 + c] * w[c * 256 + d];
    s *= (1.0f / 4096.0f);
    a1[b * 256 + d] = 1.0f + 1.0f / (1.0f + expf(-s));
}

// ---------------- stage 2: bilinear 2x upsample -> fcu[pix][256+c] (bf16) -------
__global__ __launch_bounds__(256) void k_upsample(const float* __restrict__ coarse,
                                                  u16* __restrict__ fcu) {
    int y = blockIdx.x, b = blockIdx.y, c = threadIdx.x;
    float sy = fminf(fmaxf(0.5f * y - 0.25f, 0.0f), 31.0f);
    int y0 = (int)floorf(sy); float wy = sy - (float)y0; int y1 = min(y0 + 1, 31);
    const float* base = coarse + (size_t)b * 32 * 32 * 256 + c;
    u16* ob = fcu + ((size_t)b * 64 + y) * 64 * 512 + 256 + c;
    for (int x = 0; x < 64; x++) {
        float sx = fminf(fmaxf(0.5f * x - 0.25f, 0.0f), 31.0f);
        int x0 = (int)floorf(sx); float wx = sx - (float)x0; int x1 = min(x0 + 1, 31);
        float v00 = base[((size_t)y0 * 32 + x0) * 256];
        float v01 = base[((size_t)y0 * 32 + x1) * 256];
        float v10 = base[((size_t)y1 * 32 + x0) * 256];
        float v11 = base[((size_t)y1 * 32 + x1) * 256];
        ob[(size_t)x * 512] = f2b((1.f - wy) * ((1.f - wx) * v00 + wx * v01)
                                + wy * ((1.f - wx) * v10 + wx * v11));
    }
}

// ---------------- stage 3a: fs_conv_w (fp32 [k][n]) -> fragment order bf16 ------
__global__ __launch_bounds__(256) void k_wb0(const float* __restrict__ Bw,
                                             u16* __restrict__ wb) {
    int idx = blockIdx.x * 256 + threadIdx.x;   // 8192 total
    int lane = idx & 63;
    int nt = (idx >> 6) & 15;
    int ks = idx >> 10;                          // 0..7
    int n = nt * 16 + (lane & 15);
    int k0 = ks * 32 + (lane >> 4) * 8;
    u16 tmp[8];
    #pragma unroll
    for (int j = 0; j < 8; j++) tmp[j] = f2b(Bw[(size_t)(k0 + j) * 256 + n]);
    uint4 v; __builtin_memcpy(&v, tmp, 16);
    *(uint4*)(wb + (size_t)idx * 8) = v;
}

// ---------------- stage 3b: fine_cal = (fine * a1) @ fs_conv_w  (bf16 MFMA) -----
__global__ __launch_bounds__(256) void k_g0(const float* __restrict__ fine,
                                            const float* __restrict__ a1,
                                            const u16* __restrict__ wb,
                                            u16* __restrict__ fcu) {
    __shared__ u16 cols[32 * 264];
    int tid = threadIdx.x;
    int m0 = blockIdx.x * 32;
    int lane = tid & 63, wid = tid >> 6;
    int r = lane & 15, quad = lane >> 4;
    int sp = tid >> 3, coff = (tid & 7) * 32;
    int row = m0 + sp;
    int b = row >> 12;
    {
        const float* src = fine + (size_t)row * 256 + coff;
        const float* ap = a1 + b * 256 + coff;
        u16* dst = &cols[sp * 264 + coff];
        #pragma unroll
        for (int ch = 0; ch < 4; ch++) {
            float4 v0 = *(const float4*)(src + ch * 8);
            float4 v1 = *(const float4*)(src + ch * 8 + 4);
            float4 s0 = *(const float4*)(ap + ch * 8);
            float4 s1 = *(const float4*)(ap + ch * 8 + 4);
            u16 o[8] = {f2b(v0.x * s0.x), f2b(v0.y * s0.y), f2b(v0.z * s0.z), f2b(v0.w * s0.w),
                        f2b(v1.x * s1.x), f2b(v1.y * s1.y), f2b(v1.z * s1.z), f2b(v1.w * s1.w)};
            uint4 ov; __builtin_memcpy(&ov, o, 16);
            *(uint4*)(dst + ch * 8) = ov;
        }
    }
    __syncthreads();
    floatx4 acc[2][4];
    #pragma unroll
    for (int i = 0; i < 2; i++)
        #pragma unroll
        for (int j = 0; j < 4; j++) acc[i][j] = (floatx4){0.f, 0.f, 0.f, 0.f};
    #pragma unroll
    for (int ks = 0; ks < 8; ks++) {
        short8 a0 = *(const short8*)&cols[r * 264 + ks * 32 + quad * 8];
        short8 a1v = *(const short8*)&cols[(16 + r) * 264 + ks * 32 + quad * 8];
        const u16* bp = wb + (((size_t)ks * 16 + wid * 4) * 64 + lane) * 8;
        short8 b0 = *(const short8*)(bp);
        short8 b1 = *(const short8*)(bp + 512);
        short8 b2 = *(const short8*)(bp + 1024);
        short8 b3 = *(const short8*)(bp + 1536);
        acc[0][0] = __builtin_amdgcn_mfma_f32_16x16x32_bf16(a0, b0, acc[0][0], 0, 0, 0);
        acc[0][1] = __builtin_amdgcn_mfma_f32_16x16x32_bf16(a0, b1, acc[0][1], 0, 0, 0);
        acc[0][2] = __builtin_amdgcn_mfma_f32_16x16x32_bf16(a0, b2, acc[0][2], 0, 0, 0);
        acc[0][3] = __builtin_amdgcn_mfma_f32_16x16x32_bf16(a0, b3, acc[0][3], 0, 0, 0);
        acc[1][0] = __builtin_amdgcn_mfma_f32_16x16x32_bf16(a1v, b0, acc[1][0], 0, 0, 0);
        acc[1][1] = __builtin_amdgcn_mfma_f32_16x16x32_bf16(a1v, b1, acc[1][1], 0, 0, 0);
        acc[1][2] = __builtin_amdgcn_mfma_f32_16x16x32_bf16(a1v, b2, acc[1][2], 0, 0, 0);
        acc[1][3] = __builtin_amdgcn_mfma_f32_16x16x32_bf16(a1v, b3, acc[1][3], 0, 0, 0);
    }
    #pragma unroll
    for (int mt = 0; mt < 2; mt++)
        #pragma unroll
        for (int nt = 0; nt < 4; nt++) {
            int f = wid * 64 + nt * 16 + r;
            #pragma unroll
            for (int reg = 0; reg < 4; reg++) {
                int pp = m0 + mt * 16 + quad * 4 + reg;
                fcu[(size_t)pp * 512 + f] = f2b(acc[mt][nt][reg]);
            }
        }
}

// ---------------- stage 4: Weff -> wtf (MFMA fragment order) --------------------
__global__ __launch_bounds__(256) void k_weff(const float* __restrict__ ow,
                                              const float* __restrict__ omw,
                                              u16* __restrict__ wtf) {
    __shared__ float As[16][68];
    __shared__ float Bs[16][64];
    int tid = threadIdx.x;
    int t = blockIdx.z;
    int n0 = blockIdx.x * 64, m0 = blockIdx.y * 64;
    int tx = tid & 15, ty = tid >> 4;
    int am = tid >> 2, ak = (tid & 3) * 4;
    int bk = tid >> 4, bn = (tid & 15) * 4;
    float acc[4][4] = {};
    for (int k0 = 0; k0 < 512; k0 += 16) {
        int row = m0 + am, k = k0 + ak;
        float4 r = *(const float4*)(ow + (size_t)row * 512 + k);
        As[ak + 0][am] = r.x; As[ak + 1][am] = r.y;
        As[ak + 2][am] = r.z; As[ak + 3][am] = r.w;
        int n = n0 + bn;
        float w[4] = {0.f, 0.f, 0.f, 0.f};
        if (n < 216) {
            float4 ww = *(const float4*)(omw + ((size_t)t * 512 + k0 + bk) * 216 + n);
            w[0] = ww.x; w[1] = ww.y; w[2] = ww.z; w[3] = ww.w;
        }
        Bs[bk][bn + 0] = w[0]; Bs[bk][bn + 1] = w[1];
        Bs[bk][bn + 2] = w[2]; Bs[bk][bn + 3] = w[3];
        __syncthreads();
        #pragma unroll
        for (int kk = 0; kk < 16; kk++) {
            float4 a4 = *(const float4*)&As[kk][ty * 4];
            float4 b4 = *(const float4*)&Bs[kk][tx * 4];
            float a[4] = {a4.x, a4.y, a4.z, a4.w};
            float bb[4] = {b4.x, b4.y, b4.z, b4.w};
            #pragma unroll
            for (int i = 0; i < 4; i++)
                #pragma unroll
                for (int j = 0; j < 4; j++) acc[i][j] += a[i] * bb[j];
        }
        __syncthreads();
    }
    #pragma unroll
    for (int i = 0; i < 4; i++) {
        int c = m0 + ty * 4 + i;
        float sc = (c >= 256) ? 2.0f : 1.0f;
        int ksg = t * 16 + (c >> 5);
        int laneq = ((c >> 3) & 3) * 16;
        #pragma unroll
        for (int j = 0; j < 4; j++) {
            int n = n0 + tx * 4 + j;
            size_t addr = (((size_t)ksg * 16 + (n >> 4)) * 64 + laneq + (n & 15)) * 8 + (c & 7);
            wtf[addr] = f2b(acc[i][j] * sc);
        }
    }
}

// ---------------- stage 5: halo-tiled 3x3 conv (XCD-slab swizzled) --------------
__global__ __launch_bounds__(256) void k_conv(const u16* __restrict__ fcu,
                                              const u16* __restrict__ wtf,
                                              const float* __restrict__ bias,
                                              float* __restrict__ om) {
    __shared__ u16 halo[2][6 * 10 * 36];
    int tid = threadIdx.x;
    int bx = blockIdx.x;
    int xcd = bx & 7, i5 = bx >> 3;
    int prow = xcd * 8 + (i5 >> 3);
    int pcol = i5 & 7;
    int b = prow >> 4;
    int ty0 = (prow & 15) * 4, tx0 = pcol * 8;
    int lane = tid & 63, wid = tid >> 6;
    int r = lane & 15, quad = lane >> 4;

    int hp = tid >> 2, cq8 = tid & 3;
    int hy = hp / 10, hx = hp - hy * 10;
    int gy = ty0 - 1 + hy, gx = tx0 - 1 + hx;
    bool stg = tid < 240;
    bool inb = stg && gy >= 0 && gy < 64 && gx >= 0 && gx < 64;
    int gyc = min(max(gy, 0), 63), gxc = min(max(gx, 0), 63);
    const u16* gsrc = fcu + ((size_t)((b * 64 + gyc) * 64 + gxc)) * 512 + cq8 * 8;
    int ldst = (hy * 10 + hx) * 36 + cq8 * 8;

    floatx4 acc[2][4];
    #pragma unroll
    for (int i = 0; i < 2; i++)
        #pragma unroll
        for (int j = 0; j < 4; j++) acc[i][j] = (floatx4){0.f, 0.f, 0.f, 0.f};

    {
        uint4 v = make_uint4(0, 0, 0, 0);
        if (inb) v = *(const uint4*)(gsrc);
        if (stg) *(uint4*)&halo[0][ldst] = v;
    }
    __syncthreads();

    for (int cq = 0; cq < 16; cq++) {
        int cur = cq & 1;
        uint4 vn = make_uint4(0, 0, 0, 0);
        if (cq < 15 && inb) vn = *(const uint4*)(gsrc + (cq + 1) * 32);
        #pragma unroll
        for (int t = 0; t < 9; t++) {
            int dy = t / 3 - 1, dx = t - (t / 3) * 3 - 1;
            int py0 = (r >> 3) + 1 + dy, px0 = (r & 7) + 1 + dx;
            short8 a0 = *(const short8*)&halo[cur][(py0 * 10 + px0) * 36 + quad * 8];
            short8 a1 = *(const short8*)&halo[cur][((py0 + 2) * 10 + px0) * 36 + quad * 8];
            int ksg = t * 16 + cq;
            const u16* bp = wtf + (((size_t)ksg * 16 + wid * 4) * 64 + lane) * 8;
            short8 b0 = *(const short8*)(bp);
            short8 b1 = *(const short8*)(bp + 512);
            short8 b2 = *(const short8*)(bp + 1024);
            short8 b3 = *(const short8*)(bp + 1536);
            acc[0][0] = __builtin_amdgcn_mfma_f32_16x16x32_bf16(a0, b0, acc[0][0], 0, 0, 0);
            acc[0][1] = __builtin_amdgcn_mfma_f32_16x16x32_bf16(a0, b1, acc[0][1], 0, 0, 0);
            acc[0][2] = __builtin_amdgcn_mfma_f32_16x16x32_bf16(a0, b2, acc[0][2], 0, 0, 0);
            acc[0][3] = __builtin_amdgcn_mfma_f32_16x16x32_bf16(a0, b3, acc[0][3], 0, 0, 0);
            acc[1][0] = __builtin_amdgcn_mfma_f32_16x16x32_bf16(a1, b0, acc[1][0], 0, 0, 0);
            acc[1][1] = __builtin_amdgcn_mfma_f32_16x16x32_bf16(a1, b1, acc[1][1], 0, 0, 0);
            acc[1][2] = __builtin_amdgcn_mfma_f32_16x16x32_bf16(a1, b2, acc[1][2], 0, 0, 0);
            acc[1][3] = __builtin_amdgcn_mfma_f32_16x16x32_bf16(a1, b3, acc[1][3], 0, 0, 0);
        }
        if (cq < 15 && stg) *(uint4*)&halo[cur ^ 1][ldst] = vn;
        __syncthreads();
    }
    #pragma unroll
    for (int nt = 0; nt < 4; nt++) {
        int n = wid * 64 + nt * 16 + r;
        if (n < 216) {
            float bv = bias[n];
            #pragma unroll
            for (int mt = 0; mt < 2; mt++) {
                #pragma unroll
                for (int reg = 0; reg < 4; reg++) {
                    int m = mt * 16 + quad * 4 + reg;
                    int gyy = ty0 + (m >> 3), gxx = tx0 + (m & 7);
                    size_t pix = (size_t)((b * 64 + gyy) * 64 + gxx);
                    om[pix * 216 + n] = acc[mt][nt][reg] + bv;
                }
            }
        }
    }
}

// ---------------- stage 5b: dcn_kernel -> bf16 MFMA-fragment order --------------
__global__ __launch_bounds__(256) void k_wkt(const float* __restrict__ Wk,
                                             u16* __restrict__ bf) {
    int idx = blockIdx.x * 256 + threadIdx.x;   // 73728 total
    int lane = idx & 63;
    int nt = (idx >> 6) & 15;
    int ks = idx >> 10;
    int n = nt * 16 + (lane & 15);
    int k0 = ks * 32 + (lane >> 4) * 8;
    u16 tmp[8];
    #pragma unroll
    for (int j = 0; j < 8; j++) tmp[j] = f2b(Wk[(size_t)(k0 + j) * 256 + n]);
    uint4 v; __builtin_memcpy(&v, tmp, 16);
    *(uint4*)(bf + (size_t)idx * 8) = v;
}

// ---------------- stage 6 helpers: sample issue + blend -------------------------
__device__ __forceinline__ void dcn_sample(const float* __restrict__ omp,
                                           const u16* __restrict__ cub,
                                           int y, int xs, int sg, int h, int t,
                                           uint4 v[8], float* w) {
    int dy = t / 3 - 1, dx = t - (t / 3) * 3 - 1;
    float oy = omp[sg * 18 + 2 * t];
    float ox = omp[sg * 18 + 2 * t + 1];
    float mk = 2.0f / (1.0f + expf(-omp[144 + sg * 9 + t]));
    float py = (float)(y + dy) + oy;
    float px = (float)(xs + dx) + ox;
    float fy = floorf(py), fx = floorf(px);
    int iy = (int)fy, ix = (int)fx;
    float wy1 = py - fy, wx1 = px - fx;
    float wy0 = 1.f - wy1, wx0 = 1.f - wx1;
    bool y0in = iy >= 0 && iy < 64, y1in = iy >= -1 && iy < 63;
    bool x0in = ix >= 0 && ix < 64, x1in = ix >= -1 && ix < 63;
    w[0] = (y0in && x0in) ? wy0 * wx0 * mk : 0.f;
    w[1] = (y0in && x1in) ? wy0 * wx1 * mk : 0.f;
    w[2] = (y1in && x0in) ? wy1 * wx0 * mk : 0.f;
    w[3] = (y1in && x1in) ? wy1 * wx1 * mk : 0.f;
    int iy0 = min(max(iy, 0), 63), iy1 = min(max(iy + 1, 0), 63);
    int ix0 = min(max(ix, 0), 63), ix1 = min(max(ix + 1, 0), 63);
    const u16* r0 = cub + (size_t)(iy0 * 64) * 512 + sg * 32 + h * 16;
    const u16* r1 = cub + (size_t)(iy1 * 64) * 512 + sg * 32 + h * 16;
    #pragma unroll
    for (int c = 0; c < 2; c++) {
        v[c * 4 + 0] = *(const uint4*)(r0 + (size_t)ix0 * 512 + c * 8);
        v[c * 4 + 1] = *(const uint4*)(r0 + (size_t)ix1 * 512 + c * 8);
        v[c * 4 + 2] = *(const uint4*)(r1 + (size_t)ix0 * 512 + c * 8);
        v[c * 4 + 3] = *(const uint4*)(r1 + (size_t)ix1 * 512 + c * 8);
    }
}

__device__ __forceinline__ void dcn_blend(u16* __restrict__ dst,
                                          const uint4 v[8], const float* w) {
    #pragma unroll
    for (int c = 0; c < 2; c++) {
        const u16* p00 = (const u16*)&v[c * 4 + 0];
        const u16* p01 = (const u16*)&v[c * 4 + 1];
        const u16* p10 = (const u16*)&v[c * 4 + 2];
        const u16* p11 = (const u16*)&v[c * 4 + 3];
        u16 o[8];
        #pragma unroll
        for (int j = 0; j < 8; j++) {
            float val = w[0] * b2f(p00[j]) + w[1] * b2f(p01[j])
                      + w[2] * b2f(p10[j]) + w[3] * b2f(p11[j]);
            o[j] = f2b(val);
        }
        uint4 ov; __builtin_memcpy(&ov, o, 16);
        *(uint4*)(dst + c * 8) = ov;
    }
}

// ---------------- stage 6: fused DCN, tap-pipelined, M=16, grid 1024 ------------
__global__ __launch_bounds__(256, 4) void k_dcn(const u16* __restrict__ fcu,
                                                const float* __restrict__ om,
                                                const u16* __restrict__ bfr,
                                                const float* __restrict__ bias,
                                                float* __restrict__ out) {
    __shared__ u16 cols[2][16 * 264];
    int tid = threadIdx.x;
    int bx = blockIdx.x;
    int xcd = bx & 7, i5 = bx >> 3;           // XCD slab swizzle (1024 blocks)
    int grow = xcd * 32 + (i5 >> 2);          // global row 0..255
    int p0 = grow * 64 + (i5 & 3) * 16;
    int b = p0 >> 12;
    int y = (p0 & 4095) >> 6;
    int x0 = p0 & 63;
    int lane = tid & 63, wid = tid >> 6;
    int r = lane & 15, quad = lane >> 4;
    int sp = tid >> 4, h = (tid >> 3) & 1, sg = tid & 7;
    int pix = p0 + sp;
    int xs = x0 + sp;
    const u16* cub = fcu + ((size_t)b * 4096) * 512 + 256;
    const float* omp = om + (size_t)pix * 216;
    u16* mydst = &cols[0][0] + sp * 264 + sg * 32 + h * 16;  // buffer 0 offset
    const int bufstride = 16 * 264;

    floatx4 acc[4];
    #pragma unroll
    for (int j = 0; j < 4; j++) acc[j] = (floatx4){0.f, 0.f, 0.f, 0.f};

    uint4 pv[8]; float pw[4];
    dcn_sample(omp, cub, y, xs, sg, h, 0, pv, pw);
    dcn_blend(mydst, pv, pw);
    __syncthreads();

    for (int t = 0; t < 9; t++) {
        int cur = t & 1;
        uint4 nv[8]; float nw[4];
        if (t < 8) dcn_sample(omp, cub, y, xs, sg, h, t + 1, nv, nw);
        const u16* colsb = &cols[cur][0];
        #pragma unroll
        for (int ks = 0; ks < 8; ks++) {
            short8 a0 = *(const short8*)&colsb[r * 264 + ks * 32 + quad * 8];
            int ksg = t * 8 + ks;
            const u16* bp = bfr + (((size_t)ksg * 16 + wid * 4) * 64 + lane) * 8;
            short8 b0 = *(const short8*)(bp);
            short8 b1 = *(const short8*)(bp + 512);
            short8 b2 = *(const short8*)(bp + 1024);
            short8 b3 = *(const short8*)(bp + 1536);
            acc[0] = __builtin_amdgcn_mfma_f32_16x16x32_bf16(a0, b0, acc[0], 0, 0, 0);
            acc[1] = __builtin_amdgcn_mfma_f32_16x16x32_bf16(a0, b1, acc[1], 0, 0, 0);
            acc[2] = __builtin_amdgcn_mfma_f32_16x16x32_bf16(a0, b2, acc[2], 0, 0, 0);
            acc[3] = __builtin_amdgcn_mfma_f32_16x16x32_bf16(a0, b3, acc[3], 0, 0, 0);
        }
        if (t < 8) dcn_blend(mydst + (cur ^ 1) * bufstride, nv, nw);
        __syncthreads();
    }
    #pragma unroll
    for (int nt = 0; nt < 4; nt++) {
        int f = wid * 64 + nt * 16 + r;
        float bv = bias[f];
        #pragma unroll
        for (int reg = 0; reg < 4; reg++) {
            int pp = p0 + quad * 4 + reg;
            float fcv = b2f(fcu[(size_t)pp * 512 + f]);
            out[(size_t)pp * 256 + f] = fmaxf(acc[nt][reg] + bv, 0.f) + fcv;
        }
    }
}

// ---------------- launch ----------------
extern "C" void kernel_launch(void* const* d_in, const int* in_sizes, int n_in,
                              void* d_out, int out_size, void* d_ws, size_t ws_size,
                              hipStream_t stream) {
    const float* fine       = (const float*)d_in[0];
    const float* coarse     = (const float*)d_in[1];
    const float* fs_attn_w  = (const float*)d_in[2];
    const float* fs_conv_w  = (const float*)d_in[3];
    const float* offset_w   = (const float*)d_in[4];
    const float* om_w       = (const float*)d_in[5];
    const float* om_b       = (const float*)d_in[6];
    const float* dcn_kernel = (const float*)d_in[7];
    const float* dcn_bias   = (const float*)d_in[8];
    float* out = (float*)d_out;

    // workspace layout (~36 MB)
    char* ws = (char*)d_ws;
    float* gap = (float*)ws;                              // 4 KB
    float* a1  = (float*)(ws + 4096);                     // 4 KB
    u16*   fcu = (u16*)(ws + 8192);                       // 16.78 MB
    float* om  = (float*)(ws + 8192 + 16777216ull);       // 14.16 MB
    u16*   wtf = (u16*)(ws + 8192 + 16777216ull + 14155776ull);   // 2.36 MB
    u16*   wkt = (u16*)(ws + 8192 + 16777216ull + 14155776ull + 2359296ull); // 1.18 MB
    u16*   wb0 = (u16*)(ws + 8192 + 16777216ull + 14155776ull + 2359296ull + 1179648ull); // 128 KB

    hipMemsetAsync(gap, 0, 4 * 256 * sizeof(float), stream);
    k_gap<<<dim3(32, 4), 256, 0, stream>>>(fine, gap);
    k_attn<<<4, 256, 0, stream>>>(gap, fs_attn_w, a1);
    k_upsample<<<dim3(64, 4), 256, 0, stream>>>(coarse, fcu);
    k_wb0<<<32, 256, 0, stream>>>(fs_conv_w, wb0);
    k_g0<<<512, 256, 0, stream>>>(fine, a1, wb0, fcu);
    k_weff<<<dim3(4, 8, 9), 256, 0, stream>>>(offset_w, om_w, wtf);
    k_wkt<<<288, 256, 0, stream>>>(dcn_kernel, wkt);
    k_conv<<<512, 256, 0, stream>>>(fcu, wtf, om_b, om);
    k_dcn<<<1024, 256, 0, stream>>>(fcu, om, wkt, dcn_bias, out);
}

// Round 10
// 287.574 us; speedup vs baseline: 3.9780x; 1.0425x over previous
//
#include <hip/hip_runtime.h>
#include <hip/hip_bf16.h>

using u16 = unsigned short;
typedef __attribute__((ext_vector_type(8))) short short8;
typedef __attribute__((ext_vector_type(4))) float floatx4;

__device__ __forceinline__ float b2f(u16 u) {
    union { unsigned int i; float f; } v; v.i = ((unsigned int)u) << 16; return v.f;
}
__device__ __forceinline__ u16 f2b(float f) {
    __hip_bfloat16 h = __float2bfloat16(f);
    u16 u; __builtin_memcpy(&u, &h, sizeof(u)); return u;
}

// B=4, fine 64x64x256, coarse 32x32x256, F=256, DG=8, KK=9, om ch=216
// Inputs fp32; OUTPUT fp32. fcu = concat(fine_cal, coarse_up) bf16 interleaved.
// wtf/wkt/wb0: weights in MFMA fragment order [ksg][ntile][lane][8].
// XCD-slab swizzle throughout.

// ---------------- stage 1a: global average pool (partial + atomic) --------------
__global__ __launch_bounds__(256) void k_gap(const float* __restrict__ fine,
                                             float* __restrict__ gap) {
    int b = blockIdx.y, chunk = blockIdx.x, c = threadIdx.x;
    const float* p = fine + ((size_t)b * 4096 + (size_t)chunk * 128) * 256 + c;
    float s = 0.f;
    for (int i = 0; i < 128; i++) s += p[(size_t)i * 256];
    atomicAdd(&gap[b * 256 + c], s);
}

// ---------------- stage 1b: a1 = sigmoid(gap@W / 4096) + 1 ----------------------
__global__ __launch_bounds__(256) void k_attn(const float* __restrict__ gap,
                                              const float* __restrict__ w,
                                              float* __restrict__ a1) {
    int b = blockIdx.x, d = threadIdx.x;
    float s = 0.f;
    for (int c = 0; c < 256; c++) s += gap[b * 256 + c] * w[c * 256 + d];
    s *= (1.0f / 4096.0f);
    a1[b * 256 + d] = 1.0f + 1.0f / (1.0f + expf(-s));
}

// ---------------- stage 2: bilinear 2x upsample -> fcu[pix][256+c] (bf16) -------
__global__ __launch_bounds__(256) void k_upsample(const float* __restrict__ coarse,
                                                  u16* __restrict__ fcu) {
    int y = blockIdx.x, b = blockIdx.y, c = threadIdx.x;
    float sy = fminf(fmaxf(0.5f * y - 0.25f, 0.0f), 31.0f);
    int y0 = (int)floorf(sy); float wy = sy - (float)y0; int y1 = min(y0 + 1, 31);
    const float* base = coarse + (size_t)b * 32 * 32 * 256 + c;
    u16* ob = fcu + ((size_t)b * 64 + y) * 64 * 512 + 256 + c;
    for (int x = 0; x < 64; x++) {
        float sx = fminf(fmaxf(0.5f * x - 0.25f, 0.0f), 31.0f);
        int x0 = (int)floorf(sx); float wx = sx - (float)x0; int x1 = min(x0 + 1, 31);
        float v00 = base[((size_t)y0 * 32 + x0) * 256];
        float v01 = base[((size_t)y0 * 32 + x1) * 256];
        float v10 = base[((size_t)y1 * 32 + x0) * 256];
        float v11 = base[((size_t)y1 * 32 + x1) * 256];
        ob[(size_t)x * 512] = f2b((1.f - wy) * ((1.f - wx) * v00 + wx * v01)
                                + wy * ((1.f - wx) * v10 + wx * v11));
    }
}

// ---------------- stage 3a: fs_conv_w (fp32 [k][n]) -> fragment order bf16 ------
__global__ __launch_bounds__(256) void k_wb0(const float* __restrict__ Bw,
                                             u16* __restrict__ wb) {
    int idx = blockIdx.x * 256 + threadIdx.x;   // 8192 total
    int lane = idx & 63;
    int nt = (idx >> 6) & 15;
    int ks = idx >> 10;                          // 0..7
    int n = nt * 16 + (lane & 15);
    int k0 = ks * 32 + (lane >> 4) * 8;
    u16 tmp[8];
    #pragma unroll
    for (int j = 0; j < 8; j++) tmp[j] = f2b(Bw[(size_t)(k0 + j) * 256 + n]);
    uint4 v; __builtin_memcpy(&v, tmp, 16);
    *(uint4*)(wb + (size_t)idx * 8) = v;
}

// ---------------- stage 3b: fine_cal = (fine * a1) @ fs_conv_w  (bf16 MFMA) -----
__global__ __launch_bounds__(256) void k_g0(const float* __restrict__ fine,
                                            const float* __restrict__ a1,
                                            const u16* __restrict__ wb,
                                            u16* __restrict__ fcu) {
    __shared__ u16 cols[32 * 264];
    int tid = threadIdx.x;
    int m0 = blockIdx.x * 32;
    int lane = tid & 63, wid = tid >> 6;
    int r = lane & 15, quad = lane >> 4;
    int sp = tid >> 3, coff = (tid & 7) * 32;
    int row = m0 + sp;
    int b = row >> 12;
    {
        const float* src = fine + (size_t)row * 256 + coff;
        const float* ap = a1 + b * 256 + coff;
        u16* dst = &cols[sp * 264 + coff];
        #pragma unroll
        for (int ch = 0; ch < 4; ch++) {
            float4 v0 = *(const float4*)(src + ch * 8);
            float4 v1 = *(const float4*)(src + ch * 8 + 4);
            float4 s0 = *(const float4*)(ap + ch * 8);
            float4 s1 = *(const float4*)(ap + ch * 8 + 4);
            u16 o[8] = {f2b(v0.x * s0.x), f2b(v0.y * s0.y), f2b(v0.z * s0.z), f2b(v0.w * s0.w),
                        f2b(v1.x * s1.x), f2b(v1.y * s1.y), f2b(v1.z * s1.z), f2b(v1.w * s1.w)};
            uint4 ov; __builtin_memcpy(&ov, o, 16);
            *(uint4*)(dst + ch * 8) = ov;
        }
    }
    __syncthreads();
    floatx4 acc[2][4];
    #pragma unroll
    for (int i = 0; i < 2; i++)
        #pragma unroll
        for (int j = 0; j < 4; j++) acc[i][j] = (floatx4){0.f, 0.f, 0.f, 0.f};
    #pragma unroll
    for (int ks = 0; ks < 8; ks++) {
        short8 a0 = *(const short8*)&cols[r * 264 + ks * 32 + quad * 8];
        short8 a1v = *(const short8*)&cols[(16 + r) * 264 + ks * 32 + quad * 8];
        const u16* bp = wb + (((size_t)ks * 16 + wid * 4) * 64 + lane) * 8;
        short8 b0 = *(const short8*)(bp);
        short8 b1 = *(const short8*)(bp + 512);
        short8 b2 = *(const short8*)(bp + 1024);
        short8 b3 = *(const short8*)(bp + 1536);
        acc[0][0] = __builtin_amdgcn_mfma_f32_16x16x32_bf16(a0, b0, acc[0][0], 0, 0, 0);
        acc[0][1] = __builtin_amdgcn_mfma_f32_16x16x32_bf16(a0, b1, acc[0][1], 0, 0, 0);
        acc[0][2] = __builtin_amdgcn_mfma_f32_16x16x32_bf16(a0, b2, acc[0][2], 0, 0, 0);
        acc[0][3] = __builtin_amdgcn_mfma_f32_16x16x32_bf16(a0, b3, acc[0][3], 0, 0, 0);
        acc[1][0] = __builtin_amdgcn_mfma_f32_16x16x32_bf16(a1v, b0, acc[1][0], 0, 0, 0);
        acc[1][1] = __builtin_amdgcn_mfma_f32_16x16x32_bf16(a1v, b1, acc[1][1], 0, 0, 0);
        acc[1][2] = __builtin_amdgcn_mfma_f32_16x16x32_bf16(a1v, b2, acc[1][2], 0, 0, 0);
        acc[1][3] = __builtin_amdgcn_mfma_f32_16x16x32_bf16(a1v, b3, acc[1][3], 0, 0, 0);
    }
    #pragma unroll
    for (int mt = 0; mt < 2; mt++)
        #pragma unroll
        for (int nt = 0; nt < 4; nt++) {
            int f = wid * 64 + nt * 16 + r;
            #pragma unroll
            for (int reg = 0; reg < 4; reg++) {
                int pp = m0 + mt * 16 + quad * 4 + reg;
                fcu[(size_t)pp * 512 + f] = f2b(acc[mt][nt][reg]);
            }
        }
}

// ---------------- stage 4: Weff -> wtf (MFMA fragment order) --------------------
__global__ __launch_bounds__(256) void k_weff(const float* __restrict__ ow,
                                              const float* __restrict__ omw,
                                              u16* __restrict__ wtf) {
    __shared__ float As[16][68];
    __shared__ float Bs[16][64];
    int tid = threadIdx.x;
    int t = blockIdx.z;
    int n0 = blockIdx.x * 64, m0 = blockIdx.y * 64;
    int tx = tid & 15, ty = tid >> 4;
    int am = tid >> 2, ak = (tid & 3) * 4;
    int bk = tid >> 4, bn = (tid & 15) * 4;
    float acc[4][4] = {};
    for (int k0 = 0; k0 < 512; k0 += 16) {
        int row = m0 + am, k = k0 + ak;
        float4 r = *(const float4*)(ow + (size_t)row * 512 + k);
        As[ak + 0][am] = r.x; As[ak + 1][am] = r.y;
        As[ak + 2][am] = r.z; As[ak + 3][am] = r.w;
        int n = n0 + bn;
        float w[4] = {0.f, 0.f, 0.f, 0.f};
        if (n < 216) {
            float4 ww = *(const float4*)(omw + ((size_t)t * 512 + k0 + bk) * 216 + n);
            w[0] = ww.x; w[1] = ww.y; w[2] = ww.z; w[3] = ww.w;
        }
        Bs[bk][bn + 0] = w[0]; Bs[bk][bn + 1] = w[1];
        Bs[bk][bn + 2] = w[2]; Bs[bk][bn + 3] = w[3];
        __syncthreads();
        #pragma unroll
        for (int kk = 0; kk < 16; kk++) {
            float4 a4 = *(const float4*)&As[kk][ty * 4];
            float4 b4 = *(const float4*)&Bs[kk][tx * 4];
            float a[4] = {a4.x, a4.y, a4.z, a4.w};
            float bb[4] = {b4.x, b4.y, b4.z, b4.w};
            #pragma unroll
            for (int i = 0; i < 4; i++)
                #pragma unroll
                for (int j = 0; j < 4; j++) acc[i][j] += a[i] * bb[j];
        }
        __syncthreads();
    }
    #pragma unroll
    for (int i = 0; i < 4; i++) {
        int c = m0 + ty * 4 + i;
        float sc = (c >= 256) ? 2.0f : 1.0f;
        int ksg = t * 16 + (c >> 5);
        int laneq = ((c >> 3) & 3) * 16;
        #pragma unroll
        for (int j = 0; j < 4; j++) {
            int n = n0 + tx * 4 + j;
            size_t addr = (((size_t)ksg * 16 + (n >> 4)) * 64 + laneq + (n & 15)) * 8 + (c & 7);
            wtf[addr] = f2b(acc[i][j] * sc);
        }
    }
}

// ---------------- stage 5: halo-tiled 3x3 conv, M=64 (8x8), N=128, grid 512 -----
__global__ __launch_bounds__(256, 2) void k_conv(const u16* __restrict__ fcu,
                                                 const u16* __restrict__ wtf,
                                                 const float* __restrict__ bias,
                                                 float* __restrict__ om) {
    __shared__ u16 halo[2][100 * 40];   // 10x10 halo, stride 40 shorts (80B, 16B-aligned)
    int tid = threadIdx.x;
    int bx = blockIdx.x;
    int xcd = bx & 7, i = bx >> 3;       // slab swizzle: 512 blocks
    int prow = xcd * 4 + (i >> 4);       // global patch-row 0..31
    int pcol = (i >> 1) & 7;
    int ns = i & 1;                      // N-split 0/1
    int b = prow >> 3;
    int py0 = (prow & 7) * 8, px0 = pcol * 8;
    int n0 = ns * 128;
    int lane = tid & 63, wid = tid >> 6;
    int r = lane & 15, quad = lane >> 4;

    // staging roles: j in [0,400): pix = j>>2 (0..99), q8 = j&3
    int j0 = tid, j1 = tid + 256;
    int pix0 = j0 >> 2, q80 = j0 & 3;
    int pix1 = j1 >> 2, q81 = j1 & 3;
    int hy0 = pix0 / 10, hx0 = pix0 - hy0 * 10;
    int hy1 = pix1 / 10, hx1 = pix1 - hy1 * 10;
    int gy0 = py0 - 1 + hy0, gx0 = px0 - 1 + hx0;
    int gy1 = py0 - 1 + hy1, gx1 = px0 - 1 + hx1;
    bool act1 = j1 < 400;
    bool in0 = gy0 >= 0 && gy0 < 64 && gx0 >= 0 && gx0 < 64;
    bool in1 = act1 && gy1 >= 0 && gy1 < 64 && gx1 >= 0 && gx1 < 64;
    const u16* gs0 = fcu + ((size_t)((b * 64 + min(max(gy0, 0), 63)) * 64 + min(max(gx0, 0), 63))) * 512 + q80 * 8;
    const u16* gs1 = fcu + ((size_t)((b * 64 + min(max(gy1, 0), 63)) * 64 + min(max(gx1, 0), 63))) * 512 + q81 * 8;
    int ld0 = pix0 * 40 + q80 * 8;
    int ld1 = pix1 * 40 + q81 * 8;

    floatx4 acc[4][2];
    #pragma unroll
    for (int a = 0; a < 4; a++)
        #pragma unroll
        for (int c = 0; c < 2; c++) acc[a][c] = (floatx4){0.f, 0.f, 0.f, 0.f};

    {   // prologue: stage chunk 0
        uint4 v0 = make_uint4(0, 0, 0, 0), v1 = make_uint4(0, 0, 0, 0);
        if (in0) v0 = *(const uint4*)(gs0);
        if (in1) v1 = *(const uint4*)(gs1);
        *(uint4*)&halo[0][ld0] = v0;
        if (act1) *(uint4*)&halo[0][ld1] = v1;
    }
    __syncthreads();

    for (int cq = 0; cq < 16; cq++) {
        int cur = cq & 1;
        uint4 v0 = make_uint4(0, 0, 0, 0), v1 = make_uint4(0, 0, 0, 0);
        if (cq < 15) {
            if (in0) v0 = *(const uint4*)(gs0 + (cq + 1) * 32);
            if (in1) v1 = *(const uint4*)(gs1 + (cq + 1) * 32);
        }
        const u16* hb = &halo[cur][0];
        #pragma unroll
        for (int t = 0; t < 9; t++) {
            int dy = t / 3 - 1, dx = t - (t / 3) * 3 - 1;
            int ksg = t * 16 + cq;
            const u16* bp = wtf + (((size_t)ksg * 16 + ns * 8 + wid * 2) * 64 + lane) * 8;
            short8 b0 = *(const short8*)(bp);
            short8 b1 = *(const short8*)(bp + 512);
            short8 a[4];
            #pragma unroll
            for (int mt = 0; mt < 4; mt++) {
                int m = mt * 16 + r;
                int hy = (m >> 3) + 1 + dy, hx = (m & 7) + 1 + dx;
                a[mt] = *(const short8*)&hb[(hy * 10 + hx) * 40 + quad * 8];
            }
            #pragma unroll
            for (int mt = 0; mt < 4; mt++) {
                acc[mt][0] = __builtin_amdgcn_mfma_f32_16x16x32_bf16(a[mt], b0, acc[mt][0], 0, 0, 0);
                acc[mt][1] = __builtin_amdgcn_mfma_f32_16x16x32_bf16(a[mt], b1, acc[mt][1], 0, 0, 0);
            }
        }
        if (cq < 15) {
            *(uint4*)&halo[cur ^ 1][ld0] = v0;
            if (act1) *(uint4*)&halo[cur ^ 1][ld1] = v1;
        }
        __syncthreads();
    }
    // epilogue
    #pragma unroll
    for (int nt = 0; nt < 2; nt++) {
        int n = n0 + wid * 32 + nt * 16 + r;
        if (n < 216) {
            float bv = bias[n];
            #pragma unroll
            for (int mt = 0; mt < 4; mt++) {
                #pragma unroll
                for (int reg = 0; reg < 4; reg++) {
                    int m = mt * 16 + quad * 4 + reg;
                    int gyy = py0 + (m >> 3), gxx = px0 + (m & 7);
                    size_t pix = (size_t)((b * 64 + gyy) * 64 + gxx);
                    om[pix * 216 + n] = acc[mt][nt][reg] + bv;
                }
            }
        }
    }
}

// ---------------- stage 5b: dcn_kernel -> bf16 MFMA-fragment order --------------
__global__ __launch_bounds__(256) void k_wkt(const float* __restrict__ Wk,
                                             u16* __restrict__ bf) {
    int idx = blockIdx.x * 256 + threadIdx.x;   // 73728 total
    int lane = idx & 63;
    int nt = (idx >> 6) & 15;
    int ks = idx >> 10;
    int n = nt * 16 + (lane & 15);
    int k0 = ks * 32 + (lane >> 4) * 8;
    u16 tmp[8];
    #pragma unroll
    for (int j = 0; j < 8; j++) tmp[j] = f2b(Wk[(size_t)(k0 + j) * 256 + n]);
    uint4 v; __builtin_memcpy(&v, tmp, 16);
    *(uint4*)(bf + (size_t)idx * 8) = v;
}

// ---------------- stage 6 helpers -----------------------------------------------
struct Smp { uint4 g[4][4]; float w[4]; };

__device__ __forceinline__ void dcn_issue(Smp& s, const u16* __restrict__ cub,
                                          int y, int xs, int sg, int t,
                                          float oy, float ox, float mlog) {
    int dy = t / 3 - 1, dx = t - (t / 3) * 3 - 1;
    float mk = 2.0f / (1.0f + expf(-mlog));
    float py = (float)(y + dy) + oy;
    float px = (float)(xs + dx) + ox;
    float fy = floorf(py), fx = floorf(px);
    int iy = (int)fy, ix = (int)fx;
    float wy1 = py - fy, wx1 = px - fx;
    float wy0 = 1.f - wy1, wx0 = 1.f - wx1;
    bool y0in = iy >= 0 && iy < 64, y1in = iy >= -1 && iy < 63;
    bool x0in = ix >= 0 && ix < 64, x1in = ix >= -1 && ix < 63;
    s.w[0] = (y0in && x0in) ? wy0 * wx0 * mk : 0.f;
    s.w[1] = (y0in && x1in) ? wy0 * wx1 * mk : 0.f;
    s.w[2] = (y1in && x0in) ? wy1 * wx0 * mk : 0.f;
    s.w[3] = (y1in && x1in) ? wy1 * wx1 * mk : 0.f;
    int iy0 = min(max(iy, 0), 63), iy1 = min(max(iy + 1, 0), 63);
    int ix0 = min(max(ix, 0), 63), ix1 = min(max(ix + 1, 0), 63);
    const u16* p00 = cub + (size_t)(iy0 * 64 + ix0) * 512 + sg * 32;
    const u16* p01 = cub + (size_t)(iy0 * 64 + ix1) * 512 + sg * 32;
    const u16* p10 = cub + (size_t)(iy1 * 64 + ix0) * 512 + sg * 32;
    const u16* p11 = cub + (size_t)(iy1 * 64 + ix1) * 512 + sg * 32;
    #pragma unroll
    for (int k = 0; k < 4; k++) {
        s.g[0][k] = *(const uint4*)(p00 + k * 8);
        s.g[1][k] = *(const uint4*)(p01 + k * 8);
        s.g[2][k] = *(const uint4*)(p10 + k * 8);
        s.g[3][k] = *(const uint4*)(p11 + k * 8);
    }
}

__device__ __forceinline__ void dcn_blend(const Smp& s, u16* __restrict__ dst) {
    #pragma unroll
    for (int k = 0; k < 4; k++) {
        const u16* p00 = (const u16*)&s.g[0][k];
        const u16* p01 = (const u16*)&s.g[1][k];
        const u16* p10 = (const u16*)&s.g[2][k];
        const u16* p11 = (const u16*)&s.g[3][k];
        u16 o[8];
        #pragma unroll
        for (int j = 0; j < 8; j++) {
            float v = s.w[0] * b2f(p00[j]) + s.w[1] * b2f(p01[j])
                    + s.w[2] * b2f(p10[j]) + s.w[3] * b2f(p11[j]);
            o[j] = f2b(v);
        }
        uint4 ov; __builtin_memcpy(&ov, o, 16);
        *(uint4*)(dst + k * 8) = ov;
    }
}

// ---------------- stage 6: fused DCN, M=32, 3-tap K-groups, grid 512 ------------
__global__ __launch_bounds__(256, 2) void k_dcn(const u16* __restrict__ fcu,
                                                const float* __restrict__ om,
                                                const u16* __restrict__ bfr,
                                                const float* __restrict__ bias,
                                                float* __restrict__ out) {
    __shared__ u16 cols[32 * 776];   // 32 pix x 768 ch, stride 776 (1552B, 16B-aligned)
    int tid = threadIdx.x;
    int bx = blockIdx.x;
    int xcd = bx & 7, i = bx >> 3;       // slab swizzle, 512 blocks
    int grow = xcd * 32 + (i >> 1);      // global row 0..255
    int p0 = grow * 64 + (i & 1) * 32;
    int b = p0 >> 12;
    int y = (p0 & 4095) >> 6;
    int x0 = p0 & 63;
    int lane = tid & 63, wid = tid >> 6;
    int r = lane & 15, quad = lane >> 4;
    int sp = tid >> 3, sg = tid & 7;     // 32 pixels x 8 groups
    int pix = p0 + sp;
    int xs = x0 + sp;
    const u16* cub = fcu + ((size_t)b * 4096) * 512 + 256;
    const float* omp = om + (size_t)pix * 216;
    u16* mydst = &cols[0] + sp * 776 + sg * 32;

    // preload all offsets/mask-logits (27 regs)
    float offy[9], offx[9], ml[9];
    #pragma unroll
    for (int t = 0; t < 9; t++) {
        offy[t] = omp[sg * 18 + 2 * t];
        offx[t] = omp[sg * 18 + 2 * t + 1];
        ml[t] = omp[144 + sg * 9 + t];
    }

    floatx4 acc[2][4];
    #pragma unroll
    for (int a = 0; a < 2; a++)
        #pragma unroll
        for (int c = 0; c < 4; c++) acc[a][c] = (floatx4){0.f, 0.f, 0.f, 0.f};

    #pragma unroll
    for (int g = 0; g < 3; g++) {
        int t0 = g * 3, t1 = g * 3 + 1, t2 = g * 3 + 2;
        // software-pipelined sampling (loads for tap i+1 issued before tap i's wait)
        Smp s0, s1;
        dcn_issue(s0, cub, y, xs, sg, t0, offy[t0], offx[t0], ml[t0]);
        dcn_issue(s1, cub, y, xs, sg, t1, offy[t1], offx[t1], ml[t1]);
        dcn_blend(s0, mydst + 0 * 256);
        dcn_issue(s0, cub, y, xs, sg, t2, offy[t2], offx[t2], ml[t2]);
        dcn_blend(s1, mydst + 1 * 256);
        dcn_blend(s0, mydst + 2 * 256);
        __syncthreads();
        // homogeneous MFMA + B-stream phase: 24 k-steps
        #pragma unroll
        for (int kb = 0; kb < 3; kb++) {
            #pragma unroll
            for (int ks = 0; ks < 8; ks++) {
                int ksl = kb * 8 + ks;
                int ksg = g * 24 + ksl;
                short8 a0 = *(const short8*)&cols[r * 776 + ksl * 32 + quad * 8];
                short8 a1 = *(const short8*)&cols[(16 + r) * 776 + ksl * 32 + quad * 8];
                const u16* bp = bfr + (((size_t)ksg * 16 + wid * 4) * 64 + lane) * 8;
                short8 b0 = *(const short8*)(bp);
                short8 b1 = *(const short8*)(bp + 512);
                short8 b2 = *(const short8*)(bp + 1024);
                short8 b3 = *(const short8*)(bp + 1536);
                acc[0][0] = __builtin_amdgcn_mfma_f32_16x16x32_bf16(a0, b0, acc[0][0], 0, 0, 0);
                acc[0][1] = __builtin_amdgcn_mfma_f32_16x16x32_bf16(a0, b1, acc[0][1], 0, 0, 0);
                acc[0][2] = __builtin_amdgcn_mfma_f32_16x16x32_bf16(a0, b2, acc[0][2], 0, 0, 0);
                acc[0][3] = __builtin_amdgcn_mfma_f32_16x16x32_bf16(a0, b3, acc[0][3], 0, 0, 0);
                acc[1][0] = __builtin_amdgcn_mfma_f32_16x16x32_bf16(a1, b0, acc[1][0], 0, 0, 0);
                acc[1][1] = __builtin_amdgcn_mfma_f32_16x16x32_bf16(a1, b1, acc[1][1], 0, 0, 0);
                acc[1][2] = __builtin_amdgcn_mfma_f32_16x16x32_bf16(a1, b2, acc[1][2], 0, 0, 0);
                acc[1][3] = __builtin_amdgcn_mfma_f32_16x16x32_bf16(a1, b3, acc[1][3], 0, 0, 0);
            }
        }
        __syncthreads();
    }
    // epilogue
    #pragma unroll
    for (int mt = 0; mt < 2; mt++) {
        #pragma unroll
        for (int nt = 0; nt < 4; nt++) {
            int f = wid * 64 + nt * 16 + r;
            float bv = bias[f];
            #pragma unroll
            for (int reg = 0; reg < 4; reg++) {
                int pp = p0 + mt * 16 + quad * 4 + reg;
                float fcv = b2f(fcu[(size_t)pp * 512 + f]);
                out[(size_t)pp * 256 + f] = fmaxf(acc[mt][nt][reg] + bv, 0.f) + fcv;
            }
        }
    }
}

// ---------------- launch ----------------
extern "C" void kernel_launch(void* const* d_in, const int* in_sizes, int n_in,
                              void* d_out, int out_size, void* d_ws, size_t ws_size,
                              hipStream_t stream) {
    const float* fine       = (const float*)d_in[0];
    const float* coarse     = (const float*)d_in[1];
    const float* fs_attn_w  = (const float*)d_in[2];
    const float* fs_conv_w  = (const float*)d_in[3];
    const float* offset_w   = (const float*)d_in[4];
    const float* om_w       = (const float*)d_in[5];
    const float* om_b       = (const float*)d_in[6];
    const float* dcn_kernel = (const float*)d_in[7];
    const float* dcn_bias   = (const float*)d_in[8];
    float* out = (float*)d_out;

    // workspace layout (~36 MB)
    char* ws = (char*)d_ws;
    float* gap = (float*)ws;                              // 4 KB
    float* a1  = (float*)(ws + 4096);                     // 4 KB
    u16*   fcu = (u16*)(ws + 8192);                       // 16.78 MB
    float* om  = (float*)(ws + 8192 + 16777216ull);       // 14.16 MB
    u16*   wtf = (u16*)(ws + 8192 + 16777216ull + 14155776ull);   // 2.36 MB
    u16*   wkt = (u16*)(ws + 8192 + 16777216ull + 14155776ull + 2359296ull); // 1.18 MB
    u16*   wb0 = (u16*)(ws + 8192 + 16777216ull + 14155776ull + 2359296ull + 1179648ull); // 128 KB

    hipMemsetAsync(gap, 0, 4 * 256 * sizeof(float), stream);
    k_gap<<<dim3(32, 4), 256, 0, stream>>>(fine, gap);
    k_attn<<<4, 256, 0, stream>>>(gap, fs_attn_w, a1);
    k_upsample<<<dim3(64, 4), 256, 0, stream>>>(coarse, fcu);
    k_wb0<<<32, 256, 0, stream>>>(fs_conv_w, wb0);
    k_g0<<<512, 256, 0, stream>>>(fine, a1, wb0, fcu);
    k_weff<<<dim3(4, 8, 9), 256, 0, stream>>>(offset_w, om_w, wtf);
    k_wkt<<<288, 256, 0, stream>>>(dcn_kernel, wkt);
    k_conv<<<512, 256, 0, stream>>>(fcu, wtf, om_b, om);
    k_dcn<<<512, 256, 0, stream>>>(fcu, om, wkt, dcn_bias, out);
}

// Round 11
// 260.924 us; speedup vs baseline: 4.3844x; 1.1021x over previous
//
#include <hip/hip_runtime.h>
#include <hip/hip_bf16.h>

using u16 = unsigned short;
typedef __attribute__((ext_vector_type(8))) short short8;
typedef __attribute__((ext_vector_type(4))) float floatx4;

__device__ __forceinline__ float b2f(u16 u) {
    union { unsigned int i; float f; } v; v.i = ((unsigned int)u) << 16; return v.f;
}
__device__ __forceinline__ u16 f2b(float f) {
    __hip_bfloat16 h = __float2bfloat16(f);
    u16 u; __builtin_memcpy(&u, &h, sizeof(u)); return u;
}

// B=4, fine 64x64x256, coarse 32x32x256, F=256, DG=8, KK=9, om ch=216
// Inputs fp32; OUTPUT fp32. fcu = concat(fine_cal, coarse_up) bf16 interleaved.
// wtf/wkt/wb0/bomw: weights in MFMA fragment order [ksg][ntile][lane][8].
// XCD-slab swizzle: XCD (bx&7) owns global rows [xcd*32, xcd*32+32).

// ---------------- stage 1a: global average pool (partial + atomic) --------------
__global__ __launch_bounds__(256) void k_gap(const float* __restrict__ fine,
                                             float* __restrict__ gap) {
    int b = blockIdx.y, chunk = blockIdx.x, c = threadIdx.x;
    const float* p = fine + ((size_t)b * 4096 + (size_t)chunk * 128) * 256 + c;
    float s = 0.f;
    for (int i = 0; i < 128; i++) s += p[(size_t)i * 256];
    atomicAdd(&gap[b * 256 + c], s);
}

// ---------------- stage 1b: a1 = sigmoid(gap@W / 4096) + 1 ----------------------
__global__ __launch_bounds__(256) void k_attn(const float* __restrict__ gap,
                                              const float* __restrict__ w,
                                              float* __restrict__ a1) {
    int b = blockIdx.x, d = threadIdx.x;
    float s = 0.f;
    for (int c = 0; c < 256; c++) s += gap[b * 256 + c] * w[c * 256 + d];
    s *= (1.0f / 4096.0f);
    a1[b * 256 + d] = 1.0f + 1.0f / (1.0f + expf(-s));
}

// ---------------- stage 2: bilinear 2x upsample, vectorized ---------------------
// thread = (pixel, 32-ch chunk); grid 512 x 256
__global__ __launch_bounds__(256) void k_upsample(const float* __restrict__ coarse,
                                                  u16* __restrict__ fcu) {
    int tid = threadIdx.x;
    int p = blockIdx.x * 32 + (tid >> 3);
    int ch = (tid & 7) * 32;
    int b = p >> 12, y = (p & 4095) >> 6, x = p & 63;
    float sy = fminf(fmaxf(0.5f * y - 0.25f, 0.0f), 31.0f);
    float sx = fminf(fmaxf(0.5f * x - 0.25f, 0.0f), 31.0f);
    int y0 = (int)floorf(sy); float wy = sy - (float)y0; int y1 = min(y0 + 1, 31);
    int x0 = (int)floorf(sx); float wx = sx - (float)x0; int x1 = min(x0 + 1, 31);
    float w00 = (1.f - wy) * (1.f - wx), w01 = (1.f - wy) * wx;
    float w10 = wy * (1.f - wx), w11 = wy * wx;
    const float* c00 = coarse + ((size_t)((b * 32 + y0) * 32 + x0)) * 256 + ch;
    const float* c01 = coarse + ((size_t)((b * 32 + y0) * 32 + x1)) * 256 + ch;
    const float* c10 = coarse + ((size_t)((b * 32 + y1) * 32 + x0)) * 256 + ch;
    const float* c11 = coarse + ((size_t)((b * 32 + y1) * 32 + x1)) * 256 + ch;
    u16* dst = fcu + (size_t)p * 512 + 256 + ch;
    #pragma unroll
    for (int k = 0; k < 4; k++) {
        float4 a0 = *(const float4*)(c00 + k * 8), a1v = *(const float4*)(c00 + k * 8 + 4);
        float4 b0 = *(const float4*)(c01 + k * 8), b1v = *(const float4*)(c01 + k * 8 + 4);
        float4 g0 = *(const float4*)(c10 + k * 8), g1 = *(const float4*)(c10 + k * 8 + 4);
        float4 d0 = *(const float4*)(c11 + k * 8), d1 = *(const float4*)(c11 + k * 8 + 4);
        u16 o[8] = {
            f2b(w00 * a0.x + w01 * b0.x + w10 * g0.x + w11 * d0.x),
            f2b(w00 * a0.y + w01 * b0.y + w10 * g0.y + w11 * d0.y),
            f2b(w00 * a0.z + w01 * b0.z + w10 * g0.z + w11 * d0.z),
            f2b(w00 * a0.w + w01 * b0.w + w10 * g0.w + w11 * d0.w),
            f2b(w00 * a1v.x + w01 * b1v.x + w10 * g1.x + w11 * d1.x),
            f2b(w00 * a1v.y + w01 * b1v.y + w10 * g1.y + w11 * d1.y),
            f2b(w00 * a1v.z + w01 * b1v.z + w10 * g1.z + w11 * d1.z),
            f2b(w00 * a1v.w + w01 * b1v.w + w10 * g1.w + w11 * d1.w)};
        uint4 ov; __builtin_memcpy(&ov, o, 16);
        *(uint4*)(dst + k * 8) = ov;
    }
}

// ---------------- stage 3a: fs_conv_w (fp32 [k][n]) -> fragment order bf16 ------
__global__ __launch_bounds__(256) void k_wb0(const float* __restrict__ Bw,
                                             u16* __restrict__ wb) {
    int idx = blockIdx.x * 256 + threadIdx.x;   // 8192 total
    int lane = idx & 63;
    int nt = (idx >> 6) & 15;
    int ks = idx >> 10;                          // 0..7
    int n = nt * 16 + (lane & 15);
    int k0 = ks * 32 + (lane >> 4) * 8;
    u16 tmp[8];
    #pragma unroll
    for (int j = 0; j < 8; j++) tmp[j] = f2b(Bw[(size_t)(k0 + j) * 256 + n]);
    uint4 v; __builtin_memcpy(&v, tmp, 16);
    *(uint4*)(wb + (size_t)idx * 8) = v;
}

// ---------------- stage 3b: fine_cal = (fine * a1) @ fs_conv_w  (bf16 MFMA) -----
__global__ __launch_bounds__(256) void k_g0(const float* __restrict__ fine,
                                            const float* __restrict__ a1,
                                            const u16* __restrict__ wb,
                                            u16* __restrict__ fcu) {
    __shared__ u16 cols[32 * 264];
    int tid = threadIdx.x;
    int m0 = blockIdx.x * 32;
    int lane = tid & 63, wid = tid >> 6;
    int r = lane & 15, quad = lane >> 4;
    int sp = tid >> 3, coff = (tid & 7) * 32;
    int row = m0 + sp;
    int b = row >> 12;
    {
        const float* src = fine + (size_t)row * 256 + coff;
        const float* ap = a1 + b * 256 + coff;
        u16* dst = &cols[sp * 264 + coff];
        #pragma unroll
        for (int ch = 0; ch < 4; ch++) {
            float4 v0 = *(const float4*)(src + ch * 8);
            float4 v1 = *(const float4*)(src + ch * 8 + 4);
            float4 s0 = *(const float4*)(ap + ch * 8);
            float4 s1 = *(const float4*)(ap + ch * 8 + 4);
            u16 o[8] = {f2b(v0.x * s0.x), f2b(v0.y * s0.y), f2b(v0.z * s0.z), f2b(v0.w * s0.w),
                        f2b(v1.x * s1.x), f2b(v1.y * s1.y), f2b(v1.z * s1.z), f2b(v1.w * s1.w)};
            uint4 ov; __builtin_memcpy(&ov, o, 16);
            *(uint4*)(dst + ch * 8) = ov;
        }
    }
    __syncthreads();
    floatx4 acc[2][4];
    #pragma unroll
    for (int i = 0; i < 2; i++)
        #pragma unroll
        for (int j = 0; j < 4; j++) acc[i][j] = (floatx4){0.f, 0.f, 0.f, 0.f};
    #pragma unroll
    for (int ks = 0; ks < 8; ks++) {
        short8 a0 = *(const short8*)&cols[r * 264 + ks * 32 + quad * 8];
        short8 a1v = *(const short8*)&cols[(16 + r) * 264 + ks * 32 + quad * 8];
        const u16* bp = wb + (((size_t)ks * 16 + wid * 4) * 64 + lane) * 8;
        short8 b0 = *(const short8*)(bp);
        short8 b1 = *(const short8*)(bp + 512);
        short8 b2 = *(const short8*)(bp + 1024);
        short8 b3 = *(const short8*)(bp + 1536);
        acc[0][0] = __builtin_amdgcn_mfma_f32_16x16x32_bf16(a0, b0, acc[0][0], 0, 0, 0);
        acc[0][1] = __builtin_amdgcn_mfma_f32_16x16x32_bf16(a0, b1, acc[0][1], 0, 0, 0);
        acc[0][2] = __builtin_amdgcn_mfma_f32_16x16x32_bf16(a0, b2, acc[0][2], 0, 0, 0);
        acc[0][3] = __builtin_amdgcn_mfma_f32_16x16x32_bf16(a0, b3, acc[0][3], 0, 0, 0);
        acc[1][0] = __builtin_amdgcn_mfma_f32_16x16x32_bf16(a1v, b0, acc[1][0], 0, 0, 0);
        acc[1][1] = __builtin_amdgcn_mfma_f32_16x16x32_bf16(a1v, b1, acc[1][1], 0, 0, 0);
        acc[1][2] = __builtin_amdgcn_mfma_f32_16x16x32_bf16(a1v, b2, acc[1][2], 0, 0, 0);
        acc[1][3] = __builtin_amdgcn_mfma_f32_16x16x32_bf16(a1v, b3, acc[1][3], 0, 0, 0);
    }
    #pragma unroll
    for (int mt = 0; mt < 2; mt++)
        #pragma unroll
        for (int nt = 0; nt < 4; nt++) {
            int f = wid * 64 + nt * 16 + r;
            #pragma unroll
            for (int reg = 0; reg < 4; reg++) {
                int pp = m0 + mt * 16 + quad * 4 + reg;
                fcu[(size_t)pp * 512 + f] = f2b(acc[mt][nt][reg]);
            }
        }
}

// ---------------- stage 4a: om_w -> B-fragment order bf16 (bomw) ----------------
// bomw[t][ks(16)][nt(16)][lane][8]: n = nt*16+(lane&15), f = ks*32+(lane>>4)*8+j
__global__ __launch_bounds__(256) void k_womw(const float* __restrict__ omw,
                                              u16* __restrict__ bf) {
    int idx = blockIdx.x * 256 + threadIdx.x;   // 147456 total
    int lane = idx & 63;
    int nt = (idx >> 6) & 15;
    int ks = (idx >> 10) & 15;
    int t = idx >> 14;                           // 0..8
    int n = nt * 16 + (lane & 15);
    int f0 = ks * 32 + (lane >> 4) * 8;
    u16 tmp[8];
    #pragma unroll
    for (int j = 0; j < 8; j++)
        tmp[j] = (n < 216) ? f2b(omw[((size_t)t * 512 + f0 + j) * 216 + n]) : (u16)0;
    uint4 v; __builtin_memcpy(&v, tmp, 16);
    *(uint4*)(bf + (size_t)idx * 8) = v;
}

// ---------------- stage 4b: Weff = ow @ omw[t] -> wtf (bf16 MFMA) ---------------
// grid (16 c-blocks, 9 t); M=32 c-rows, N=256, K=512(f)
__global__ __launch_bounds__(256) void k_weff(const float* __restrict__ ow,
                                              const u16* __restrict__ bomw,
                                              u16* __restrict__ wtf) {
    __shared__ u16 cols[32 * 520];
    int tid = threadIdx.x;
    int c0 = blockIdx.x * 32, t = blockIdx.y;
    int lane = tid & 63, wid = tid >> 6;
    int r = lane & 15, quad = lane >> 4;
    int sp = tid >> 3, f0 = (tid & 7) * 64;
    {   // stage A rows: 64 f-values per thread, fp32 -> bf16
        const float* src = ow + (size_t)(c0 + sp) * 512 + f0;
        u16* dst = &cols[sp * 520 + f0];
        #pragma unroll
        for (int k = 0; k < 8; k++) {
            float4 v0 = *(const float4*)(src + k * 8);
            float4 v1 = *(const float4*)(src + k * 8 + 4);
            u16 o[8] = {f2b(v0.x), f2b(v0.y), f2b(v0.z), f2b(v0.w),
                        f2b(v1.x), f2b(v1.y), f2b(v1.z), f2b(v1.w)};
            uint4 ov; __builtin_memcpy(&ov, o, 16);
            *(uint4*)(dst + k * 8) = ov;
        }
    }
    __syncthreads();
    floatx4 acc[2][4];
    #pragma unroll
    for (int i = 0; i < 2; i++)
        #pragma unroll
        for (int j = 0; j < 4; j++) acc[i][j] = (floatx4){0.f, 0.f, 0.f, 0.f};
    #pragma unroll
    for (int ks = 0; ks < 16; ks++) {
        short8 a0 = *(const short8*)&cols[r * 520 + ks * 32 + quad * 8];
        short8 a1v = *(const short8*)&cols[(16 + r) * 520 + ks * 32 + quad * 8];
        const u16* bp = bomw + (((size_t)(t * 16 + ks) * 16 + wid * 4) * 64 + lane) * 8;
        short8 b0 = *(const short8*)(bp);
        short8 b1 = *(const short8*)(bp + 512);
        short8 b2 = *(const short8*)(bp + 1024);
        short8 b3 = *(const short8*)(bp + 1536);
        acc[0][0] = __builtin_amdgcn_mfma_f32_16x16x32_bf16(a0, b0, acc[0][0], 0, 0, 0);
        acc[0][1] = __builtin_amdgcn_mfma_f32_16x16x32_bf16(a0, b1, acc[0][1], 0, 0, 0);
        acc[0][2] = __builtin_amdgcn_mfma_f32_16x16x32_bf16(a0, b2, acc[0][2], 0, 0, 0);
        acc[0][3] = __builtin_amdgcn_mfma_f32_16x16x32_bf16(a0, b3, acc[0][3], 0, 0, 0);
        acc[1][0] = __builtin_amdgcn_mfma_f32_16x16x32_bf16(a1v, b0, acc[1][0], 0, 0, 0);
        acc[1][1] = __builtin_amdgcn_mfma_f32_16x16x32_bf16(a1v, b1, acc[1][1], 0, 0, 0);
        acc[1][2] = __builtin_amdgcn_mfma_f32_16x16x32_bf16(a1v, b2, acc[1][2], 0, 0, 0);
        acc[1][3] = __builtin_amdgcn_mfma_f32_16x16x32_bf16(a1v, b3, acc[1][3], 0, 0, 0);
    }
    // epilogue: c = c0 + mt*16 + quad*4 + reg; n = wid*64 + nt*16 + r
    #pragma unroll
    for (int mt = 0; mt < 2; mt++) {
        #pragma unroll
        for (int nt = 0; nt < 4; nt++) {
            int n = wid * 64 + nt * 16 + r;
            #pragma unroll
            for (int reg = 0; reg < 4; reg++) {
                int c = c0 + mt * 16 + quad * 4 + reg;
                float sc = (c >= 256) ? 2.0f : 1.0f;
                size_t addr = (((size_t)(t * 16 + (c >> 5)) * 16 + (n >> 4)) * 64
                               + ((c >> 3) & 3) * 16 + (n & 15)) * 8 + (c & 7);
                wtf[addr] = f2b(acc[mt][nt][reg] * sc);
            }
        }
    }
}

// ---------------- stage 5: halo-tiled 3x3 conv, M=128 (16x8), N=128, grid 256 ---
__global__ __launch_bounds__(256) void k_conv(const u16* __restrict__ fcu,
                                              const u16* __restrict__ wtf,
                                              const float* __restrict__ bias,
                                              float* __restrict__ om) {
    __shared__ u16 halo[2][180 * 40];   // 18x10 halo, stride 40 shorts
    int tid = threadIdx.x;
    int bx = blockIdx.x;
    int xcd = bx & 7, i = bx >> 3;       // 256 blocks
    int ns = i & 1;
    int pcol = (i >> 1) & 7;
    int prl = (i >> 4) & 1;
    int pr = xcd * 2 + prl;              // patch-row 0..15 (16 rows each)
    int b = pr >> 2;
    int py0 = (pr & 3) * 16, px0 = pcol * 8;
    int n0 = ns * 128;
    int lane = tid & 63, wid = tid >> 6;
    int r = lane & 15, quad = lane >> 4;

    // staging roles: 720 slots (180 pos x 4 q8-chunks), 3 per thread
    int jj0 = tid, jj1 = tid + 256, jj2 = tid + 512;
    int px_[3] = {jj0 >> 2, jj1 >> 2, jj2 >> 2};
    int q8_[3] = {jj0 & 3, jj1 & 3, jj2 & 3};
    bool act[3] = {true, true, jj2 < 720};
    const u16* gs[3];
    bool inb[3];
    int ld[3];
    #pragma unroll
    for (int s = 0; s < 3; s++) {
        int hy = px_[s] / 10, hx = px_[s] - hy * 10;
        int gy = py0 - 1 + hy, gx = px0 - 1 + hx;
        inb[s] = act[s] && gy >= 0 && gy < 64 && gx >= 0 && gx < 64;
        int gyc = min(max(gy, 0), 63), gxc = min(max(gx, 0), 63);
        gs[s] = fcu + ((size_t)((b * 64 + gyc) * 64 + gxc)) * 512 + q8_[s] * 8;
        ld[s] = px_[s] * 40 + q8_[s] * 8;
    }

    floatx4 acc[8][2];
    #pragma unroll
    for (int a = 0; a < 8; a++)
        #pragma unroll
        for (int c = 0; c < 2; c++) acc[a][c] = (floatx4){0.f, 0.f, 0.f, 0.f};

    {   // prologue: chunk 0
        #pragma unroll
        for (int s = 0; s < 3; s++) {
            uint4 v = make_uint4(0, 0, 0, 0);
            if (inb[s]) v = *(const uint4*)(gs[s]);
            if (act[s]) *(uint4*)&halo[0][ld[s]] = v;
        }
    }
    __syncthreads();

    for (int cq = 0; cq < 16; cq++) {
        int cur = cq & 1;
        uint4 vn[3] = {make_uint4(0, 0, 0, 0), make_uint4(0, 0, 0, 0), make_uint4(0, 0, 0, 0)};
        if (cq < 15) {
            #pragma unroll
            for (int s = 0; s < 3; s++)
                if (inb[s]) vn[s] = *(const uint4*)(gs[s] + (cq + 1) * 32);
        }
        const u16* hb = &halo[cur][0];
        #pragma unroll
        for (int t = 0; t < 9; t++) {
            int dy = t / 3 - 1, dx = t - (t / 3) * 3 - 1;
            int ksg = t * 16 + cq;
            const u16* bp = wtf + (((size_t)ksg * 16 + ns * 8 + wid * 2) * 64 + lane) * 8;
            short8 b0 = *(const short8*)(bp);
            short8 b1 = *(const short8*)(bp + 512);
            short8 a[8];
            #pragma unroll
            for (int mt = 0; mt < 8; mt++) {
                int ly = mt * 2 + (r >> 3), lx = r & 7;
                int hy = ly + 1 + dy, hx = lx + 1 + dx;
                a[mt] = *(const short8*)&hb[(hy * 10 + hx) * 40 + quad * 8];
            }
            #pragma unroll
            for (int mt = 0; mt < 8; mt++) {
                acc[mt][0] = __builtin_amdgcn_mfma_f32_16x16x32_bf16(a[mt], b0, acc[mt][0], 0, 0, 0);
                acc[mt][1] = __builtin_amdgcn_mfma_f32_16x16x32_bf16(a[mt], b1, acc[mt][1], 0, 0, 0);
            }
        }
        if (cq < 15) {
            #pragma unroll
            for (int s = 0; s < 3; s++)
                if (act[s]) *(uint4*)&halo[cur ^ 1][ld[s]] = vn[s];
        }
        __syncthreads();
    }
    // epilogue
    #pragma unroll
    for (int nt = 0; nt < 2; nt++) {
        int n = n0 + wid * 32 + nt * 16 + r;
        if (n < 216) {
            float bv = bias[n];
            #pragma unroll
            for (int mt = 0; mt < 8; mt++) {
                #pragma unroll
                for (int reg = 0; reg < 4; reg++) {
                    int m = mt * 16 + quad * 4 + reg;
                    int gyy = py0 + (m >> 3), gxx = px0 + (m & 7);
                    size_t pix = (size_t)((b * 64 + gyy) * 64 + gxx);
                    om[pix * 216 + n] = acc[mt][nt][reg] + bv;
                }
            }
        }
    }
}

// ---------------- stage 5b: dcn_kernel -> bf16 MFMA-fragment order --------------
__global__ __launch_bounds__(256) void k_wkt(const float* __restrict__ Wk,
                                             u16* __restrict__ bf) {
    int idx = blockIdx.x * 256 + threadIdx.x;   // 73728 total
    int lane = idx & 63;
    int nt = (idx >> 6) & 15;
    int ks = idx >> 10;
    int n = nt * 16 + (lane & 15);
    int k0 = ks * 32 + (lane >> 4) * 8;
    u16 tmp[8];
    #pragma unroll
    for (int j = 0; j < 8; j++) tmp[j] = f2b(Wk[(size_t)(k0 + j) * 256 + n]);
    uint4 v; __builtin_memcpy(&v, tmp, 16);
    *(uint4*)(bf + (size_t)idx * 8) = v;
}

// ---------------- stage 6 helpers -----------------------------------------------
struct Smp { uint4 g[4][4]; float w[4]; };

__device__ __forceinline__ void dcn_issue(Smp& s, const u16* __restrict__ cub,
                                          int y, int xs, int sg, int t,
                                          float oy, float ox, float mlog) {
    int dy = t / 3 - 1, dx = t - (t / 3) * 3 - 1;
    float mk = 2.0f / (1.0f + expf(-mlog));
    float py = (float)(y + dy) + oy;
    float px = (float)(xs + dx) + ox;
    float fy = floorf(py), fx = floorf(px);
    int iy = (int)fy, ix = (int)fx;
    float wy1 = py - fy, wx1 = px - fx;
    float wy0 = 1.f - wy1, wx0 = 1.f - wx1;
    bool y0in = iy >= 0 && iy < 64, y1in = iy >= -1 && iy < 63;
    bool x0in = ix >= 0 && ix < 64, x1in = ix >= -1 && ix < 63;
    s.w[0] = (y0in && x0in) ? wy0 * wx0 * mk : 0.f;
    s.w[1] = (y0in && x1in) ? wy0 * wx1 * mk : 0.f;
    s.w[2] = (y1in && x0in) ? wy1 * wx0 * mk : 0.f;
    s.w[3] = (y1in && x1in) ? wy1 * wx1 * mk : 0.f;
    int iy0 = min(max(iy, 0), 63), iy1 = min(max(iy + 1, 0), 63);
    int ix0 = min(max(ix, 0), 63), ix1 = min(max(ix + 1, 0), 63);
    const u16* p00 = cub + (size_t)(iy0 * 64 + ix0) * 512 + sg * 32;
    const u16* p01 = cub + (size_t)(iy0 * 64 + ix1) * 512 + sg * 32;
    const u16* p10 = cub + (size_t)(iy1 * 64 + ix0) * 512 + sg * 32;
    const u16* p11 = cub + (size_t)(iy1 * 64 + ix1) * 512 + sg * 32;
    #pragma unroll
    for (int k = 0; k < 4; k++) {
        s.g[0][k] = *(const uint4*)(p00 + k * 8);
        s.g[1][k] = *(const uint4*)(p01 + k * 8);
        s.g[2][k] = *(const uint4*)(p10 + k * 8);
        s.g[3][k] = *(const uint4*)(p11 + k * 8);
    }
}

__device__ __forceinline__ void dcn_blend(const Smp& s, u16* __restrict__ dst) {
    #pragma unroll
    for (int k = 0; k < 4; k++) {
        const u16* p00 = (const u16*)&s.g[0][k];
        const u16* p01 = (const u16*)&s.g[1][k];
        const u16* p10 = (const u16*)&s.g[2][k];
        const u16* p11 = (const u16*)&s.g[3][k];
        u16 o[8];
        #pragma unroll
        for (int j = 0; j < 8; j++) {
            float v = s.w[0] * b2f(p00[j]) + s.w[1] * b2f(p01[j])
                    + s.w[2] * b2f(p10[j]) + s.w[3] * b2f(p11[j]);
            o[j] = f2b(v);
        }
        uint4 ov; __builtin_memcpy(&ov, o, 16);
        *(uint4*)(dst + k * 8) = ov;
    }
}

// ---------------- stage 6: fused DCN, M=32, 3-tap K-groups, grid 512 ------------
__global__ __launch_bounds__(256, 2) void k_dcn(const u16* __restrict__ fcu,
                                                const float* __restrict__ om,
                                                const u16* __restrict__ bfr,
                                                const float* __restrict__ bias,
                                                float* __restrict__ out) {
    __shared__ u16 cols[32 * 776];   // 32 pix x 768 ch, stride 776 (16B-aligned)
    int tid = threadIdx.x;
    int bx = blockIdx.x;
    int xcd = bx & 7, i = bx >> 3;       // slab swizzle, 512 blocks
    int grow = xcd * 32 + (i >> 1);      // global row 0..255
    int p0 = grow * 64 + (i & 1) * 32;
    int b = p0 >> 12;
    int y = (p0 & 4095) >> 6;
    int x0 = p0 & 63;
    int lane = tid & 63, wid = tid >> 6;
    int r = lane & 15, quad = lane >> 4;
    int sp = tid >> 3, sg = tid & 7;     // 32 pixels x 8 groups
    int pix = p0 + sp;
    int xs = x0 + sp;
    const u16* cub = fcu + ((size_t)b * 4096) * 512 + 256;
    const float* omp = om + (size_t)pix * 216;
    u16* mydst = &cols[0] + sp * 776 + sg * 32;

    float offy[9], offx[9], ml[9];
    #pragma unroll
    for (int t = 0; t < 9; t++) {
        offy[t] = omp[sg * 18 + 2 * t];
        offx[t] = omp[sg * 18 + 2 * t + 1];
        ml[t] = omp[144 + sg * 9 + t];
    }

    floatx4 acc[2][4];
    #pragma unroll
    for (int a = 0; a < 2; a++)
        #pragma unroll
        for (int c = 0; c < 4; c++) acc[a][c] = (floatx4){0.f, 0.f, 0.f, 0.f};

    #pragma unroll
    for (int g = 0; g < 3; g++) {
        int t0 = g * 3, t1 = g * 3 + 1, t2 = g * 3 + 2;
        Smp s0, s1;
        dcn_issue(s0, cub, y, xs, sg, t0, offy[t0], offx[t0], ml[t0]);
        dcn_issue(s1, cub, y, xs, sg, t1, offy[t1], offx[t1], ml[t1]);
        dcn_blend(s0, mydst + 0 * 256);
        dcn_issue(s0, cub, y, xs, sg, t2, offy[t2], offx[t2], ml[t2]);
        dcn_blend(s1, mydst + 1 * 256);
        dcn_blend(s0, mydst + 2 * 256);
        __syncthreads();
        #pragma unroll
        for (int kb = 0; kb < 3; kb++) {
            #pragma unroll
            for (int ks = 0; ks < 8; ks++) {
                int ksl = kb * 8 + ks;
                int ksg = g * 24 + ksl;
                short8 a0 = *(const short8*)&cols[r * 776 + ksl * 32 + quad * 8];
                short8 a1 = *(const short8*)&cols[(16 + r) * 776 + ksl * 32 + quad * 8];
                const u16* bp = bfr + (((size_t)ksg * 16 + wid * 4) * 64 + lane) * 8;
                short8 b0 = *(const short8*)(bp);
                short8 b1 = *(const short8*)(bp + 512);
                short8 b2 = *(const short8*)(bp + 1024);
                short8 b3 = *(const short8*)(bp + 1536);
                acc[0][0] = __builtin_amdgcn_mfma_f32_16x16x32_bf16(a0, b0, acc[0][0], 0, 0, 0);
                acc[0][1] = __builtin_amdgcn_mfma_f32_16x16x32_bf16(a0, b1, acc[0][1], 0, 0, 0);
                acc[0][2] = __builtin_amdgcn_mfma_f32_16x16x32_bf16(a0, b2, acc[0][2], 0, 0, 0);
                acc[0][3] = __builtin_amdgcn_mfma_f32_16x16x32_bf16(a0, b3, acc[0][3], 0, 0, 0);
                acc[1][0] = __builtin_amdgcn_mfma_f32_16x16x32_bf16(a1, b0, acc[1][0], 0, 0, 0);
                acc[1][1] = __builtin_amdgcn_mfma_f32_16x16x32_bf16(a1, b1, acc[1][1], 0, 0, 0);
                acc[1][2] = __builtin_amdgcn_mfma_f32_16x16x32_bf16(a1, b2, acc[1][2], 0, 0, 0);
                acc[1][3] = __builtin_amdgcn_mfma_f32_16x16x32_bf16(a1, b3, acc[1][3], 0, 0, 0);
            }
        }
        __syncthreads();
    }
    #pragma unroll
    for (int mt = 0; mt < 2; mt++) {
        #pragma unroll
        for (int nt = 0; nt < 4; nt++) {
            int f = wid * 64 + nt * 16 + r;
            float bv = bias[f];
            #pragma unroll
            for (int reg = 0; reg < 4; reg++) {
                int pp = p0 + mt * 16 + quad * 4 + reg;
                float fcv = b2f(fcu[(size_t)pp * 512 + f]);
                out[(size_t)pp * 256 + f] = fmaxf(acc[mt][nt][reg] + bv, 0.f) + fcv;
            }
        }
    }
}

// ---------------- launch ----------------
extern "C" void kernel_launch(void* const* d_in, const int* in_sizes, int n_in,
                              void* d_out, int out_size, void* d_ws, size_t ws_size,
                              hipStream_t stream) {
    const float* fine       = (const float*)d_in[0];
    const float* coarse     = (const float*)d_in[1];
    const float* fs_attn_w  = (const float*)d_in[2];
    const float* fs_conv_w  = (const float*)d_in[3];
    const float* offset_w   = (const float*)d_in[4];
    const float* om_w       = (const float*)d_in[5];
    const float* om_b       = (const float*)d_in[6];
    const float* dcn_kernel = (const float*)d_in[7];
    const float* dcn_bias   = (const float*)d_in[8];
    float* out = (float*)d_out;

    // workspace layout (~38.5 MB)
    char* ws = (char*)d_ws;
    size_t off = 0;
    float* gap = (float*)(ws + off); off += 4096;
    float* a1  = (float*)(ws + off); off += 4096;
    u16*   fcu = (u16*)(ws + off);   off += 16777216ull;   // 16.78 MB
    float* om  = (float*)(ws + off); off += 14155776ull;   // 14.16 MB
    u16*   wtf = (u16*)(ws + off);   off += 2359296ull;    // 2.36 MB
    u16*   wkt = (u16*)(ws + off);   off += 1179648ull;    // 1.18 MB
    u16*   wb0 = (u16*)(ws + off);   off += 131072ull;     // 128 KB
    u16*   bomw = (u16*)(ws + off);  off += 2359296ull;    // 2.36 MB

    hipMemsetAsync(gap, 0, 4 * 256 * sizeof(float), stream);
    k_gap<<<dim3(32, 4), 256, 0, stream>>>(fine, gap);
    k_attn<<<4, 256, 0, stream>>>(gap, fs_attn_w, a1);
    k_upsample<<<512, 256, 0, stream>>>(coarse, fcu);
    k_wb0<<<32, 256, 0, stream>>>(fs_conv_w, wb0);
    k_g0<<<512, 256, 0, stream>>>(fine, a1, wb0, fcu);
    k_womw<<<576, 256, 0, stream>>>(om_w, bomw);
    k_weff<<<dim3(16, 9), 256, 0, stream>>>(offset_w, bomw, wtf);
    k_wkt<<<288, 256, 0, stream>>>(dcn_kernel, wkt);
    k_conv<<<256, 256, 0, stream>>>(fcu, wtf, om_b, om);
    k_dcn<<<512, 256, 0, stream>>>(fcu, om, wkt, dcn_bias, out);
}

// Round 12
// 249.665 us; speedup vs baseline: 4.5821x; 1.0451x over previous
//
#include <hip/hip_runtime.h>
#include <hip/hip_bf16.h>

using u16 = unsigned short;
typedef __attribute__((ext_vector_type(8))) short short8;
typedef __attribute__((ext_vector_type(4))) float floatx4;

__device__ __forceinline__ float b2f(u16 u) {
    union { unsigned int i; float f; } v; v.i = ((unsigned int)u) << 16; return v.f;
}
__device__ __forceinline__ u16 f2b(float f) {
    __hip_bfloat16 h = __float2bfloat16(f);
    u16 u; __builtin_memcpy(&u, &h, sizeof(u)); return u;
}

// B=4, fine 64x64x256, coarse 32x32x256, F=256, DG=8, KK=9, om ch=216
// Inputs fp32; OUTPUT fp32. fcu = concat(fine_cal, coarse_up) bf16 interleaved.
// wtf/wkt/wb0/bomw: weights in MFMA fragment order [ksg][ntile][lane][8].
// XCD-slab swizzle: XCD (bx&7) owns global rows [xcd*32, xcd*32+32).

// ---------------- stage 1a: global average pool (partial + atomic) --------------
__global__ __launch_bounds__(256) void k_gap(const float* __restrict__ fine,
                                             float* __restrict__ gap) {
    int b = blockIdx.y, chunk = blockIdx.x, c = threadIdx.x;
    const float* p = fine + ((size_t)b * 4096 + (size_t)chunk * 128) * 256 + c;
    float s = 0.f;
    for (int i = 0; i < 128; i++) s += p[(size_t)i * 256];
    atomicAdd(&gap[b * 256 + c], s);
}

// ---------------- stage 1b: a1 = sigmoid(gap@W / 4096) + 1 ----------------------
__global__ __launch_bounds__(256) void k_attn(const float* __restrict__ gap,
                                              const float* __restrict__ w,
                                              float* __restrict__ a1) {
    int b = blockIdx.x, d = threadIdx.x;
    float s = 0.f;
    for (int c = 0; c < 256; c++) s += gap[b * 256 + c] * w[c * 256 + d];
    s *= (1.0f / 4096.0f);
    a1[b * 256 + d] = 1.0f + 1.0f / (1.0f + expf(-s));
}

// ---------------- stage 2: bilinear 2x upsample, vectorized ---------------------
__global__ __launch_bounds__(256) void k_upsample(const float* __restrict__ coarse,
                                                  u16* __restrict__ fcu) {
    int tid = threadIdx.x;
    int p = blockIdx.x * 32 + (tid >> 3);
    int ch = (tid & 7) * 32;
    int b = p >> 12, y = (p & 4095) >> 6, x = p & 63;
    float sy = fminf(fmaxf(0.5f * y - 0.25f, 0.0f), 31.0f);
    float sx = fminf(fmaxf(0.5f * x - 0.25f, 0.0f), 31.0f);
    int y0 = (int)floorf(sy); float wy = sy - (float)y0; int y1 = min(y0 + 1, 31);
    int x0 = (int)floorf(sx); float wx = sx - (float)x0; int x1 = min(x0 + 1, 31);
    float w00 = (1.f - wy) * (1.f - wx), w01 = (1.f - wy) * wx;
    float w10 = wy * (1.f - wx), w11 = wy * wx;
    const float* c00 = coarse + ((size_t)((b * 32 + y0) * 32 + x0)) * 256 + ch;
    const float* c01 = coarse + ((size_t)((b * 32 + y0) * 32 + x1)) * 256 + ch;
    const float* c10 = coarse + ((size_t)((b * 32 + y1) * 32 + x0)) * 256 + ch;
    const float* c11 = coarse + ((size_t)((b * 32 + y1) * 32 + x1)) * 256 + ch;
    u16* dst = fcu + (size_t)p * 512 + 256 + ch;
    #pragma unroll
    for (int k = 0; k < 4; k++) {
        float4 a0 = *(const float4*)(c00 + k * 8), a1v = *(const float4*)(c00 + k * 8 + 4);
        float4 b0 = *(const float4*)(c01 + k * 8), b1v = *(const float4*)(c01 + k * 8 + 4);
        float4 g0 = *(const float4*)(c10 + k * 8), g1 = *(const float4*)(c10 + k * 8 + 4);
        float4 d0 = *(const float4*)(c11 + k * 8), d1 = *(const float4*)(c11 + k * 8 + 4);
        u16 o[8] = {
            f2b(w00 * a0.x + w01 * b0.x + w10 * g0.x + w11 * d0.x),
            f2b(w00 * a0.y + w01 * b0.y + w10 * g0.y + w11 * d0.y),
            f2b(w00 * a0.z + w01 * b0.z + w10 * g0.z + w11 * d0.z),
            f2b(w00 * a0.w + w01 * b0.w + w10 * g0.w + w11 * d0.w),
            f2b(w00 * a1v.x + w01 * b1v.x + w10 * g1.x + w11 * d1.x),
            f2b(w00 * a1v.y + w01 * b1v.y + w10 * g1.y + w11 * d1.y),
            f2b(w00 * a1v.z + w01 * b1v.z + w10 * g1.z + w11 * d1.z),
            f2b(w00 * a1v.w + w01 * b1v.w + w10 * g1.w + w11 * d1.w)};
        uint4 ov; __builtin_memcpy(&ov, o, 16);
        *(uint4*)(dst + k * 8) = ov;
    }
}

// ---------------- merged weight swizzles: wb0 (32) | wkt (288) | bomw (576) -----
__global__ __launch_bounds__(256) void k_wswz(const float* __restrict__ fsw,
                                              const float* __restrict__ Wk,
                                              const float* __restrict__ omw,
                                              u16* __restrict__ wb0,
                                              u16* __restrict__ wkt,
                                              u16* __restrict__ bomw) {
    int bx = blockIdx.x;
    int tid = threadIdx.x;
    if (bx < 32) {
        int idx = bx * 256 + tid;
        int lane = idx & 63, nt = (idx >> 6) & 15, ks = idx >> 10;
        int n = nt * 16 + (lane & 15);
        int k0 = ks * 32 + (lane >> 4) * 8;
        u16 tmp[8];
        #pragma unroll
        for (int j = 0; j < 8; j++) tmp[j] = f2b(fsw[(size_t)(k0 + j) * 256 + n]);
        uint4 v; __builtin_memcpy(&v, tmp, 16);
        *(uint4*)(wb0 + (size_t)idx * 8) = v;
    } else if (bx < 320) {
        int idx = (bx - 32) * 256 + tid;
        int lane = idx & 63, nt = (idx >> 6) & 15, ks = idx >> 10;
        int n = nt * 16 + (lane & 15);
        int k0 = ks * 32 + (lane >> 4) * 8;
        u16 tmp[8];
        #pragma unroll
        for (int j = 0; j < 8; j++) tmp[j] = f2b(Wk[(size_t)(k0 + j) * 256 + n]);
        uint4 v; __builtin_memcpy(&v, tmp, 16);
        *(uint4*)(wkt + (size_t)idx * 8) = v;
    } else {
        int idx = (bx - 320) * 256 + tid;
        int lane = idx & 63, nt = (idx >> 6) & 15, ks = (idx >> 10) & 15, t = idx >> 14;
        int n = nt * 16 + (lane & 15);
        int f0 = ks * 32 + (lane >> 4) * 8;
        u16 tmp[8];
        #pragma unroll
        for (int j = 0; j < 8; j++)
            tmp[j] = (n < 216) ? f2b(omw[((size_t)t * 512 + f0 + j) * 216 + n]) : (u16)0;
        uint4 v; __builtin_memcpy(&v, tmp, 16);
        *(uint4*)(bomw + (size_t)idx * 8) = v;
    }
}

// ---------------- stage 3b: fine_cal = (fine * a1) @ fs_conv_w  (bf16 MFMA) -----
__global__ __launch_bounds__(256) void k_g0(const float* __restrict__ fine,
                                            const float* __restrict__ a1,
                                            const u16* __restrict__ wb,
                                            u16* __restrict__ fcu) {
    __shared__ u16 cols[32 * 264];
    int tid = threadIdx.x;
    int m0 = blockIdx.x * 32;
    int lane = tid & 63, wid = tid >> 6;
    int r = lane & 15, quad = lane >> 4;
    int sp = tid >> 3, coff = (tid & 7) * 32;
    int row = m0 + sp;
    int b = row >> 12;
    {
        const float* src = fine + (size_t)row * 256 + coff;
        const float* ap = a1 + b * 256 + coff;
        u16* dst = &cols[sp * 264 + coff];
        #pragma unroll
        for (int ch = 0; ch < 4; ch++) {
            float4 v0 = *(const float4*)(src + ch * 8);
            float4 v1 = *(const float4*)(src + ch * 8 + 4);
            float4 s0 = *(const float4*)(ap + ch * 8);
            float4 s1 = *(const float4*)(ap + ch * 8 + 4);
            u16 o[8] = {f2b(v0.x * s0.x), f2b(v0.y * s0.y), f2b(v0.z * s0.z), f2b(v0.w * s0.w),
                        f2b(v1.x * s1.x), f2b(v1.y * s1.y), f2b(v1.z * s1.z), f2b(v1.w * s1.w)};
            uint4 ov; __builtin_memcpy(&ov, o, 16);
            *(uint4*)(dst + ch * 8) = ov;
        }
    }
    __syncthreads();
    floatx4 acc[2][4];
    #pragma unroll
    for (int i = 0; i < 2; i++)
        #pragma unroll
        for (int j = 0; j < 4; j++) acc[i][j] = (floatx4){0.f, 0.f, 0.f, 0.f};
    #pragma unroll
    for (int ks = 0; ks < 8; ks++) {
        short8 a0 = *(const short8*)&cols[r * 264 + ks * 32 + quad * 8];
        short8 a1v = *(const short8*)&cols[(16 + r) * 264 + ks * 32 + quad * 8];
        const u16* bp = wb + (((size_t)ks * 16 + wid * 4) * 64 + lane) * 8;
        short8 b0 = *(const short8*)(bp);
        short8 b1 = *(const short8*)(bp + 512);
        short8 b2 = *(const short8*)(bp + 1024);
        short8 b3 = *(const short8*)(bp + 1536);
        acc[0][0] = __builtin_amdgcn_mfma_f32_16x16x32_bf16(a0, b0, acc[0][0], 0, 0, 0);
        acc[0][1] = __builtin_amdgcn_mfma_f32_16x16x32_bf16(a0, b1, acc[0][1], 0, 0, 0);
        acc[0][2] = __builtin_amdgcn_mfma_f32_16x16x32_bf16(a0, b2, acc[0][2], 0, 0, 0);
        acc[0][3] = __builtin_amdgcn_mfma_f32_16x16x32_bf16(a0, b3, acc[0][3], 0, 0, 0);
        acc[1][0] = __builtin_amdgcn_mfma_f32_16x16x32_bf16(a1v, b0, acc[1][0], 0, 0, 0);
        acc[1][1] = __builtin_amdgcn_mfma_f32_16x16x32_bf16(a1v, b1, acc[1][1], 0, 0, 0);
        acc[1][2] = __builtin_amdgcn_mfma_f32_16x16x32_bf16(a1v, b2, acc[1][2], 0, 0, 0);
        acc[1][3] = __builtin_amdgcn_mfma_f32_16x16x32_bf16(a1v, b3, acc[1][3], 0, 0, 0);
    }
    #pragma unroll
    for (int mt = 0; mt < 2; mt++)
        #pragma unroll
        for (int nt = 0; nt < 4; nt++) {
            int f = wid * 64 + nt * 16 + r;
            #pragma unroll
            for (int reg = 0; reg < 4; reg++) {
                int pp = m0 + mt * 16 + quad * 4 + reg;
                fcu[(size_t)pp * 512 + f] = f2b(acc[mt][nt][reg]);
            }
        }
}

// ---------------- stage 4b: Weff = ow @ omw[t] -> wtf (bf16 MFMA) ---------------
__global__ __launch_bounds__(256) void k_weff(const float* __restrict__ ow,
                                              const u16* __restrict__ bomw,
                                              u16* __restrict__ wtf) {
    __shared__ u16 cols[32 * 520];
    int tid = threadIdx.x;
    int c0 = blockIdx.x * 32, t = blockIdx.y;
    int lane = tid & 63, wid = tid >> 6;
    int r = lane & 15, quad = lane >> 4;
    int sp = tid >> 3, f0 = (tid & 7) * 64;
    {
        const float* src = ow + (size_t)(c0 + sp) * 512 + f0;
        u16* dst = &cols[sp * 520 + f0];
        #pragma unroll
        for (int k = 0; k < 8; k++) {
            float4 v0 = *(const float4*)(src + k * 8);
            float4 v1 = *(const float4*)(src + k * 8 + 4);
            u16 o[8] = {f2b(v0.x), f2b(v0.y), f2b(v0.z), f2b(v0.w),
                        f2b(v1.x), f2b(v1.y), f2b(v1.z), f2b(v1.w)};
            uint4 ov; __builtin_memcpy(&ov, o, 16);
            *(uint4*)(dst + k * 8) = ov;
        }
    }
    __syncthreads();
    floatx4 acc[2][4];
    #pragma unroll
    for (int i = 0; i < 2; i++)
        #pragma unroll
        for (int j = 0; j < 4; j++) acc[i][j] = (floatx4){0.f, 0.f, 0.f, 0.f};
    #pragma unroll
    for (int ks = 0; ks < 16; ks++) {
        short8 a0 = *(const short8*)&cols[r * 520 + ks * 32 + quad * 8];
        short8 a1v = *(const short8*)&cols[(16 + r) * 520 + ks * 32 + quad * 8];
        const u16* bp = bomw + (((size_t)(t * 16 + ks) * 16 + wid * 4) * 64 + lane) * 8;
        short8 b0 = *(const short8*)(bp);
        short8 b1 = *(const short8*)(bp + 512);
        short8 b2 = *(const short8*)(bp + 1024);
        short8 b3 = *(const short8*)(bp + 1536);
        acc[0][0] = __builtin_amdgcn_mfma_f32_16x16x32_bf16(a0, b0, acc[0][0], 0, 0, 0);
        acc[0][1] = __builtin_amdgcn_mfma_f32_16x16x32_bf16(a0, b1, acc[0][1], 0, 0, 0);
        acc[0][2] = __builtin_amdgcn_mfma_f32_16x16x32_bf16(a0, b2, acc[0][2], 0, 0, 0);
        acc[0][3] = __builtin_amdgcn_mfma_f32_16x16x32_bf16(a0, b3, acc[0][3], 0, 0, 0);
        acc[1][0] = __builtin_amdgcn_mfma_f32_16x16x32_bf16(a1v, b0, acc[1][0], 0, 0, 0);
        acc[1][1] = __builtin_amdgcn_mfma_f32_16x16x32_bf16(a1v, b1, acc[1][1], 0, 0, 0);
        acc[1][2] = __builtin_amdgcn_mfma_f32_16x16x32_bf16(a1v, b2, acc[1][2], 0, 0, 0);
        acc[1][3] = __builtin_amdgcn_mfma_f32_16x16x32_bf16(a1v, b3, acc[1][3], 0, 0, 0);
    }
    #pragma unroll
    for (int mt = 0; mt < 2; mt++) {
        #pragma unroll
        for (int nt = 0; nt < 4; nt++) {
            int n = wid * 64 + nt * 16 + r;
            #pragma unroll
            for (int reg = 0; reg < 4; reg++) {
                int c = c0 + mt * 16 + quad * 4 + reg;
                float sc = (c >= 256) ? 2.0f : 1.0f;
                size_t addr = (((size_t)(t * 16 + (c >> 5)) * 16 + (n >> 4)) * 64
                               + ((c >> 3) & 3) * 16 + (n & 15)) * 8 + (c & 7);
                wtf[addr] = f2b(acc[mt][nt][reg] * sc);
            }
        }
    }
}

// ---------------- stage 5: halo conv, M=64 (8x8), N=128, grid 512, B-prefetch ---
__global__ __launch_bounds__(256, 2) void k_conv(const u16* __restrict__ fcu,
                                                 const u16* __restrict__ wtf,
                                                 const float* __restrict__ bias,
                                                 float* __restrict__ om) {
    __shared__ u16 halo[2][100 * 40];
    int tid = threadIdx.x;
    int bx = blockIdx.x;
    int xcd = bx & 7, i = bx >> 3;
    int prow = xcd * 4 + (i >> 4);
    int pcol = (i >> 1) & 7;
    int ns = i & 1;
    int b = prow >> 3;
    int py0 = (prow & 7) * 8, px0 = pcol * 8;
    int n0 = ns * 128;
    int lane = tid & 63, wid = tid >> 6;
    int r = lane & 15, quad = lane >> 4;

    int j0 = tid, j1 = tid + 256;
    int pix0 = j0 >> 2, q80 = j0 & 3;
    int pix1 = j1 >> 2, q81 = j1 & 3;
    int hy0 = pix0 / 10, hx0 = pix0 - hy0 * 10;
    int hy1 = pix1 / 10, hx1 = pix1 - hy1 * 10;
    int gy0 = py0 - 1 + hy0, gx0 = px0 - 1 + hx0;
    int gy1 = py0 - 1 + hy1, gx1 = px0 - 1 + hx1;
    bool act1 = j1 < 400;
    bool in0 = gy0 >= 0 && gy0 < 64 && gx0 >= 0 && gx0 < 64;
    bool in1 = act1 && gy1 >= 0 && gy1 < 64 && gx1 >= 0 && gx1 < 64;
    const u16* gs0 = fcu + ((size_t)((b * 64 + min(max(gy0, 0), 63)) * 64 + min(max(gx0, 0), 63))) * 512 + q80 * 8;
    const u16* gs1 = fcu + ((size_t)((b * 64 + min(max(gy1, 0), 63)) * 64 + min(max(gx1, 0), 63))) * 512 + q81 * 8;
    int ld0 = pix0 * 40 + q80 * 8;
    int ld1 = pix1 * 40 + q81 * 8;

    floatx4 acc[4][2];
    #pragma unroll
    for (int a = 0; a < 4; a++)
        #pragma unroll
        for (int c = 0; c < 2; c++) acc[a][c] = (floatx4){0.f, 0.f, 0.f, 0.f};

    {
        uint4 v0 = make_uint4(0, 0, 0, 0), v1 = make_uint4(0, 0, 0, 0);
        if (in0) v0 = *(const uint4*)(gs0);
        if (in1) v1 = *(const uint4*)(gs1);
        *(uint4*)&halo[0][ld0] = v0;
        if (act1) *(uint4*)&halo[0][ld1] = v1;
    }
    __syncthreads();

    for (int cq = 0; cq < 16; cq++) {
        int cur = cq & 1;
        const u16* hb = &halo[cur][0];
        // B-prefetch pipeline, depth 2 taps
        short8 Bp[2][2];
        #pragma unroll
        for (int d = 0; d < 2; d++) {
            const u16* bp = wtf + (((size_t)(d * 16 + cq) * 16 + ns * 8 + wid * 2) * 64 + lane) * 8;
            Bp[d][0] = *(const short8*)(bp);
            Bp[d][1] = *(const short8*)(bp + 512);
        }
        uint4 v0 = make_uint4(0, 0, 0, 0), v1 = make_uint4(0, 0, 0, 0);
        #pragma unroll
        for (int t = 0; t < 7; t++) {
            int d = t & 1;
            short8 b0 = Bp[d][0], b1 = Bp[d][1];
            const u16* bp = wtf + (((size_t)((t + 2) * 16 + cq) * 16 + ns * 8 + wid * 2) * 64 + lane) * 8;
            Bp[d][0] = *(const short8*)(bp);
            Bp[d][1] = *(const short8*)(bp + 512);
            int dy = t / 3 - 1, dx = t - (t / 3) * 3 - 1;
            short8 a[4];
            #pragma unroll
            for (int mt = 0; mt < 4; mt++) {
                int m = mt * 16 + r;
                int hy = (m >> 3) + 1 + dy, hx = (m & 7) + 1 + dx;
                a[mt] = *(const short8*)&hb[(hy * 10 + hx) * 40 + quad * 8];
            }
            #pragma unroll
            for (int mt = 0; mt < 4; mt++) {
                acc[mt][0] = __builtin_amdgcn_mfma_f32_16x16x32_bf16(a[mt], b0, acc[mt][0], 0, 0, 0);
                acc[mt][1] = __builtin_amdgcn_mfma_f32_16x16x32_bf16(a[mt], b1, acc[mt][1], 0, 0, 0);
            }
        }
        // staging loads issued AFTER all B loads (no vmcnt inversion)
        if (cq < 15) {
            if (in0) v0 = *(const uint4*)(gs0 + (cq + 1) * 32);
            if (in1) v1 = *(const uint4*)(gs1 + (cq + 1) * 32);
        }
        #pragma unroll
        for (int t = 7; t < 9; t++) {
            int d = t & 1;
            short8 b0 = Bp[d][0], b1 = Bp[d][1];
            int dy = t / 3 - 1, dx = t - (t / 3) * 3 - 1;
            short8 a[4];
            #pragma unroll
            for (int mt = 0; mt < 4; mt++) {
                int m = mt * 16 + r;
                int hy = (m >> 3) + 1 + dy, hx = (m & 7) + 1 + dx;
                a[mt] = *(const short8*)&hb[(hy * 10 + hx) * 40 + quad * 8];
            }
            #pragma unroll
            for (int mt = 0; mt < 4; mt++) {
                acc[mt][0] = __builtin_amdgcn_mfma_f32_16x16x32_bf16(a[mt], b0, acc[mt][0], 0, 0, 0);
                acc[mt][1] = __builtin_amdgcn_mfma_f32_16x16x32_bf16(a[mt], b1, acc[mt][1], 0, 0, 0);
            }
        }
        if (cq < 15) {
            *(uint4*)&halo[cur ^ 1][ld0] = v0;
            if (act1) *(uint4*)&halo[cur ^ 1][ld1] = v1;
        }
        __syncthreads();
    }
    #pragma unroll
    for (int nt = 0; nt < 2; nt++) {
        int n = n0 + wid * 32 + nt * 16 + r;
        if (n < 216) {
            float bv = bias[n];
            #pragma unroll
            for (int mt = 0; mt < 4; mt++) {
                #pragma unroll
                for (int reg = 0; reg < 4; reg++) {
                    int m = mt * 16 + quad * 4 + reg;
                    int gyy = py0 + (m >> 3), gxx = px0 + (m & 7);
                    size_t pix = (size_t)((b * 64 + gyy) * 64 + gxx);
                    om[pix * 216 + n] = acc[mt][nt][reg] + bv;
                }
            }
        }
    }
}

// ---------------- stage 6 helpers -----------------------------------------------
struct Smp { uint4 g[4][4]; float w[4]; };

__device__ __forceinline__ void dcn_issue(Smp& s, const u16* __restrict__ cub,
                                          int y, int xs, int sg, int t,
                                          float oy, float ox, float mlog) {
    int dy = t / 3 - 1, dx = t - (t / 3) * 3 - 1;
    float mk = 2.0f / (1.0f + expf(-mlog));
    float py = (float)(y + dy) + oy;
    float px = (float)(xs + dx) + ox;
    float fy = floorf(py), fx = floorf(px);
    int iy = (int)fy, ix = (int)fx;
    float wy1 = py - fy, wx1 = px - fx;
    float wy0 = 1.f - wy1, wx0 = 1.f - wx1;
    bool y0in = iy >= 0 && iy < 64, y1in = iy >= -1 && iy < 63;
    bool x0in = ix >= 0 && ix < 64, x1in = ix >= -1 && ix < 63;
    s.w[0] = (y0in && x0in) ? wy0 * wx0 * mk : 0.f;
    s.w[1] = (y0in && x1in) ? wy0 * wx1 * mk : 0.f;
    s.w[2] = (y1in && x0in) ? wy1 * wx0 * mk : 0.f;
    s.w[3] = (y1in && x1in) ? wy1 * wx1 * mk : 0.f;
    int iy0 = min(max(iy, 0), 63), iy1 = min(max(iy + 1, 0), 63);
    int ix0 = min(max(ix, 0), 63), ix1 = min(max(ix + 1, 0), 63);
    const u16* p00 = cub + (size_t)(iy0 * 64 + ix0) * 512 + sg * 32;
    const u16* p01 = cub + (size_t)(iy0 * 64 + ix1) * 512 + sg * 32;
    const u16* p10 = cub + (size_t)(iy1 * 64 + ix0) * 512 + sg * 32;
    const u16* p11 = cub + (size_t)(iy1 * 64 + ix1) * 512 + sg * 32;
    #pragma unroll
    for (int k = 0; k < 4; k++) {
        s.g[0][k] = *(const uint4*)(p00 + k * 8);
        s.g[1][k] = *(const uint4*)(p01 + k * 8);
        s.g[2][k] = *(const uint4*)(p10 + k * 8);
        s.g[3][k] = *(const uint4*)(p11 + k * 8);
    }
}

__device__ __forceinline__ void dcn_blend(const Smp& s, u16* __restrict__ dst) {
    #pragma unroll
    for (int k = 0; k < 4; k++) {
        const u16* p00 = (const u16*)&s.g[0][k];
        const u16* p01 = (const u16*)&s.g[1][k];
        const u16* p10 = (const u16*)&s.g[2][k];
        const u16* p11 = (const u16*)&s.g[3][k];
        u16 o[8];
        #pragma unroll
        for (int j = 0; j < 8; j++) {
            float v = s.w[0] * b2f(p00[j]) + s.w[1] * b2f(p01[j])
                    + s.w[2] * b2f(p10[j]) + s.w[3] * b2f(p11[j]);
            o[j] = f2b(v);
        }
        uint4 ov; __builtin_memcpy(&ov, o, 16);
        *(uint4*)(dst + k * 8) = ov;
    }
}

// ---------------- stage 6: fused DCN, M=32, 3-tap groups, 4-deep B pipeline -----
__global__ __launch_bounds__(256, 2) void k_dcn(const u16* __restrict__ fcu,
                                                const float* __restrict__ om,
                                                const u16* __restrict__ bfr,
                                                const float* __restrict__ bias,
                                                float* __restrict__ out) {
    __shared__ u16 cols[32 * 776];
    int tid = threadIdx.x;
    int bx = blockIdx.x;
    int xcd = bx & 7, i = bx >> 3;
    int grow = xcd * 32 + (i >> 1);
    int p0 = grow * 64 + (i & 1) * 32;
    int b = p0 >> 12;
    int y = (p0 & 4095) >> 6;
    int x0 = p0 & 63;
    int lane = tid & 63, wid = tid >> 6;
    int r = lane & 15, quad = lane >> 4;
    int sp = tid >> 3, sg = tid & 7;
    int pix = p0 + sp;
    int xs = x0 + sp;
    const u16* cub = fcu + ((size_t)b * 4096) * 512 + 256;
    const float* omp = om + (size_t)pix * 216;
    u16* mydst = &cols[0] + sp * 776 + sg * 32;

    float offy[9], offx[9], ml[9];
    #pragma unroll
    for (int t = 0; t < 9; t++) {
        offy[t] = omp[sg * 18 + 2 * t];
        offx[t] = omp[sg * 18 + 2 * t + 1];
        ml[t] = omp[144 + sg * 9 + t];
    }

    floatx4 acc[2][4];
    #pragma unroll
    for (int a = 0; a < 2; a++)
        #pragma unroll
        for (int c = 0; c < 4; c++) acc[a][c] = (floatx4){0.f, 0.f, 0.f, 0.f};

    #pragma unroll
    for (int g = 0; g < 3; g++) {
        int t0 = g * 3, t1 = g * 3 + 1, t2 = g * 3 + 2;
        Smp s0, s1;
        dcn_issue(s0, cub, y, xs, sg, t0, offy[t0], offx[t0], ml[t0]);
        dcn_issue(s1, cub, y, xs, sg, t1, offy[t1], offx[t1], ml[t1]);
        dcn_blend(s0, mydst + 0 * 256);
        dcn_issue(s0, cub, y, xs, sg, t2, offy[t2], offx[t2], ml[t2]);
        dcn_blend(s1, mydst + 1 * 256);
        dcn_blend(s0, mydst + 2 * 256);
        __syncthreads();
        // MFMA phase with 4-deep rotating B-register pipeline
        short8 Bb[4][4];
        #pragma unroll
        for (int d = 0; d < 4; d++) {
            const u16* bp = bfr + (((size_t)(g * 24 + d) * 16 + wid * 4) * 64 + lane) * 8;
            Bb[d][0] = *(const short8*)(bp);
            Bb[d][1] = *(const short8*)(bp + 512);
            Bb[d][2] = *(const short8*)(bp + 1024);
            Bb[d][3] = *(const short8*)(bp + 1536);
        }
        #pragma unroll
        for (int ksl = 0; ksl < 24; ksl++) {
            int d = ksl & 3;
            short8 b0 = Bb[d][0], b1 = Bb[d][1], b2 = Bb[d][2], b3 = Bb[d][3];
            if (ksl + 4 < 24) {
                const u16* bp = bfr + (((size_t)(g * 24 + ksl + 4) * 16 + wid * 4) * 64 + lane) * 8;
                Bb[d][0] = *(const short8*)(bp);
                Bb[d][1] = *(const short8*)(bp + 512);
                Bb[d][2] = *(const short8*)(bp + 1024);
                Bb[d][3] = *(const short8*)(bp + 1536);
            }
            short8 a0 = *(const short8*)&cols[r * 776 + ksl * 32 + quad * 8];
            short8 a1 = *(const short8*)&cols[(16 + r) * 776 + ksl * 32 + quad * 8];
            acc[0][0] = __builtin_amdgcn_mfma_f32_16x16x32_bf16(a0, b0, acc[0][0], 0, 0, 0);
            acc[0][1] = __builtin_amdgcn_mfma_f32_16x16x32_bf16(a0, b1, acc[0][1], 0, 0, 0);
            acc[0][2] = __builtin_amdgcn_mfma_f32_16x16x32_bf16(a0, b2, acc[0][2], 0, 0, 0);
            acc[0][3] = __builtin_amdgcn_mfma_f32_16x16x32_bf16(a0, b3, acc[0][3], 0, 0, 0);
            acc[1][0] = __builtin_amdgcn_mfma_f32_16x16x32_bf16(a1, b0, acc[1][0], 0, 0, 0);
            acc[1][1] = __builtin_amdgcn_mfma_f32_16x16x32_bf16(a1, b1, acc[1][1], 0, 0, 0);
            acc[1][2] = __builtin_amdgcn_mfma_f32_16x16x32_bf16(a1, b2, acc[1][2], 0, 0, 0);
            acc[1][3] = __builtin_amdgcn_mfma_f32_16x16x32_bf16(a1, b3, acc[1][3], 0, 0, 0);
        }
        __syncthreads();
    }
    #pragma unroll
    for (int mt = 0; mt < 2; mt++) {
        #pragma unroll
        for (int nt = 0; nt < 4; nt++) {
            int f = wid * 64 + nt * 16 + r;
            float bv = bias[f];
            #pragma unroll
            for (int reg = 0; reg < 4; reg++) {
                int pp = p0 + mt * 16 + quad * 4 + reg;
                float fcv = b2f(fcu[(size_t)pp * 512 + f]);
                out[(size_t)pp * 256 + f] = fmaxf(acc[mt][nt][reg] + bv, 0.f) + fcv;
            }
        }
    }
}

// ---------------- launch ----------------
extern "C" void kernel_launch(void* const* d_in, const int* in_sizes, int n_in,
                              void* d_out, int out_size, void* d_ws, size_t ws_size,
                              hipStream_t stream) {
    const float* fine       = (const float*)d_in[0];
    const float* coarse     = (const float*)d_in[1];
    const float* fs_attn_w  = (const float*)d_in[2];
    const float* fs_conv_w  = (const float*)d_in[3];
    const float* offset_w   = (const float*)d_in[4];
    const float* om_w       = (const float*)d_in[5];
    const float* om_b       = (const float*)d_in[6];
    const float* dcn_kernel = (const float*)d_in[7];
    const float* dcn_bias   = (const float*)d_in[8];
    float* out = (float*)d_out;

    // workspace layout (~38.5 MB)
    char* ws = (char*)d_ws;
    size_t off = 0;
    float* gap = (float*)(ws + off); off += 4096;
    float* a1  = (float*)(ws + off); off += 4096;
    u16*   fcu = (u16*)(ws + off);   off += 16777216ull;
    float* om  = (float*)(ws + off); off += 14155776ull;
    u16*   wtf = (u16*)(ws + off);   off += 2359296ull;
    u16*   wkt = (u16*)(ws + off);   off += 1179648ull;
    u16*   wb0 = (u16*)(ws + off);   off += 131072ull;
    u16*   bomw = (u16*)(ws + off);  off += 2359296ull;

    hipMemsetAsync(gap, 0, 4 * 256 * sizeof(float), stream);
    k_gap<<<dim3(32, 4), 256, 0, stream>>>(fine, gap);
    k_attn<<<4, 256, 0, stream>>>(gap, fs_attn_w, a1);
    k_upsample<<<512, 256, 0, stream>>>(coarse, fcu);
    k_wswz<<<896, 256, 0, stream>>>(fs_conv_w, dcn_kernel, om_w, wb0, wkt, bomw);
    k_g0<<<512, 256, 0, stream>>>(fine, a1, wb0, fcu);
    k_weff<<<dim3(16, 9), 256, 0, stream>>>(offset_w, bomw, wtf);
    k_conv<<<512, 256, 0, stream>>>(fcu, wtf, om_b, om);
    k_dcn<<<512, 256, 0, stream>>>(fcu, om, wkt, dcn_bias, out);
}